// Round 4
// baseline (618.621 us; speedup 1.0000x reference)
//
#include <hip/hip_runtime.h>
#include <hip/hip_bf16.h>

// Self_mask_Spectral_MSA on MI355X — Round 7: gram via second-moment matrix (S = X^T X).
// B=4, H=W=256, C=32, heads=4, d=8. f32 I/O, fp32 accumulation, bf16 intermediates.
//
// R7 changes vs R6 (passed, 497us, absmax 0.015625):
//  - qk_gram_kernel (125us, VALUBusy 17%, latency-bound on 8 serial __shfl per row at
//    2 waves/SIMD) REMOVED. Algebraic identity: G[o][c] = Wk_o^T S Wq_c,
//    ||k_o||^2 = Wk_o^T S Wk_o, ||q_c||^2 = Wq_c^T S Wq_c with S = sum_n x_n x_n^T.
//  - new x2_kernel: S[b] = X_b^T X_b, f32. Lane owns 16 outer-product entries
//    (o=lane&31, e=(lane>>5)*16..+16) -> zero cross-lane ops. 64 rows/wave,
//    LDS block-reduce, 1 atomic per entry per block.
//  - mid_kernel computes T=S·Wq^T, U=S·Wk^T and derives G + norms from them (f32).
//  - ws small-region remapped (S needs 16KB); all other kernels unchanged.

#define NB 4
#define NC 32
#define NS 256
#define NN 65536

typedef unsigned short u16;
typedef unsigned int u32;
typedef __bf16 bf16x8 __attribute__((ext_vector_type(8)));
typedef float f32x4 __attribute__((ext_vector_type(4)));

__device__ __forceinline__ float bf2f(u16 s){ return __uint_as_float(((u32)s) << 16); }
__device__ __forceinline__ u16 f2bf(float x){
  u32 u = __float_as_uint(x);
  u32 r = (u + 0x7fffu + ((u >> 16) & 1u)) >> 16;   // RNE
  return (u16)r;
}
__device__ __forceinline__ void dec8(uint4 u, float* f){
  f[0] = __uint_as_float((u.x & 0xffffu) << 16);
  f[1] = __uint_as_float(u.x & 0xffff0000u);
  f[2] = __uint_as_float((u.y & 0xffffu) << 16);
  f[3] = __uint_as_float(u.y & 0xffff0000u);
  f[4] = __uint_as_float((u.z & 0xffffu) << 16);
  f[5] = __uint_as_float(u.z & 0xffff0000u);
  f[6] = __uint_as_float((u.w & 0xffffu) << 16);
  f[7] = __uint_as_float(u.w & 0xffff0000u);
}
__device__ __forceinline__ void ld32f(const float* __restrict__ p, float* x){
  const float4* q = (const float4*)p;
  #pragma unroll
  for (int k = 0; k < 8; k++){
    float4 f = q[k];
    x[4 * k] = f.x; x[4 * k + 1] = f.y; x[4 * k + 2] = f.z; x[4 * k + 3] = f.w;
  }
}
__device__ __forceinline__ uint4 pack8(const float* f){
  uint4 u;
  u.x = (u32)f2bf(f[0]) | ((u32)f2bf(f[1]) << 16);
  u.y = (u32)f2bf(f[2]) | ((u32)f2bf(f[3]) << 16);
  u.z = (u32)f2bf(f[4]) | ((u32)f2bf(f[5]) << 16);
  u.w = (u32)f2bf(f[6]) | ((u32)f2bf(f[7]) << 16);
  return u;
}
__device__ __forceinline__ float gelu_exact(float x){
  return 0.5f * x * (1.0f + erff(x * 0.70710678118654752f));
}
__device__ __forceinline__ float sigmoidf_(float x){ return 1.0f / (1.0f + expf(-x)); }

// ---------------------- pre: zero accumulators + fold SA weights + transpose pos weights
__global__ __launch_bounds__(256) void pre_kernel(
    const float* __restrict__ c1a, const float* __restrict__ c1b,
    const float* __restrict__ c2a, const float* __restrict__ c2b,
    const float* __restrict__ p1, const float* __restrict__ p2,
    const float* __restrict__ aw,
    float* __restrict__ zbase, float* __restrict__ W1, float* __restrict__ W2,
    u16* __restrict__ wt1, u16* __restrict__ wt2,
    u16* __restrict__ wA1, u16* __restrict__ wA2,
    u16* __restrict__ wAv, int fb){
  int t = threadIdx.x;
  for (int i = t; i < 4352; i += 256) zbase[i] = 0.f;          // sums(128) + S(4096 @ +256)
  for (int idx = t; idx < 288; idx += 256){                    // W1[r*32+j]
    int r = idx >> 5, j = idx & 31;
    float s = 0.f;
    for (int i = 0; i < 32; i++) s += c1b[i] * c1a[(i * 32 + j) * 9 + r];
    W1[idx] = s;
  }
  for (int idx = t; idx < 1568; idx += 256){                   // W2[r*32+j]
    int r = idx >> 5, j = idx & 31;
    float s = 0.f;
    for (int i = 0; i < 32; i++) s += c2b[i] * c2a[(i * 32 + j) * 49 + r];
    W2[idx] = s;
  }
  for (int idx = t; idx < 9216; idx += 256){                   // OIHW -> layouts
    int o = idx / 288;
    int rem = idx - o * 288;
    int i = rem / 9;
    int r = rem - i * 9;
    u16 w1v = f2bf(p1[idx]);
    u16 w2v = f2bf(p2[idx]);
    if (fb){
      wt1[(r * 32 + i) * 32 + o] = w1v;    // [r][i][o]  (fallback path only)
      wt2[(r * 32 + i) * 32 + o] = w2v;
    }
    wA1[(r * 32 + o) * 32 + i] = w1v;      // [r][o][i]  (MFMA A-fragments)
    wA2[(r * 32 + o) * 32 + i] = w2v;
    wAv[(r * 32 + o) * 32 + i] = f2bf(aw[idx]);
  }
}

// ---------------------------------------------------------------- channel sums
__global__ __launch_bounds__(256) void channel_sum_kernel(const float* __restrict__ xhsi,
                                                          float* __restrict__ sums){
  int b = blockIdx.x >> 6;
  int blk = blockIdx.x & 63;
  const float* p = xhsi + (size_t)b * NN * NC;
  int t = threadIdx.x;
  int base = blk * 32768;
  float acc = 0.f;
  for (int k = 0; k < 128; k++) acc += p[base + t + k * 256];
  __shared__ float red[256];
  red[t] = acc;
  __syncthreads();
  if (t < 32){
    float s = 0.f;
    #pragma unroll
    for (int k = 0; k < 8; k++) s += red[t + k * 32];     // channel of red[j] is j&31
    atomicAdd(&sums[b * 32 + t], s);
  }
}

// -------------------------------- R7: S = X^T X per batch (second-moment matrix)
// Lane owns 16 entries: o = lane&31, e = (lane>>5)*16 + j. 64 rows per wave.
__global__ __launch_bounds__(256) void x2_kernel(const float* __restrict__ xfu,
                                                 float* __restrict__ S){
  int t = threadIdx.x;
  int wv = t >> 6, l = t & 63;
  int o = l & 31, ebase = (l >> 5) * 16;
  int b = blockIdx.x >> 8;                       // 256 blocks per batch
  const float* rp = xfu + (size_t)(blockIdx.x * 256 + wv * 64) * NC;
  float acc[16];
  #pragma unroll
  for (int j = 0; j < 16; j++) acc[j] = 0.f;
  #pragma unroll 2
  for (int r = 0; r < 64; r++){
    const float* row = rp + r * NC;
    float xo = row[o];
    const float4* ep = (const float4*)(row + ebase);
    float4 e0 = ep[0], e1 = ep[1], e2 = ep[2], e3 = ep[3];
    acc[0]  += xo * e0.x; acc[1]  += xo * e0.y; acc[2]  += xo * e0.z; acc[3]  += xo * e0.w;
    acc[4]  += xo * e1.x; acc[5]  += xo * e1.y; acc[6]  += xo * e1.z; acc[7]  += xo * e1.w;
    acc[8]  += xo * e2.x; acc[9]  += xo * e2.y; acc[10] += xo * e2.z; acc[11] += xo * e2.w;
    acc[12] += xo * e3.x; acc[13] += xo * e3.y; acc[14] += xo * e3.z; acc[15] += xo * e3.w;
  }
  __shared__ float red[4][64][17];               // pad 17: spread write banks
  #pragma unroll
  for (int j = 0; j < 16; j++) red[wv][l][j] = acc[j];
  __syncthreads();
  #pragma unroll
  for (int k = 0; k < 4; k++){
    int idx = t * 4 + k;
    int ll = idx >> 4, j = idx & 15;
    float s = red[0][ll][j] + red[1][ll][j] + red[2][ll][j] + red[3][ll][j];
    int oo = ll & 31, eb = (ll >> 5) * 16;
    atomicAdd(&S[b * 1024 + oo * 32 + eb + j], s);
  }
}

// --- mid: channel mask (sigmoid MLP) + attention softmax from S + M fold
__global__ __launch_bounds__(256) void mid_kernel(
    const float* __restrict__ sums, const float* __restrict__ fc1,
    const float* __restrict__ fc2, float* __restrict__ cmaskf, float* __restrict__ out_cm,
    const float* __restrict__ S, const float* __restrict__ Wq, const float* __restrict__ Wk,
    const float* __restrict__ projW, float* __restrict__ Mf, u16* __restrict__ Mbf){
  __shared__ float avg[NB][NC], hid[NB][NC];
  __shared__ float attn_s[16][64];
  __shared__ float Wqs[32][32], Wks[32][32];
  __shared__ float Ss[4][32][32];
  __shared__ float Ts[4][32][32], Us[4][32][32];
  __shared__ float nq2[4][32], nk2[4][32];
  int t = threadIdx.x;
  for (int idx = t; idx < 1024; idx += 256){
    Wqs[idx >> 5][idx & 31] = Wq[idx];
    Wks[idx >> 5][idx & 31] = Wk[idx];
  }
  for (int idx = t; idx < 4096; idx += 256)
    Ss[idx >> 10][(idx >> 5) & 31][idx & 31] = S[idx];
  if (t < 128){
    int b = t >> 5, o = t & 31;
    avg[b][o] = sums[t] * (1.0f / 65536.0f);
  }
  __syncthreads();
  // T = S·Wq^T, U = S·Wk^T  (T[b][i][c] = sum_j S[b][i][j]·Wq[c][j])
  for (int idx = t; idx < 8192; idx += 256){
    int which = idx >> 12;
    int b = (idx >> 10) & 3, i = (idx >> 5) & 31, c = idx & 31;
    const float* wrow = which ? &Wks[c][0] : &Wqs[c][0];
    const float* srow = &Ss[b][i][0];
    float s = 0.f;
    #pragma unroll
    for (int j = 0; j < 32; j++) s += srow[j] * wrow[j];
    if (which) Us[b][i][c] = s; else Ts[b][i][c] = s;
  }
  if (t < 128){
    int b = t >> 5, o = t & 31;
    float s = 0.f;
    for (int j = 0; j < 32; j++) s += fc1[o * 32 + j] * avg[b][j];
    hid[b][o] = fmaxf(s, 0.f);
  }
  __syncthreads();
  // norms: ||q_c||^2 = Wq_c·T[:,c], ||k_o||^2 = Wk_o·U[:,o]
  if (t < 128){
    int b = t >> 5, c = t & 31;
    float sq = 0.f, sk = 0.f;
    #pragma unroll
    for (int i = 0; i < 32; i++){
      sq += Wqs[c][i] * Ts[b][i][c];
      sk += Wks[c][i] * Us[b][i][c];
    }
    nq2[b][c] = sq; nk2[b][c] = sk;
  }
  __syncthreads();
  // softmax over normalized gram; G[o][c] = Wk_o · T[:,c]
  if (t < 128){
    int bh = t >> 3, d = t & 7;   // bh = b*4+h
    int b = bh >> 2, h = bh & 3;
    int o = h * 8 + d;
    float nk = fmaxf(sqrtf(nk2[b][o]), 1e-12f);
    float l[8];
    float mx = -1e30f;
    #pragma unroll
    for (int e = 0; e < 8; e++){
      int c = h * 8 + e;
      float G = 0.f;
      #pragma unroll
      for (int i = 0; i < 32; i++) G += Wks[o][i] * Ts[b][i][c];
      float nq = fmaxf(sqrtf(nq2[b][c]), 1e-12f);
      l[e] = G / (nk * nq);
      mx = fmaxf(mx, l[e]);
    }
    float se = 0.f;
    #pragma unroll
    for (int e = 0; e < 8; e++){ l[e] = expf(l[e] - mx); se += l[e]; }
    float inv = 1.f / se;
    #pragma unroll
    for (int e = 0; e < 8; e++) attn_s[bh][d * 8 + e] = l[e] * inv;
  }
  if (t < 128){
    int b = t >> 5, o = t & 31;
    float s2 = 0.f;
    for (int i = 0; i < 32; i++) s2 += fc2[o * 32 + i] * hid[b][i];
    float m = sigmoidf_(s2);
    cmaskf[t] = m;
    out_cm[t] = m;
  }
  __syncthreads();
  for (int idx = t; idx < 4096; idx += 256){        // M[b][o][i]
    int b = idx >> 10, o = (idx >> 5) & 31, i = idx & 31;
    int hd = i >> 3, e = i & 7;
    float s = 0.f;
    #pragma unroll
    for (int d = 0; d < 8; d++)
      s += projW[o * 32 + hd * 8 + d] * attn_s[b * 4 + hd][d * 8 + e];
    Mf[idx] = s;
    Mbf[idx] = f2bf(s);
  }
}

// tile: [c8][xl][yl] uint4 (8 bf16 channels per uint4). 16x16 output px, halo 3.
__global__ __launch_bounds__(256) void spatial_mask_kernel(
    const float* __restrict__ xmsi, const float* __restrict__ W1, const float* __restrict__ W2,
    const float* __restrict__ sac3, float* __restrict__ out_sm){
  __shared__ uint4 tile[4][22][25];
  __shared__ float W1s[9 * 32], W2s[49 * 32];
  int t = threadIdx.x;
  int b = blockIdx.z;
  int x0 = blockIdx.x * 16, y0 = blockIdx.y * 16;
  for (int idx = t; idx < 9 * 32;  idx += 256) W1s[idx] = W1[idx];
  for (int idx = t; idx < 49 * 32; idx += 256) W2s[idx] = W2[idx];
  for (int p = t; p < 484; p += 256){
    int xl = p / 22, yl = p - xl * 22;
    int X = x0 - 3 + xl, Y = y0 - 3 + yl;
    uint4 u0, u1, u2, u3;
    if (X >= 0 && X < NS && Y >= 0 && Y < NS){
      float xr[32];
      ld32f(xmsi + ((size_t)b * NN + (size_t)Y * NS + X) * NC, xr);
      u0 = pack8(xr); u1 = pack8(xr + 8); u2 = pack8(xr + 16); u3 = pack8(xr + 24);
    } else {
      u0 = u1 = u2 = u3 = make_uint4(0, 0, 0, 0);
    }
    tile[0][xl][yl] = u0; tile[1][xl][yl] = u1; tile[2][xl][yl] = u2; tile[3][xl][yl] = u3;
  }
  __syncthreads();
  int j = t & 15, i = t >> 4;     // j: y (h), i: x (w)
  float m1 = 0.f, m2 = 0.f;
  for (int aw = 0; aw < 7; aw++){
    for (int ah = 0; ah < 7; ah++){
      const float* wr = &W2s[(aw * 7 + ah) * 32];
      float s = 0.f;
      #pragma unroll
      for (int c = 0; c < 4; c++){
        uint4 u = tile[c][i + aw][j + ah];
        float g[8]; dec8(u, g);
        #pragma unroll
        for (int k = 0; k < 8; k++) s += g[k] * wr[c * 8 + k];
      }
      m2 += s;
    }
  }
  for (int aw = 0; aw < 3; aw++){
    for (int ah = 0; ah < 3; ah++){
      const float* wr = &W1s[(aw * 3 + ah) * 32];
      float s = 0.f;
      #pragma unroll
      for (int c = 0; c < 4; c++){
        uint4 u = tile[c][i + aw + 2][j + ah + 2];
        float g[8]; dec8(u, g);
        #pragma unroll
        for (int k = 0; k < 8; k++) s += g[k] * wr[c * 8 + k];
      }
      m1 += s;
    }
  }
  float m = sac3[0] * m1 + sac3[1] * m2;
  float sg = sigmoidf_(m);
  int x = x0 + i, y = y0 + j;
  out_sm[(size_t)b * NN + (size_t)x * NS + y] = sg;   // (b,1,w,h): w-major
}

// ----------------------- R6 SPLIT: vgate — f32 V-proj + gate, 2 px/thread, no halo
__global__ __launch_bounds__(256) void vgate_kernel(
    const float* __restrict__ xfu, const float* __restrict__ Wv,
    const float* __restrict__ out_sm, const float* __restrict__ cmaskf,
    u16* __restrict__ gv){
  __shared__ alignas(16) float WvL[1024];       // [i][o]
  __shared__ float cml[NC];
  int t = threadIdx.x;
  int b = blockIdx.x >> 7;                      // 512 blocks: 128 per batch, 2 rows each
  int px0 = blockIdx.x * 512 + t;               // (X = t, Y = 2*(blk&127))
  int px1 = px0 + 256;                          // (X = t, Y+1)
  int X = t;
  int Y0 = (px0 >> 8) & 255;

  for (int idx = t; idx < 1024; idx += 256){
    int oo = idx >> 5, ii = idx & 31;
    WvL[ii * 32 + oo] = Wv[idx];                // Wv[o][i] -> [i][o]
  }
  if (t < 32) cml[t] = cmaskf[b * 32 + t];
  __syncthreads();

  float xr0[32], xr1[32];
  ld32f(xfu + (size_t)px0 * NC, xr0);
  ld32f(xfu + (size_t)px1 * NC, xr1);
  float sm0 = out_sm[(size_t)b * NN + (size_t)X * NS + Y0];
  float sm1 = out_sm[(size_t)b * NN + (size_t)X * NS + Y0 + 1];

  float vo0[32], vo1[32];
  #pragma unroll
  for (int q = 0; q < 32; q++){ vo0[q] = 0.f; vo1[q] = 0.f; }
  for (int i = 0; i < 32; i++){
    const float4* wr = (const float4*)&WvL[i * 32];
    float a0 = xr0[i], a1 = xr1[i];
    #pragma unroll
    for (int q = 0; q < 8; q++){
      float4 w4 = wr[q];
      vo0[4 * q]     += a0 * w4.x;  vo1[4 * q]     += a1 * w4.x;
      vo0[4 * q + 1] += a0 * w4.y;  vo1[4 * q + 1] += a1 * w4.y;
      vo0[4 * q + 2] += a0 * w4.z;  vo1[4 * q + 2] += a1 * w4.z;
      vo0[4 * q + 3] += a0 * w4.w;  vo1[4 * q + 3] += a1 * w4.w;
    }
  }
  float g0[32], g1[32];
  #pragma unroll
  for (int c = 0; c < 32; c++){
    float cm = cml[c];
    g0[c] = vo0[c] * sm0 * cm;
    g1[c] = vo1[c] * sm1 * cm;
  }
  uint4* d0 = (uint4*)(gv + (size_t)px0 * NC);
  uint4* d1 = (uint4*)(gv + (size_t)px1 * NC);
  d0[0] = pack8(g0);  d0[1] = pack8(g0 + 8);  d0[2] = pack8(g0 + 16);  d0[3] = pack8(g0 + 24);
  d1[0] = pack8(g1);  d1[1] = pack8(g1 + 8);  d1[2] = pack8(g1 + 16);  d1[3] = pack8(g1 + 24);
}

// ------------------- R6 SPLIT: vconv — pos1-pattern MFMA conv3x3 + xhsi residual
__global__ __launch_bounds__(256) void vconv_mfma_kernel(
    const u16* __restrict__ gv, const u16* __restrict__ wAv,
    const float* __restrict__ xhsi, u16* __restrict__ vspec_g){
  int t = threadIdx.x;
  int wv = t >> 6, l = t & 63;
  int lp = l & 15, lk = l >> 4;                 // fragment pixel / k-chunk
  int b = blockIdx.x >> 8, Y = blockIdx.x & 255;

  bf16x8 wf[9][2];
  #pragma unroll
  for (int r = 0; r < 9; r++){
    wf[r][0] = *(const bf16x8*)(wAv + ((r * 32 + lp) * 32 + lk * 8));
    wf[r][1] = *(const bf16x8*)(wAv + ((r * 32 + 16 + lp) * 32 + lk * 8));
  }

  const u16* src = gv + (size_t)b * NN * NC;
  const float* res = xhsi + (size_t)b * NN * NC;
  u16* dst = vspec_g + (size_t)b * NN * NC;

  for (int g = 0; g < 4; g++){
    int X0 = wv * 64 + g * 16;
    f32x4 acc0 = {0.f, 0.f, 0.f, 0.f};
    f32x4 acc1 = {0.f, 0.f, 0.f, 0.f};
    #pragma unroll
    for (int dh = -1; dh <= 1; dh++){
      int Yi = Y + dh;
      if ((unsigned)Yi < NS){                   // uniform skip = zero-pad rows
        const u16* row = src + (size_t)Yi * (NS * NC) + lk * 8;
        #pragma unroll
        for (int dw = -1; dw <= 1; dw++){
          int Xi = X0 + lp + dw;
          uint4 u = make_uint4(0, 0, 0, 0);
          if (dw == 0 || (unsigned)Xi < NS) u = *(const uint4*)(row + Xi * NC);
          bf16x8 bfr = __builtin_bit_cast(bf16x8, u);
          const int r = (dw + 1) * 3 + (dh + 1);
          acc0 = __builtin_amdgcn_mfma_f32_16x16x32_bf16(wf[r][0], bfr, acc0, 0, 0, 0);
          acc1 = __builtin_amdgcn_mfma_f32_16x16x32_bf16(wf[r][1], bfr, acc1, 0, 0, 0);
        }
      }
    }
    // D: col=lp=pixel, rows = lk*4+j (+16 for tile 1) = out channel; + residual
    size_t n = (size_t)Y * NS + (X0 + lp);
    float4 rA = *(const float4*)(res + n * NC + lk * 4);
    float4 rB = *(const float4*)(res + n * NC + lk * 4 + 16);
    float v0 = acc0.x + rA.x;
    float v1 = acc0.y + rA.y;
    float v2 = acc0.z + rA.z;
    float v3 = acc0.w + rA.w;
    float v4 = acc1.x + rB.x;
    float v5 = acc1.y + rB.y;
    float v6 = acc1.z + rB.z;
    float v7 = acc1.w + rB.w;
    u16* dp = dst + n * NC + lk * 4;
    *(uint2*)dp = make_uint2((u32)f2bf(v0) | ((u32)f2bf(v1) << 16),
                             (u32)f2bf(v2) | ((u32)f2bf(v3) << 16));
    *(uint2*)(dp + 16) = make_uint2((u32)f2bf(v4) | ((u32)f2bf(v5) << 16),
                                    (u32)f2bf(v6) | ((u32)f2bf(v7) << 16));
  }
}

// ---------------- FALLBACK: fused V-proj + gate + conv + residual (R4, proven)
__global__ __launch_bounds__(256) void vspec_kernel(
    const float* __restrict__ xfu, const float* __restrict__ Wv,
    const float* __restrict__ attnW, const float* __restrict__ out_sm,
    const float* __restrict__ cmaskf, const float* __restrict__ xhsi,
    u16* __restrict__ vspec_g){
  __shared__ u16 gv[32 * 10 * 40];              // [c][xl][yl(34,pad40)] gated v, bf16
  __shared__ u16 Wl[9 * 32 * 32];               // [r][i][o] bf16, r = aw*3+ah
  __shared__ alignas(16) float WvL[1024];       // [i][o]
  __shared__ float cml[32];
  int t = threadIdx.x;
  int b = blockIdx.z;
  int x0 = blockIdx.x * 8, y0 = blockIdx.y * 32;

  for (int idx = t; idx < 1024; idx += 256){
    int oo = idx >> 5, ii = idx & 31;
    WvL[ii * 32 + oo] = Wv[idx];                // Wv[o][i] -> [i][o]
  }
  if (t < 32) cml[t] = cmaskf[b * 32 + t];
  __syncthreads();

  for (int idx = t; idx < 9216; idx += 256){
    int oo = idx / 288;
    int rem = idx - oo * 288;
    int ii = rem / 9;
    int r = rem - ii * 9;
    Wl[(r * 32 + ii) * 32 + oo] = f2bf(attnW[idx]);
  }
  for (int p = t; p < 340; p += 256){           // 10 x 34 halo tile
    int xl = p / 34, yl = p - xl * 34;
    int X = x0 - 1 + xl, Y = y0 - 1 + yl;       // X: w, Y: h
    u16* dst = &gv[xl * 40 + yl];               // + c*400 per channel
    if (X >= 0 && X < NS && Y >= 0 && Y < NS){
      float xr[32];
      ld32f(xfu + ((size_t)b * NN + (size_t)Y * NS + X) * NC, xr);
      float sm = out_sm[(size_t)b * NN + (size_t)X * NS + Y];
      float vo[32];
      #pragma unroll
      for (int q = 0; q < 32; q++) vo[q] = 0.f;
      for (int i = 0; i < 32; i++){
        const float4* wr = (const float4*)&WvL[i * 32];
        float xv = xr[i];
        #pragma unroll
        for (int q = 0; q < 8; q++){
          float4 w4 = wr[q];
          vo[4 * q]     += xv * w4.x;
          vo[4 * q + 1] += xv * w4.y;
          vo[4 * q + 2] += xv * w4.z;
          vo[4 * q + 3] += xv * w4.w;
        }
      }
      #pragma unroll
      for (int c = 0; c < 32; c++) dst[c * 400] = f2bf(vo[c] * sm * cml[c]);
    } else {
      #pragma unroll
      for (int c = 0; c < 32; c++) dst[c * 400] = 0;
    }
  }
  __syncthreads();

  int o = t & 31, xs = t >> 5;
  float acc[32];
  #pragma unroll
  for (int yy = 0; yy < 32; yy++) acc[yy] = 0.f;
  #pragma unroll
  for (int aw = 0; aw < 3; aw++){
    for (int i2 = 0; i2 < 32; i2++){
      const uint4* rp = (const uint4*)(gv + (i2 * 10 + xs + aw) * 40);
      uint4 r0 = rp[0], r1 = rp[1], r2 = rp[2], r3 = rp[3], r4 = rp[4];
      float g[40];
      dec8(r0, g); dec8(r1, g + 8); dec8(r2, g + 16); dec8(r3, g + 24); dec8(r4, g + 32);
      const int wb = (aw * 3 * 32 + i2) * 32 + o;
      float w0 = bf2f(Wl[wb]);
      float w1 = bf2f(Wl[wb + 1024]);
      float w2 = bf2f(Wl[wb + 2048]);
      #pragma unroll
      for (int yy = 0; yy < 32; yy++)
        acc[yy] = fmaf(g[yy], w0, fmaf(g[yy + 1], w1, fmaf(g[yy + 2], w2, acc[yy])));
    }
  }
  int x = x0 + xs;
  #pragma unroll
  for (int yy = 0; yy < 32; yy++){
    size_t n = (size_t)b * NN + (size_t)(y0 + yy) * NS + x;
    vspec_g[n * NC + o] = f2bf(acc[yy] + xhsi[n * NC + o]);
  }
}

// ------------------------- SPLIT PATH R5: MFMA pos1 (vspec -> t), no LDS
// Wave handles 4 groups of 16 consecutive X at fixed Y. A=W[r][o][i], B=vspec px.
__global__ __launch_bounds__(256) void pos1_mfma_kernel(
    const u16* __restrict__ vspec_g, const u16* __restrict__ wA,
    const float* __restrict__ pos1b, u16* __restrict__ t_g){
  int t = threadIdx.x;
  int wv = t >> 6, l = t & 63;
  int lp = l & 15, lk = l >> 4;                 // fragment pixel / k-chunk
  int b = blockIdx.x >> 8, Y = blockIdx.x & 255;

  bf16x8 wf[9][2];
  #pragma unroll
  for (int r = 0; r < 9; r++){
    wf[r][0] = *(const bf16x8*)(wA + ((r * 32 + lp) * 32 + lk * 8));
    wf[r][1] = *(const bf16x8*)(wA + ((r * 32 + 16 + lp) * 32 + lk * 8));
  }
  float bs[8];
  #pragma unroll
  for (int j = 0; j < 4; j++){
    bs[j]     = pos1b[lk * 4 + j];
    bs[4 + j] = pos1b[16 + lk * 4 + j];
  }

  const u16* src = vspec_g + (size_t)b * NN * NC;
  u16* dst = t_g + (size_t)b * NN * NC;

  for (int g = 0; g < 4; g++){
    int X0 = wv * 64 + g * 16;
    f32x4 acc0 = {0.f, 0.f, 0.f, 0.f};
    f32x4 acc1 = {0.f, 0.f, 0.f, 0.f};
    #pragma unroll
    for (int dh = -1; dh <= 1; dh++){
      int Yi = Y + dh;
      if ((unsigned)Yi < NS){                   // uniform skip = zero-pad rows
        const u16* row = src + (size_t)Yi * (NS * NC) + lk * 8;
        #pragma unroll
        for (int dw = -1; dw <= 1; dw++){
          int Xi = X0 + lp + dw;
          uint4 u = make_uint4(0, 0, 0, 0);
          if (dw == 0 || (unsigned)Xi < NS) u = *(const uint4*)(row + Xi * NC);
          bf16x8 bfr = __builtin_bit_cast(bf16x8, u);
          const int r = (dw + 1) * 3 + (dh + 1);
          acc0 = __builtin_amdgcn_mfma_f32_16x16x32_bf16(wf[r][0], bfr, acc0, 0, 0, 0);
          acc1 = __builtin_amdgcn_mfma_f32_16x16x32_bf16(wf[r][1], bfr, acc1, 0, 0, 0);
        }
      }
    }
    // D: col=lp=pixel, rows = lk*4+j (+16 for tile 1) = out channel
    float v0 = gelu_exact(acc0.x + bs[0]);
    float v1 = gelu_exact(acc0.y + bs[1]);
    float v2 = gelu_exact(acc0.z + bs[2]);
    float v3 = gelu_exact(acc0.w + bs[3]);
    float v4 = gelu_exact(acc1.x + bs[4]);
    float v5 = gelu_exact(acc1.y + bs[5]);
    float v6 = gelu_exact(acc1.z + bs[6]);
    float v7 = gelu_exact(acc1.w + bs[7]);
    u16* dp = dst + ((size_t)Y * NS + (X0 + lp)) * NC + lk * 4;
    *(uint2*)dp = make_uint2((u32)f2bf(v0) | ((u32)f2bf(v1) << 16),
                             (u32)f2bf(v2) | ((u32)f2bf(v3) << 16));
    *(uint2*)(dp + 16) = make_uint2((u32)f2bf(v4) | ((u32)f2bf(v5) << 16),
                                    (u32)f2bf(v6) | ((u32)f2bf(v7) << 16));
  }
}

// -------------------- SPLIT PATH R5: MFMA pos2 (t -> out, + out1 epilogue), no LDS
// Wave handles 4 groups of 16 consecutive Y at fixed X (store (b,c,w,h) coalesced in h).
__global__ __launch_bounds__(256) void pos2_mfma_kernel(
    const u16* __restrict__ t_g, const u16* __restrict__ vspec_g,
    const u16* __restrict__ wA, const float* __restrict__ pos2b,
    const u16* __restrict__ Mbf, const float* __restrict__ projb,
    float* __restrict__ outp){
  int t = threadIdx.x;
  int wv = t >> 6, l = t & 63;
  int lp = l & 15, lk = l >> 4;
  int b = blockIdx.x >> 8, X = blockIdx.x & 255;

  bf16x8 wf[9][2];
  #pragma unroll
  for (int r = 0; r < 9; r++){
    wf[r][0] = *(const bf16x8*)(wA + ((r * 32 + lp) * 32 + lk * 8));
    wf[r][1] = *(const bf16x8*)(wA + ((r * 32 + 16 + lp) * 32 + lk * 8));
  }
  bf16x8 mf0 = *(const bf16x8*)(Mbf + ((b * 32 + lp) * 32 + lk * 8));
  bf16x8 mf1 = *(const bf16x8*)(Mbf + ((b * 32 + 16 + lp) * 32 + lk * 8));
  float b2s[8], pbs[8];
  #pragma unroll
  for (int j = 0; j < 4; j++){
    b2s[j]     = pos2b[lk * 4 + j];
    b2s[4 + j] = pos2b[16 + lk * 4 + j];
    pbs[j]     = projb[lk * 4 + j];
    pbs[4 + j] = projb[16 + lk * 4 + j];
  }

  const u16* tsrc = t_g + (size_t)b * NN * NC;
  const u16* vsrc = vspec_g + (size_t)b * NN * NC;
  float* ob0 = outp + (size_t)b * 32 * NN + (size_t)X * NS;

  for (int g = 0; g < 4; g++){
    int Y0 = wv * 64 + g * 16;
    int Yp = Y0 + lp;
    // epilogue GEMM first (independent chain): P = M @ vspec[px]
    f32x4 e0 = {0.f, 0.f, 0.f, 0.f};
    f32x4 e1 = {0.f, 0.f, 0.f, 0.f};
    {
      uint4 u = *(const uint4*)(vsrc + ((size_t)Yp * NS + X) * NC + lk * 8);
      bf16x8 bfr = __builtin_bit_cast(bf16x8, u);
      e0 = __builtin_amdgcn_mfma_f32_16x16x32_bf16(mf0, bfr, e0, 0, 0, 0);
      e1 = __builtin_amdgcn_mfma_f32_16x16x32_bf16(mf1, bfr, e1, 0, 0, 0);
    }
    f32x4 acc0 = {0.f, 0.f, 0.f, 0.f};
    f32x4 acc1 = {0.f, 0.f, 0.f, 0.f};
    #pragma unroll
    for (int dw = -1; dw <= 1; dw++){
      int Xi = X + dw;
      if ((unsigned)Xi < NS){                   // uniform skip = zero-pad cols
        const u16* col = tsrc + (size_t)Xi * NC + lk * 8;
        #pragma unroll
        for (int dh = -1; dh <= 1; dh++){
          int Yi = Yp + dh;
          uint4 u = make_uint4(0, 0, 0, 0);
          if (dh == 0 || (unsigned)Yi < NS) u = *(const uint4*)(col + (size_t)Yi * (NS * NC));
          bf16x8 bfr = __builtin_bit_cast(bf16x8, u);
          const int r = (dw + 1) * 3 + (dh + 1);
          acc0 = __builtin_amdgcn_mfma_f32_16x16x32_bf16(wf[r][0], bfr, acc0, 0, 0, 0);
          acc1 = __builtin_amdgcn_mfma_f32_16x16x32_bf16(wf[r][1], bfr, acc1, 0, 0, 0);
        }
      }
    }
    float r0 = acc0.x + b2s[0] + gelu_exact(e0.x + pbs[0]);
    float r1 = acc0.y + b2s[1] + gelu_exact(e0.y + pbs[1]);
    float r2 = acc0.z + b2s[2] + gelu_exact(e0.z + pbs[2]);
    float r3 = acc0.w + b2s[3] + gelu_exact(e0.w + pbs[3]);
    float r4 = acc1.x + b2s[4] + gelu_exact(e1.x + pbs[4]);
    float r5 = acc1.y + b2s[5] + gelu_exact(e1.y + pbs[5]);
    float r6 = acc1.z + b2s[6] + gelu_exact(e1.z + pbs[6]);
    float r7 = acc1.w + b2s[7] + gelu_exact(e1.w + pbs[7]);
    float* ob = ob0 + Yp + (size_t)(lk * 4) * NN;   // channel lk*4, + c*NN per channel
    ob[0]                 = r0;
    ob[(size_t)NN]        = r1;
    ob[(size_t)2 * NN]    = r2;
    ob[(size_t)3 * NN]    = r3;
    float* ob2 = ob + (size_t)16 * NN;
    ob2[0]                = r4;
    ob2[(size_t)NN]       = r5;
    ob2[(size_t)2 * NN]   = r6;
    ob2[(size_t)3 * NN]   = r7;
  }
}

// ------------------------- FALLBACK PATH (ws too small): R3's fused pos_out, proven
__global__ __launch_bounds__(320) void pos_out_kernel(
    const u16* __restrict__ vspec_g, const u16* __restrict__ wt1,
    const u16* __restrict__ wt2, const float* __restrict__ pos1b,
    const float* __restrict__ pos2b, const float* __restrict__ Mf,
    const float* __restrict__ projb, float* __restrict__ outp){
  __shared__ u16 vs[32 * 12 * 40];    // [i][vxl(12)][vyl(36,pad40)]
  __shared__ u16 tt[32 * 10 * 40];    // [o][txl(10)][tyl(34,pad40)]
  __shared__ u16 wsl[3072];           // one aw-slice: [ah][i][o]
  int t = threadIdx.x;
  int b = blockIdx.z;
  int x0 = blockIdx.x * 8, y0 = blockIdx.y * 32;
  int o = t & 31, xsl = t >> 5;       // xsl in [0,10)

  for (int p = t; p < 12 * 36; p += 320){
    int vxl = p / 36, vyl = p - vxl * 36;
    int X = x0 - 2 + vxl, Y = y0 - 2 + vyl;
    u16* dst = &vs[vxl * 40 + vyl];
    if (X >= 0 && X < NS && Y >= 0 && Y < NS){
      const uint4* src = (const uint4*)(vspec_g + ((size_t)b * NN + (size_t)Y * NS + X) * NC);
      uint4 u0 = src[0], u1 = src[1], u2 = src[2], u3 = src[3];
      alignas(16) u16 raw[32];
      *(uint4*)(raw) = u0; *(uint4*)(raw + 8) = u1;
      *(uint4*)(raw + 16) = u2; *(uint4*)(raw + 24) = u3;
      #pragma unroll
      for (int i = 0; i < 32; i++) dst[i * 480] = raw[i];
    } else {
      #pragma unroll
      for (int i = 0; i < 32; i++) dst[i * 480] = 0;
    }
  }
  __syncthreads();

  float ta[34];
  #pragma unroll
  for (int k = 0; k < 34; k++) ta[k] = 0.f;
  for (int aw = 0; aw < 3; aw++){
    for (int idx = t; idx < 3072; idx += 320) wsl[idx] = wt1[aw * 3072 + idx];
    __syncthreads();
    for (int i2 = 0; i2 < 32; i2++){
      const uint4* rp = (const uint4*)(vs + (i2 * 12 + xsl + aw) * 40);
      uint4 r0 = rp[0], r1 = rp[1], r2 = rp[2], r3 = rp[3], r4 = rp[4];
      float g[40];
      dec8(r0, g); dec8(r1, g + 8); dec8(r2, g + 16); dec8(r3, g + 24); dec8(r4, g + 32);
      float w0 = bf2f(wsl[i2 * 32 + o]);
      float w1 = bf2f(wsl[i2 * 32 + o + 1024]);
      float w2 = bf2f(wsl[i2 * 32 + o + 2048]);
      #pragma unroll
      for (int yl = 0; yl < 34; yl++)
        ta[yl] = fmaf(g[yl], w0, fmaf(g[yl + 1], w1, fmaf(g[yl + 2], w2, ta[yl])));
    }
    __syncthreads();
  }
  {
    float b1 = pos1b[o];
    int X = x0 - 1 + xsl;
    bool colOK = (X >= 0 && X < NS);
    u16* trow = &tt[(o * 10 + xsl) * 40];
    #pragma unroll
    for (int yl = 0; yl < 34; yl++){
      int Y = y0 - 1 + yl;
      float val = (colOK && Y >= 0 && Y < NS) ? gelu_exact(ta[yl] + b1) : 0.f;
      trow[yl] = f2bf(val);
    }
  }
  __syncthreads();

  float acc2[32];
  #pragma unroll
  for (int yy = 0; yy < 32; yy++) acc2[yy] = 0.f;
  for (int aw = 0; aw < 3; aw++){
    for (int idx = t; idx < 3072; idx += 320) wsl[idx] = wt2[aw * 3072 + idx];
    __syncthreads();
    if (xsl < 8){
      for (int i2 = 0; i2 < 32; i2++){
        const uint4* rp = (const uint4*)(tt + (i2 * 10 + xsl + aw) * 40);
        uint4 r0 = rp[0], r1 = rp[1], r2 = rp[2], r3 = rp[3], r4 = rp[4];
        float g[40];
        dec8(r0, g); dec8(r1, g + 8); dec8(r2, g + 16); dec8(r3, g + 24); dec8(r4, g + 32);
        float w0 = bf2f(wsl[i2 * 32 + o]);
        float w1 = bf2f(wsl[i2 * 32 + o + 1024]);
        float w2 = bf2f(wsl[i2 * 32 + o + 2048]);
        #pragma unroll
        for (int yy = 0; yy < 32; yy++)
          acc2[yy] = fmaf(g[yy], w0, fmaf(g[yy + 1], w1, fmaf(g[yy + 2], w2, acc2[yy])));
      }
    }
    __syncthreads();
  }
  if (xsl < 8){
    int x = x0 + xsl;
    float m[32];
    {
      const float4* mp = (const float4*)(Mf + b * 1024 + o * 32);
      #pragma unroll
      for (int k = 0; k < 8; k++){
        float4 f = mp[k];
        m[4 * k] = f.x; m[4 * k + 1] = f.y; m[4 * k + 2] = f.z; m[4 * k + 3] = f.w;
      }
    }
    float pb = projb[o];
    float b2v = pos2b[o];
    float outv[32];
    #pragma unroll
    for (int yy = 0; yy < 32; yy++){
      size_t n = (size_t)b * NN + (size_t)(y0 + yy) * NS + x;
      const uint4* xp = (const uint4*)(vspec_g + n * NC);
      uint4 u0 = xp[0], u1 = xp[1], u2 = xp[2], u3 = xp[3];
      float xr[32];
      dec8(u0, xr); dec8(u1, xr + 8); dec8(u2, xr + 16); dec8(u3, xr + 24);
      float s = pb;
      #pragma unroll
      for (int i2 = 0; i2 < 32; i2++) s += m[i2] * xr[i2];
      outv[yy] = acc2[yy] + b2v + gelu_exact(s);
    }
    float4* dp = (float4*)(outp + (((size_t)(b * 32 + o) * NS) + x) * NS + y0);
    #pragma unroll
    for (int k = 0; k < 8; k++)
      dp[k] = make_float4(outv[4 * k], outv[4 * k + 1], outv[4 * k + 2], outv[4 * k + 3]);
  }
}

// ---------------------------------------------------------------------- launch
extern "C" void kernel_launch(void* const* d_in, const int* in_sizes, int n_in,
                              void* d_out, int out_size, void* d_ws, size_t ws_size,
                              hipStream_t stream){
  (void)in_sizes; (void)n_in; (void)out_size;
  const float* xfu   = (const float*)d_in[0];
  const float* xmsi  = (const float*)d_in[1];
  const float* xhsi  = (const float*)d_in[2];
  const float* Wq    = (const float*)d_in[3];
  const float* Wk    = (const float*)d_in[4];
  const float* Wv    = (const float*)d_in[5];
  const float* projW = (const float*)d_in[6];
  const float* projb = (const float*)d_in[7];
  const float* pos1W = (const float*)d_in[8];
  const float* pos1b = (const float*)d_in[9];
  const float* pos2W = (const float*)d_in[10];
  const float* pos2b = (const float*)d_in[11];
  const float* cafc1 = (const float*)d_in[12];
  const float* cafc2 = (const float*)d_in[13];
  const float* sac1a = (const float*)d_in[14];
  const float* sac1b = (const float*)d_in[15];
  const float* sac2a = (const float*)d_in[16];
  const float* sac2b = (const float*)d_in[17];
  const float* sac3  = (const float*)d_in[18];
  const float* attnW = (const float*)d_in[19];

  float* out = (float*)d_out;
  float* out_main = out;                  // (b,c,w,h) 8388608 f32
  float* out_cm   = out + 8388608;        // 128
  float* out_sm   = out + 8388736;        // 262144

  // workspace map (R7): sums[0,512) S[1024,17408) cmask[17920] W1[18432] W2[20480]
  // Mf[28672,45056) wt1[45056] wt2[63488] wA1[81920] wA2[100352] Mbf[118784,126976)
  // vspec [131072,+16M), t/gv [+16M,+32M)  (gv aliases t_g: disjoint lifetimes)
  char* ws = (char*)d_ws;
  float* sums   = (float*)(ws + 0);         // 128 f (zeroed with S: 4352 f total)
  float* Sm     = (float*)(ws + 1024);      // 4096 f = [4][32][32]
  float* cmaskf = (float*)(ws + 17920);     // 128 f
  float* W1     = (float*)(ws + 18432);     // 288 f
  float* W2     = (float*)(ws + 20480);     // 1568 f
  float* Mf     = (float*)(ws + 28672);     // 4096 f
  u16*   wt1    = (u16*)(ws + 45056);       // 9216 bf16 [r][i][o] (fallback) / wAv (split)
  u16*   wt2    = (u16*)(ws + 63488);       // 9216 bf16
  u16*   wA1    = (u16*)(ws + 81920);       // 9216 bf16 [r][o][i] (MFMA)
  u16*   wA2    = (u16*)(ws + 100352);      // 9216 bf16
  u16*   Mbf    = (u16*)(ws + 118784);      // 4096 bf16 [b][o][i]
  u16*   vspec  = (u16*)(ws + 131072);      // 16 MB bf16 (b,n,c)
  u16*   t_g    = (u16*)(ws + 131072 + 16777216);   // 16 MB bf16 (split path only)
  const bool split = ws_size >= (size_t)(131072 + 2 * 16777216);
  u16*   wAv    = split ? wt1 : wA1;        // split: wt1 slot free; fallback: dummy
  u16*   gvbuf  = t_g;                      // gv dies before pos1 writes t_g

  pre_kernel<<<1, 256, 0, stream>>>(sac1a, sac1b, sac2a, sac2b, pos1W, pos2W, attnW,
                                    sums, W1, W2, wt1, wt2, wA1, wA2, wAv,
                                    split ? 0 : 1);
  channel_sum_kernel<<<256, 256, 0, stream>>>(xhsi, sums);
  spatial_mask_kernel<<<dim3(16, 16, NB), 256, 0, stream>>>(xmsi, W1, W2, sac3, out_sm);
  x2_kernel<<<1024, 256, 0, stream>>>(xfu, Sm);
  mid_kernel<<<1, 256, 0, stream>>>(sums, cafc1, cafc2, cmaskf, out_cm,
                                    Sm, Wq, Wk, projW, Mf, Mbf);
  if (split){
    vgate_kernel<<<512, 256, 0, stream>>>(xfu, Wv, out_sm, cmaskf, gvbuf);
    vconv_mfma_kernel<<<1024, 256, 0, stream>>>(gvbuf, wAv, xhsi, vspec);
    pos1_mfma_kernel<<<1024, 256, 0, stream>>>(vspec, wA1, pos1b, t_g);
    pos2_mfma_kernel<<<1024, 256, 0, stream>>>(t_g, vspec, wA2, pos2b, Mbf, projb, out_main);
  } else {
    vspec_kernel<<<dim3(32, 8, NB), 256, 0, stream>>>(
        xfu, Wv, attnW, out_sm, cmaskf, xhsi, vspec);
    pos_out_kernel<<<dim3(32, 8, NB), 320, 0, stream>>>(
        vspec, wt1, wt2, pos1b, pos2b, Mf, projb, out_main);
  }
}

// Round 5
// 507.783 us; speedup vs baseline: 1.2183x; 1.2183x over previous
//
#include <hip/hip_runtime.h>
#include <hip/hip_bf16.h>

// Self_mask_Spectral_MSA on MI355X — Round 8: fix mid_kernel LDS bank conflicts.
// B=4, H=W=256, C=32, heads=4, d=8. f32 I/O, fp32 accumulation, bf16 intermediates.
//
// R8 changes vs R7 (passed, 618us — REGRESSION vs R6's 497; mid_kernel 145us,
// VALUBusy ~0, 259K bank conflicts):
//  - R7's new mid_kernel LDS arrays were [32][32] f32: row stride 128B = 32 banks.
//    Column-style reads (Wqs[c][j] across lanes c, Ts[b][i][c], Wks[o][i]) were
//    ~32-way bank-serialized on EVERY inner-loop read -> ~350K cycles = 145us.
//  - Fix: pad to stride 33 (Wqs/Wks[32][33], Ss/Ts/Us[4][32][33], attn_s[16][65]).
//    Bank becomes (c+j)&31 / (i+c)&31 -> conflict-free. LDS 65,344B <= 64KiB.
//  - Everything else unchanged from R7.

#define NB 4
#define NC 32
#define NS 256
#define NN 65536

typedef unsigned short u16;
typedef unsigned int u32;
typedef __bf16 bf16x8 __attribute__((ext_vector_type(8)));
typedef float f32x4 __attribute__((ext_vector_type(4)));

__device__ __forceinline__ float bf2f(u16 s){ return __uint_as_float(((u32)s) << 16); }
__device__ __forceinline__ u16 f2bf(float x){
  u32 u = __float_as_uint(x);
  u32 r = (u + 0x7fffu + ((u >> 16) & 1u)) >> 16;   // RNE
  return (u16)r;
}
__device__ __forceinline__ void dec8(uint4 u, float* f){
  f[0] = __uint_as_float((u.x & 0xffffu) << 16);
  f[1] = __uint_as_float(u.x & 0xffff0000u);
  f[2] = __uint_as_float((u.y & 0xffffu) << 16);
  f[3] = __uint_as_float(u.y & 0xffff0000u);
  f[4] = __uint_as_float((u.z & 0xffffu) << 16);
  f[5] = __uint_as_float(u.z & 0xffff0000u);
  f[6] = __uint_as_float((u.w & 0xffffu) << 16);
  f[7] = __uint_as_float(u.w & 0xffff0000u);
}
__device__ __forceinline__ void ld32f(const float* __restrict__ p, float* x){
  const float4* q = (const float4*)p;
  #pragma unroll
  for (int k = 0; k < 8; k++){
    float4 f = q[k];
    x[4 * k] = f.x; x[4 * k + 1] = f.y; x[4 * k + 2] = f.z; x[4 * k + 3] = f.w;
  }
}
__device__ __forceinline__ uint4 pack8(const float* f){
  uint4 u;
  u.x = (u32)f2bf(f[0]) | ((u32)f2bf(f[1]) << 16);
  u.y = (u32)f2bf(f[2]) | ((u32)f2bf(f[3]) << 16);
  u.z = (u32)f2bf(f[4]) | ((u32)f2bf(f[5]) << 16);
  u.w = (u32)f2bf(f[6]) | ((u32)f2bf(f[7]) << 16);
  return u;
}
__device__ __forceinline__ float gelu_exact(float x){
  return 0.5f * x * (1.0f + erff(x * 0.70710678118654752f));
}
__device__ __forceinline__ float sigmoidf_(float x){ return 1.0f / (1.0f + expf(-x)); }

// ---------------------- pre: zero accumulators + fold SA weights + transpose pos weights
__global__ __launch_bounds__(256) void pre_kernel(
    const float* __restrict__ c1a, const float* __restrict__ c1b,
    const float* __restrict__ c2a, const float* __restrict__ c2b,
    const float* __restrict__ p1, const float* __restrict__ p2,
    const float* __restrict__ aw,
    float* __restrict__ zbase, float* __restrict__ W1, float* __restrict__ W2,
    u16* __restrict__ wt1, u16* __restrict__ wt2,
    u16* __restrict__ wA1, u16* __restrict__ wA2,
    u16* __restrict__ wAv, int fb){
  int t = threadIdx.x;
  for (int i = t; i < 4352; i += 256) zbase[i] = 0.f;          // sums(128) + S(4096 @ +256)
  for (int idx = t; idx < 288; idx += 256){                    // W1[r*32+j]
    int r = idx >> 5, j = idx & 31;
    float s = 0.f;
    for (int i = 0; i < 32; i++) s += c1b[i] * c1a[(i * 32 + j) * 9 + r];
    W1[idx] = s;
  }
  for (int idx = t; idx < 1568; idx += 256){                   // W2[r*32+j]
    int r = idx >> 5, j = idx & 31;
    float s = 0.f;
    for (int i = 0; i < 32; i++) s += c2b[i] * c2a[(i * 32 + j) * 49 + r];
    W2[idx] = s;
  }
  for (int idx = t; idx < 9216; idx += 256){                   // OIHW -> layouts
    int o = idx / 288;
    int rem = idx - o * 288;
    int i = rem / 9;
    int r = rem - i * 9;
    u16 w1v = f2bf(p1[idx]);
    u16 w2v = f2bf(p2[idx]);
    if (fb){
      wt1[(r * 32 + i) * 32 + o] = w1v;    // [r][i][o]  (fallback path only)
      wt2[(r * 32 + i) * 32 + o] = w2v;
    }
    wA1[(r * 32 + o) * 32 + i] = w1v;      // [r][o][i]  (MFMA A-fragments)
    wA2[(r * 32 + o) * 32 + i] = w2v;
    wAv[(r * 32 + o) * 32 + i] = f2bf(aw[idx]);
  }
}

// ---------------------------------------------------------------- channel sums
__global__ __launch_bounds__(256) void channel_sum_kernel(const float* __restrict__ xhsi,
                                                          float* __restrict__ sums){
  int b = blockIdx.x >> 6;
  int blk = blockIdx.x & 63;
  const float* p = xhsi + (size_t)b * NN * NC;
  int t = threadIdx.x;
  int base = blk * 32768;
  float acc = 0.f;
  for (int k = 0; k < 128; k++) acc += p[base + t + k * 256];
  __shared__ float red[256];
  red[t] = acc;
  __syncthreads();
  if (t < 32){
    float s = 0.f;
    #pragma unroll
    for (int k = 0; k < 8; k++) s += red[t + k * 32];     // channel of red[j] is j&31
    atomicAdd(&sums[b * 32 + t], s);
  }
}

// -------------------------------- R7: S = X^T X per batch (second-moment matrix)
// Lane owns 16 entries: o = lane&31, e = (lane>>5)*16 + j. 64 rows per wave.
__global__ __launch_bounds__(256) void x2_kernel(const float* __restrict__ xfu,
                                                 float* __restrict__ S){
  int t = threadIdx.x;
  int wv = t >> 6, l = t & 63;
  int o = l & 31, ebase = (l >> 5) * 16;
  int b = blockIdx.x >> 8;                       // 256 blocks per batch
  const float* rp = xfu + (size_t)(blockIdx.x * 256 + wv * 64) * NC;
  float acc[16];
  #pragma unroll
  for (int j = 0; j < 16; j++) acc[j] = 0.f;
  #pragma unroll 2
  for (int r = 0; r < 64; r++){
    const float* row = rp + r * NC;
    float xo = row[o];
    const float4* ep = (const float4*)(row + ebase);
    float4 e0 = ep[0], e1 = ep[1], e2 = ep[2], e3 = ep[3];
    acc[0]  += xo * e0.x; acc[1]  += xo * e0.y; acc[2]  += xo * e0.z; acc[3]  += xo * e0.w;
    acc[4]  += xo * e1.x; acc[5]  += xo * e1.y; acc[6]  += xo * e1.z; acc[7]  += xo * e1.w;
    acc[8]  += xo * e2.x; acc[9]  += xo * e2.y; acc[10] += xo * e2.z; acc[11] += xo * e2.w;
    acc[12] += xo * e3.x; acc[13] += xo * e3.y; acc[14] += xo * e3.z; acc[15] += xo * e3.w;
  }
  __shared__ float red[4][64][17];               // pad 17: spread write banks
  #pragma unroll
  for (int j = 0; j < 16; j++) red[wv][l][j] = acc[j];
  __syncthreads();
  #pragma unroll
  for (int k = 0; k < 4; k++){
    int idx = t * 4 + k;
    int ll = idx >> 4, j = idx & 15;
    float s = red[0][ll][j] + red[1][ll][j] + red[2][ll][j] + red[3][ll][j];
    int oo = ll & 31, eb = (ll >> 5) * 16;
    atomicAdd(&S[b * 1024 + oo * 32 + eb + j], s);
  }
}

// --- mid: channel mask (sigmoid MLP) + attention softmax from S + M fold
// R8: all stride-32 LDS arrays padded to 33 (bank-conflict fix).
__global__ __launch_bounds__(256) void mid_kernel(
    const float* __restrict__ sums, const float* __restrict__ fc1,
    const float* __restrict__ fc2, float* __restrict__ cmaskf, float* __restrict__ out_cm,
    const float* __restrict__ S, const float* __restrict__ Wq, const float* __restrict__ Wk,
    const float* __restrict__ projW, float* __restrict__ Mf, u16* __restrict__ Mbf){
  __shared__ float avg[NB][NC], hid[NB][NC];
  __shared__ float attn_s[16][65];
  __shared__ float Wqs[32][33], Wks[32][33];
  __shared__ float Ss[4][32][33];
  __shared__ float Ts[4][32][33], Us[4][32][33];
  __shared__ float nq2[4][32], nk2[4][32];
  int t = threadIdx.x;
  for (int idx = t; idx < 1024; idx += 256){
    Wqs[idx >> 5][idx & 31] = Wq[idx];
    Wks[idx >> 5][idx & 31] = Wk[idx];
  }
  for (int idx = t; idx < 4096; idx += 256)
    Ss[idx >> 10][(idx >> 5) & 31][idx & 31] = S[idx];
  if (t < 128){
    int b = t >> 5, o = t & 31;
    avg[b][o] = sums[t] * (1.0f / 65536.0f);
  }
  __syncthreads();
  // T = S·Wq^T, U = S·Wk^T  (T[b][i][c] = sum_j S[b][i][j]·Wq[c][j])
  for (int idx = t; idx < 8192; idx += 256){
    int which = idx >> 12;
    int b = (idx >> 10) & 3, i = (idx >> 5) & 31, c = idx & 31;
    const float* wrow = which ? &Wks[c][0] : &Wqs[c][0];
    const float* srow = &Ss[b][i][0];
    float s = 0.f;
    #pragma unroll
    for (int j = 0; j < 32; j++) s += srow[j] * wrow[j];
    if (which) Us[b][i][c] = s; else Ts[b][i][c] = s;
  }
  if (t < 128){
    int b = t >> 5, o = t & 31;
    float s = 0.f;
    for (int j = 0; j < 32; j++) s += fc1[o * 32 + j] * avg[b][j];
    hid[b][o] = fmaxf(s, 0.f);
  }
  __syncthreads();
  // norms: ||q_c||^2 = Wq_c·T[:,c], ||k_o||^2 = Wk_o·U[:,o]
  if (t < 128){
    int b = t >> 5, c = t & 31;
    float sq = 0.f, sk = 0.f;
    #pragma unroll
    for (int i = 0; i < 32; i++){
      sq += Wqs[c][i] * Ts[b][i][c];
      sk += Wks[c][i] * Us[b][i][c];
    }
    nq2[b][c] = sq; nk2[b][c] = sk;
  }
  __syncthreads();
  // softmax over normalized gram; G[o][c] = Wk_o · T[:,c]
  if (t < 128){
    int bh = t >> 3, d = t & 7;   // bh = b*4+h
    int b = bh >> 2, h = bh & 3;
    int o = h * 8 + d;
    float nk = fmaxf(sqrtf(nk2[b][o]), 1e-12f);
    float l[8];
    float mx = -1e30f;
    #pragma unroll
    for (int e = 0; e < 8; e++){
      int c = h * 8 + e;
      float G = 0.f;
      #pragma unroll
      for (int i = 0; i < 32; i++) G += Wks[o][i] * Ts[b][i][c];
      float nq = fmaxf(sqrtf(nq2[b][c]), 1e-12f);
      l[e] = G / (nk * nq);
      mx = fmaxf(mx, l[e]);
    }
    float se = 0.f;
    #pragma unroll
    for (int e = 0; e < 8; e++){ l[e] = expf(l[e] - mx); se += l[e]; }
    float inv = 1.f / se;
    #pragma unroll
    for (int e = 0; e < 8; e++) attn_s[bh][d * 8 + e] = l[e] * inv;
  }
  if (t < 128){
    int b = t >> 5, o = t & 31;
    float s2 = 0.f;
    for (int i = 0; i < 32; i++) s2 += fc2[o * 32 + i] * hid[b][i];
    float m = sigmoidf_(s2);
    cmaskf[t] = m;
    out_cm[t] = m;
  }
  __syncthreads();
  for (int idx = t; idx < 4096; idx += 256){        // M[b][o][i]
    int b = idx >> 10, o = (idx >> 5) & 31, i = idx & 31;
    int hd = i >> 3, e = i & 7;
    float s = 0.f;
    #pragma unroll
    for (int d = 0; d < 8; d++)
      s += projW[o * 32 + hd * 8 + d] * attn_s[b * 4 + hd][d * 8 + e];
    Mf[idx] = s;
    Mbf[idx] = f2bf(s);
  }
}

// tile: [c8][xl][yl] uint4 (8 bf16 channels per uint4). 16x16 output px, halo 3.
__global__ __launch_bounds__(256) void spatial_mask_kernel(
    const float* __restrict__ xmsi, const float* __restrict__ W1, const float* __restrict__ W2,
    const float* __restrict__ sac3, float* __restrict__ out_sm){
  __shared__ uint4 tile[4][22][25];
  __shared__ float W1s[9 * 32], W2s[49 * 32];
  int t = threadIdx.x;
  int b = blockIdx.z;
  int x0 = blockIdx.x * 16, y0 = blockIdx.y * 16;
  for (int idx = t; idx < 9 * 32;  idx += 256) W1s[idx] = W1[idx];
  for (int idx = t; idx < 49 * 32; idx += 256) W2s[idx] = W2[idx];
  for (int p = t; p < 484; p += 256){
    int xl = p / 22, yl = p - xl * 22;
    int X = x0 - 3 + xl, Y = y0 - 3 + yl;
    uint4 u0, u1, u2, u3;
    if (X >= 0 && X < NS && Y >= 0 && Y < NS){
      float xr[32];
      ld32f(xmsi + ((size_t)b * NN + (size_t)Y * NS + X) * NC, xr);
      u0 = pack8(xr); u1 = pack8(xr + 8); u2 = pack8(xr + 16); u3 = pack8(xr + 24);
    } else {
      u0 = u1 = u2 = u3 = make_uint4(0, 0, 0, 0);
    }
    tile[0][xl][yl] = u0; tile[1][xl][yl] = u1; tile[2][xl][yl] = u2; tile[3][xl][yl] = u3;
  }
  __syncthreads();
  int j = t & 15, i = t >> 4;     // j: y (h), i: x (w)
  float m1 = 0.f, m2 = 0.f;
  for (int aw = 0; aw < 7; aw++){
    for (int ah = 0; ah < 7; ah++){
      const float* wr = &W2s[(aw * 7 + ah) * 32];
      float s = 0.f;
      #pragma unroll
      for (int c = 0; c < 4; c++){
        uint4 u = tile[c][i + aw][j + ah];
        float g[8]; dec8(u, g);
        #pragma unroll
        for (int k = 0; k < 8; k++) s += g[k] * wr[c * 8 + k];
      }
      m2 += s;
    }
  }
  for (int aw = 0; aw < 3; aw++){
    for (int ah = 0; ah < 3; ah++){
      const float* wr = &W1s[(aw * 3 + ah) * 32];
      float s = 0.f;
      #pragma unroll
      for (int c = 0; c < 4; c++){
        uint4 u = tile[c][i + aw + 2][j + ah + 2];
        float g[8]; dec8(u, g);
        #pragma unroll
        for (int k = 0; k < 8; k++) s += g[k] * wr[c * 8 + k];
      }
      m1 += s;
    }
  }
  float m = sac3[0] * m1 + sac3[1] * m2;
  float sg = sigmoidf_(m);
  int x = x0 + i, y = y0 + j;
  out_sm[(size_t)b * NN + (size_t)x * NS + y] = sg;   // (b,1,w,h): w-major
}

// ----------------------- R6 SPLIT: vgate — f32 V-proj + gate, 2 px/thread, no halo
__global__ __launch_bounds__(256) void vgate_kernel(
    const float* __restrict__ xfu, const float* __restrict__ Wv,
    const float* __restrict__ out_sm, const float* __restrict__ cmaskf,
    u16* __restrict__ gv){
  __shared__ alignas(16) float WvL[1024];       // [i][o]
  __shared__ float cml[NC];
  int t = threadIdx.x;
  int b = blockIdx.x >> 7;                      // 512 blocks: 128 per batch, 2 rows each
  int px0 = blockIdx.x * 512 + t;               // (X = t, Y = 2*(blk&127))
  int px1 = px0 + 256;                          // (X = t, Y+1)
  int X = t;
  int Y0 = (px0 >> 8) & 255;

  for (int idx = t; idx < 1024; idx += 256){
    int oo = idx >> 5, ii = idx & 31;
    WvL[ii * 32 + oo] = Wv[idx];                // Wv[o][i] -> [i][o]
  }
  if (t < 32) cml[t] = cmaskf[b * 32 + t];
  __syncthreads();

  float xr0[32], xr1[32];
  ld32f(xfu + (size_t)px0 * NC, xr0);
  ld32f(xfu + (size_t)px1 * NC, xr1);
  float sm0 = out_sm[(size_t)b * NN + (size_t)X * NS + Y0];
  float sm1 = out_sm[(size_t)b * NN + (size_t)X * NS + Y0 + 1];

  float vo0[32], vo1[32];
  #pragma unroll
  for (int q = 0; q < 32; q++){ vo0[q] = 0.f; vo1[q] = 0.f; }
  for (int i = 0; i < 32; i++){
    const float4* wr = (const float4*)&WvL[i * 32];
    float a0 = xr0[i], a1 = xr1[i];
    #pragma unroll
    for (int q = 0; q < 8; q++){
      float4 w4 = wr[q];
      vo0[4 * q]     += a0 * w4.x;  vo1[4 * q]     += a1 * w4.x;
      vo0[4 * q + 1] += a0 * w4.y;  vo1[4 * q + 1] += a1 * w4.y;
      vo0[4 * q + 2] += a0 * w4.z;  vo1[4 * q + 2] += a1 * w4.z;
      vo0[4 * q + 3] += a0 * w4.w;  vo1[4 * q + 3] += a1 * w4.w;
    }
  }
  float g0[32], g1[32];
  #pragma unroll
  for (int c = 0; c < 32; c++){
    float cm = cml[c];
    g0[c] = vo0[c] * sm0 * cm;
    g1[c] = vo1[c] * sm1 * cm;
  }
  uint4* d0 = (uint4*)(gv + (size_t)px0 * NC);
  uint4* d1 = (uint4*)(gv + (size_t)px1 * NC);
  d0[0] = pack8(g0);  d0[1] = pack8(g0 + 8);  d0[2] = pack8(g0 + 16);  d0[3] = pack8(g0 + 24);
  d1[0] = pack8(g1);  d1[1] = pack8(g1 + 8);  d1[2] = pack8(g1 + 16);  d1[3] = pack8(g1 + 24);
}

// ------------------- R6 SPLIT: vconv — pos1-pattern MFMA conv3x3 + xhsi residual
__global__ __launch_bounds__(256) void vconv_mfma_kernel(
    const u16* __restrict__ gv, const u16* __restrict__ wAv,
    const float* __restrict__ xhsi, u16* __restrict__ vspec_g){
  int t = threadIdx.x;
  int wv = t >> 6, l = t & 63;
  int lp = l & 15, lk = l >> 4;                 // fragment pixel / k-chunk
  int b = blockIdx.x >> 8, Y = blockIdx.x & 255;

  bf16x8 wf[9][2];
  #pragma unroll
  for (int r = 0; r < 9; r++){
    wf[r][0] = *(const bf16x8*)(wAv + ((r * 32 + lp) * 32 + lk * 8));
    wf[r][1] = *(const bf16x8*)(wAv + ((r * 32 + 16 + lp) * 32 + lk * 8));
  }

  const u16* src = gv + (size_t)b * NN * NC;
  const float* res = xhsi + (size_t)b * NN * NC;
  u16* dst = vspec_g + (size_t)b * NN * NC;

  for (int g = 0; g < 4; g++){
    int X0 = wv * 64 + g * 16;
    f32x4 acc0 = {0.f, 0.f, 0.f, 0.f};
    f32x4 acc1 = {0.f, 0.f, 0.f, 0.f};
    #pragma unroll
    for (int dh = -1; dh <= 1; dh++){
      int Yi = Y + dh;
      if ((unsigned)Yi < NS){                   // uniform skip = zero-pad rows
        const u16* row = src + (size_t)Yi * (NS * NC) + lk * 8;
        #pragma unroll
        for (int dw = -1; dw <= 1; dw++){
          int Xi = X0 + lp + dw;
          uint4 u = make_uint4(0, 0, 0, 0);
          if (dw == 0 || (unsigned)Xi < NS) u = *(const uint4*)(row + Xi * NC);
          bf16x8 bfr = __builtin_bit_cast(bf16x8, u);
          const int r = (dw + 1) * 3 + (dh + 1);
          acc0 = __builtin_amdgcn_mfma_f32_16x16x32_bf16(wf[r][0], bfr, acc0, 0, 0, 0);
          acc1 = __builtin_amdgcn_mfma_f32_16x16x32_bf16(wf[r][1], bfr, acc1, 0, 0, 0);
        }
      }
    }
    // D: col=lp=pixel, rows = lk*4+j (+16 for tile 1) = out channel; + residual
    size_t n = (size_t)Y * NS + (X0 + lp);
    float4 rA = *(const float4*)(res + n * NC + lk * 4);
    float4 rB = *(const float4*)(res + n * NC + lk * 4 + 16);
    float v0 = acc0.x + rA.x;
    float v1 = acc0.y + rA.y;
    float v2 = acc0.z + rA.z;
    float v3 = acc0.w + rA.w;
    float v4 = acc1.x + rB.x;
    float v5 = acc1.y + rB.y;
    float v6 = acc1.z + rB.z;
    float v7 = acc1.w + rB.w;
    u16* dp = dst + n * NC + lk * 4;
    *(uint2*)dp = make_uint2((u32)f2bf(v0) | ((u32)f2bf(v1) << 16),
                             (u32)f2bf(v2) | ((u32)f2bf(v3) << 16));
    *(uint2*)(dp + 16) = make_uint2((u32)f2bf(v4) | ((u32)f2bf(v5) << 16),
                                    (u32)f2bf(v6) | ((u32)f2bf(v7) << 16));
  }
}

// ---------------- FALLBACK: fused V-proj + gate + conv + residual (R4, proven)
__global__ __launch_bounds__(256) void vspec_kernel(
    const float* __restrict__ xfu, const float* __restrict__ Wv,
    const float* __restrict__ attnW, const float* __restrict__ out_sm,
    const float* __restrict__ cmaskf, const float* __restrict__ xhsi,
    u16* __restrict__ vspec_g){
  __shared__ u16 gv[32 * 10 * 40];              // [c][xl][yl(34,pad40)] gated v, bf16
  __shared__ u16 Wl[9 * 32 * 32];               // [r][i][o] bf16, r = aw*3+ah
  __shared__ alignas(16) float WvL[1024];       // [i][o]
  __shared__ float cml[32];
  int t = threadIdx.x;
  int b = blockIdx.z;
  int x0 = blockIdx.x * 8, y0 = blockIdx.y * 32;

  for (int idx = t; idx < 1024; idx += 256){
    int oo = idx >> 5, ii = idx & 31;
    WvL[ii * 32 + oo] = Wv[idx];                // Wv[o][i] -> [i][o]
  }
  if (t < 32) cml[t] = cmaskf[b * 32 + t];
  __syncthreads();

  for (int idx = t; idx < 9216; idx += 256){
    int oo = idx / 288;
    int rem = idx - oo * 288;
    int ii = rem / 9;
    int r = rem - ii * 9;
    Wl[(r * 32 + ii) * 32 + oo] = f2bf(attnW[idx]);
  }
  for (int p = t; p < 340; p += 256){           // 10 x 34 halo tile
    int xl = p / 34, yl = p - xl * 34;
    int X = x0 - 1 + xl, Y = y0 - 1 + yl;       // X: w, Y: h
    u16* dst = &gv[xl * 40 + yl];               // + c*400 per channel
    if (X >= 0 && X < NS && Y >= 0 && Y < NS){
      float xr[32];
      ld32f(xfu + ((size_t)b * NN + (size_t)Y * NS + X) * NC, xr);
      float sm = out_sm[(size_t)b * NN + (size_t)X * NS + Y];
      float vo[32];
      #pragma unroll
      for (int q = 0; q < 32; q++) vo[q] = 0.f;
      for (int i = 0; i < 32; i++){
        const float4* wr = (const float4*)&WvL[i * 32];
        float xv = xr[i];
        #pragma unroll
        for (int q = 0; q < 8; q++){
          float4 w4 = wr[q];
          vo[4 * q]     += xv * w4.x;
          vo[4 * q + 1] += xv * w4.y;
          vo[4 * q + 2] += xv * w4.z;
          vo[4 * q + 3] += xv * w4.w;
        }
      }
      #pragma unroll
      for (int c = 0; c < 32; c++) dst[c * 400] = f2bf(vo[c] * sm * cml[c]);
    } else {
      #pragma unroll
      for (int c = 0; c < 32; c++) dst[c * 400] = 0;
    }
  }
  __syncthreads();

  int o = t & 31, xs = t >> 5;
  float acc[32];
  #pragma unroll
  for (int yy = 0; yy < 32; yy++) acc[yy] = 0.f;
  #pragma unroll
  for (int aw = 0; aw < 3; aw++){
    for (int i2 = 0; i2 < 32; i2++){
      const uint4* rp = (const uint4*)(gv + (i2 * 10 + xs + aw) * 40);
      uint4 r0 = rp[0], r1 = rp[1], r2 = rp[2], r3 = rp[3], r4 = rp[4];
      float g[40];
      dec8(r0, g); dec8(r1, g + 8); dec8(r2, g + 16); dec8(r3, g + 24); dec8(r4, g + 32);
      const int wb = (aw * 3 * 32 + i2) * 32 + o;
      float w0 = bf2f(Wl[wb]);
      float w1 = bf2f(Wl[wb + 1024]);
      float w2 = bf2f(Wl[wb + 2048]);
      #pragma unroll
      for (int yy = 0; yy < 32; yy++)
        acc[yy] = fmaf(g[yy], w0, fmaf(g[yy + 1], w1, fmaf(g[yy + 2], w2, acc[yy])));
    }
  }
  int x = x0 + xs;
  #pragma unroll
  for (int yy = 0; yy < 32; yy++){
    size_t n = (size_t)b * NN + (size_t)(y0 + yy) * NS + x;
    vspec_g[n * NC + o] = f2bf(acc[yy] + xhsi[n * NC + o]);
  }
}

// ------------------------- SPLIT PATH R5: MFMA pos1 (vspec -> t), no LDS
// Wave handles 4 groups of 16 consecutive X at fixed Y. A=W[r][o][i], B=vspec px.
__global__ __launch_bounds__(256) void pos1_mfma_kernel(
    const u16* __restrict__ vspec_g, const u16* __restrict__ wA,
    const float* __restrict__ pos1b, u16* __restrict__ t_g){
  int t = threadIdx.x;
  int wv = t >> 6, l = t & 63;
  int lp = l & 15, lk = l >> 4;                 // fragment pixel / k-chunk
  int b = blockIdx.x >> 8, Y = blockIdx.x & 255;

  bf16x8 wf[9][2];
  #pragma unroll
  for (int r = 0; r < 9; r++){
    wf[r][0] = *(const bf16x8*)(wA + ((r * 32 + lp) * 32 + lk * 8));
    wf[r][1] = *(const bf16x8*)(wA + ((r * 32 + 16 + lp) * 32 + lk * 8));
  }
  float bs[8];
  #pragma unroll
  for (int j = 0; j < 4; j++){
    bs[j]     = pos1b[lk * 4 + j];
    bs[4 + j] = pos1b[16 + lk * 4 + j];
  }

  const u16* src = vspec_g + (size_t)b * NN * NC;
  u16* dst = t_g + (size_t)b * NN * NC;

  for (int g = 0; g < 4; g++){
    int X0 = wv * 64 + g * 16;
    f32x4 acc0 = {0.f, 0.f, 0.f, 0.f};
    f32x4 acc1 = {0.f, 0.f, 0.f, 0.f};
    #pragma unroll
    for (int dh = -1; dh <= 1; dh++){
      int Yi = Y + dh;
      if ((unsigned)Yi < NS){                   // uniform skip = zero-pad rows
        const u16* row = src + (size_t)Yi * (NS * NC) + lk * 8;
        #pragma unroll
        for (int dw = -1; dw <= 1; dw++){
          int Xi = X0 + lp + dw;
          uint4 u = make_uint4(0, 0, 0, 0);
          if (dw == 0 || (unsigned)Xi < NS) u = *(const uint4*)(row + Xi * NC);
          bf16x8 bfr = __builtin_bit_cast(bf16x8, u);
          const int r = (dw + 1) * 3 + (dh + 1);
          acc0 = __builtin_amdgcn_mfma_f32_16x16x32_bf16(wf[r][0], bfr, acc0, 0, 0, 0);
          acc1 = __builtin_amdgcn_mfma_f32_16x16x32_bf16(wf[r][1], bfr, acc1, 0, 0, 0);
        }
      }
    }
    // D: col=lp=pixel, rows = lk*4+j (+16 for tile 1) = out channel
    float v0 = gelu_exact(acc0.x + bs[0]);
    float v1 = gelu_exact(acc0.y + bs[1]);
    float v2 = gelu_exact(acc0.z + bs[2]);
    float v3 = gelu_exact(acc0.w + bs[3]);
    float v4 = gelu_exact(acc1.x + bs[4]);
    float v5 = gelu_exact(acc1.y + bs[5]);
    float v6 = gelu_exact(acc1.z + bs[6]);
    float v7 = gelu_exact(acc1.w + bs[7]);
    u16* dp = dst + ((size_t)Y * NS + (X0 + lp)) * NC + lk * 4;
    *(uint2*)dp = make_uint2((u32)f2bf(v0) | ((u32)f2bf(v1) << 16),
                             (u32)f2bf(v2) | ((u32)f2bf(v3) << 16));
    *(uint2*)(dp + 16) = make_uint2((u32)f2bf(v4) | ((u32)f2bf(v5) << 16),
                                    (u32)f2bf(v6) | ((u32)f2bf(v7) << 16));
  }
}

// -------------------- SPLIT PATH R5: MFMA pos2 (t -> out, + out1 epilogue), no LDS
// Wave handles 4 groups of 16 consecutive Y at fixed X (store (b,c,w,h) coalesced in h).
__global__ __launch_bounds__(256) void pos2_mfma_kernel(
    const u16* __restrict__ t_g, const u16* __restrict__ vspec_g,
    const u16* __restrict__ wA, const float* __restrict__ pos2b,
    const u16* __restrict__ Mbf, const float* __restrict__ projb,
    float* __restrict__ outp){
  int t = threadIdx.x;
  int wv = t >> 6, l = t & 63;
  int lp = l & 15, lk = l >> 4;
  int b = blockIdx.x >> 8, X = blockIdx.x & 255;

  bf16x8 wf[9][2];
  #pragma unroll
  for (int r = 0; r < 9; r++){
    wf[r][0] = *(const bf16x8*)(wA + ((r * 32 + lp) * 32 + lk * 8));
    wf[r][1] = *(const bf16x8*)(wA + ((r * 32 + 16 + lp) * 32 + lk * 8));
  }
  bf16x8 mf0 = *(const bf16x8*)(Mbf + ((b * 32 + lp) * 32 + lk * 8));
  bf16x8 mf1 = *(const bf16x8*)(Mbf + ((b * 32 + 16 + lp) * 32 + lk * 8));
  float b2s[8], pbs[8];
  #pragma unroll
  for (int j = 0; j < 4; j++){
    b2s[j]     = pos2b[lk * 4 + j];
    b2s[4 + j] = pos2b[16 + lk * 4 + j];
    pbs[j]     = projb[lk * 4 + j];
    pbs[4 + j] = projb[16 + lk * 4 + j];
  }

  const u16* tsrc = t_g + (size_t)b * NN * NC;
  const u16* vsrc = vspec_g + (size_t)b * NN * NC;
  float* ob0 = outp + (size_t)b * 32 * NN + (size_t)X * NS;

  for (int g = 0; g < 4; g++){
    int Y0 = wv * 64 + g * 16;
    int Yp = Y0 + lp;
    // epilogue GEMM first (independent chain): P = M @ vspec[px]
    f32x4 e0 = {0.f, 0.f, 0.f, 0.f};
    f32x4 e1 = {0.f, 0.f, 0.f, 0.f};
    {
      uint4 u = *(const uint4*)(vsrc + ((size_t)Yp * NS + X) * NC + lk * 8);
      bf16x8 bfr = __builtin_bit_cast(bf16x8, u);
      e0 = __builtin_amdgcn_mfma_f32_16x16x32_bf16(mf0, bfr, e0, 0, 0, 0);
      e1 = __builtin_amdgcn_mfma_f32_16x16x32_bf16(mf1, bfr, e1, 0, 0, 0);
    }
    f32x4 acc0 = {0.f, 0.f, 0.f, 0.f};
    f32x4 acc1 = {0.f, 0.f, 0.f, 0.f};
    #pragma unroll
    for (int dw = -1; dw <= 1; dw++){
      int Xi = X + dw;
      if ((unsigned)Xi < NS){                   // uniform skip = zero-pad cols
        const u16* col = tsrc + (size_t)Xi * NC + lk * 8;
        #pragma unroll
        for (int dh = -1; dh <= 1; dh++){
          int Yi = Yp + dh;
          uint4 u = make_uint4(0, 0, 0, 0);
          if (dh == 0 || (unsigned)Yi < NS) u = *(const uint4*)(col + (size_t)Yi * (NS * NC));
          bf16x8 bfr = __builtin_bit_cast(bf16x8, u);
          const int r = (dw + 1) * 3 + (dh + 1);
          acc0 = __builtin_amdgcn_mfma_f32_16x16x32_bf16(wf[r][0], bfr, acc0, 0, 0, 0);
          acc1 = __builtin_amdgcn_mfma_f32_16x16x32_bf16(wf[r][1], bfr, acc1, 0, 0, 0);
        }
      }
    }
    float r0 = acc0.x + b2s[0] + gelu_exact(e0.x + pbs[0]);
    float r1 = acc0.y + b2s[1] + gelu_exact(e0.y + pbs[1]);
    float r2 = acc0.z + b2s[2] + gelu_exact(e0.z + pbs[2]);
    float r3 = acc0.w + b2s[3] + gelu_exact(e0.w + pbs[3]);
    float r4 = acc1.x + b2s[4] + gelu_exact(e1.x + pbs[4]);
    float r5 = acc1.y + b2s[5] + gelu_exact(e1.y + pbs[5]);
    float r6 = acc1.z + b2s[6] + gelu_exact(e1.z + pbs[6]);
    float r7 = acc1.w + b2s[7] + gelu_exact(e1.w + pbs[7]);
    float* ob = ob0 + Yp + (size_t)(lk * 4) * NN;   // channel lk*4, + c*NN per channel
    ob[0]                 = r0;
    ob[(size_t)NN]        = r1;
    ob[(size_t)2 * NN]    = r2;
    ob[(size_t)3 * NN]    = r3;
    float* ob2 = ob + (size_t)16 * NN;
    ob2[0]                = r4;
    ob2[(size_t)NN]       = r5;
    ob2[(size_t)2 * NN]   = r6;
    ob2[(size_t)3 * NN]   = r7;
  }
}

// ------------------------- FALLBACK PATH (ws too small): R3's fused pos_out, proven
__global__ __launch_bounds__(320) void pos_out_kernel(
    const u16* __restrict__ vspec_g, const u16* __restrict__ wt1,
    const u16* __restrict__ wt2, const float* __restrict__ pos1b,
    const float* __restrict__ pos2b, const float* __restrict__ Mf,
    const float* __restrict__ projb, float* __restrict__ outp){
  __shared__ u16 vs[32 * 12 * 40];    // [i][vxl(12)][vyl(36,pad40)]
  __shared__ u16 tt[32 * 10 * 40];    // [o][txl(10)][tyl(34,pad40)]
  __shared__ u16 wsl[3072];           // one aw-slice: [ah][i][o]
  int t = threadIdx.x;
  int b = blockIdx.z;
  int x0 = blockIdx.x * 8, y0 = blockIdx.y * 32;
  int o = t & 31, xsl = t >> 5;       // xsl in [0,10)

  for (int p = t; p < 12 * 36; p += 320){
    int vxl = p / 36, vyl = p - vxl * 36;
    int X = x0 - 2 + vxl, Y = y0 - 2 + vyl;
    u16* dst = &vs[vxl * 40 + vyl];
    if (X >= 0 && X < NS && Y >= 0 && Y < NS){
      const uint4* src = (const uint4*)(vspec_g + ((size_t)b * NN + (size_t)Y * NS + X) * NC);
      uint4 u0 = src[0], u1 = src[1], u2 = src[2], u3 = src[3];
      alignas(16) u16 raw[32];
      *(uint4*)(raw) = u0; *(uint4*)(raw + 8) = u1;
      *(uint4*)(raw + 16) = u2; *(uint4*)(raw + 24) = u3;
      #pragma unroll
      for (int i = 0; i < 32; i++) dst[i * 480] = raw[i];
    } else {
      #pragma unroll
      for (int i = 0; i < 32; i++) dst[i * 480] = 0;
    }
  }
  __syncthreads();

  float ta[34];
  #pragma unroll
  for (int k = 0; k < 34; k++) ta[k] = 0.f;
  for (int aw = 0; aw < 3; aw++){
    for (int idx = t; idx < 3072; idx += 320) wsl[idx] = wt1[aw * 3072 + idx];
    __syncthreads();
    for (int i2 = 0; i2 < 32; i2++){
      const uint4* rp = (const uint4*)(vs + (i2 * 12 + xsl + aw) * 40);
      uint4 r0 = rp[0], r1 = rp[1], r2 = rp[2], r3 = rp[3], r4 = rp[4];
      float g[40];
      dec8(r0, g); dec8(r1, g + 8); dec8(r2, g + 16); dec8(r3, g + 24); dec8(r4, g + 32);
      float w0 = bf2f(wsl[i2 * 32 + o]);
      float w1 = bf2f(wsl[i2 * 32 + o + 1024]);
      float w2 = bf2f(wsl[i2 * 32 + o + 2048]);
      #pragma unroll
      for (int yl = 0; yl < 34; yl++)
        ta[yl] = fmaf(g[yl], w0, fmaf(g[yl + 1], w1, fmaf(g[yl + 2], w2, ta[yl])));
    }
    __syncthreads();
  }
  {
    float b1 = pos1b[o];
    int X = x0 - 1 + xsl;
    bool colOK = (X >= 0 && X < NS);
    u16* trow = &tt[(o * 10 + xsl) * 40];
    #pragma unroll
    for (int yl = 0; yl < 34; yl++){
      int Y = y0 - 1 + yl;
      float val = (colOK && Y >= 0 && Y < NS) ? gelu_exact(ta[yl] + b1) : 0.f;
      trow[yl] = f2bf(val);
    }
  }
  __syncthreads();

  float acc2[32];
  #pragma unroll
  for (int yy = 0; yy < 32; yy++) acc2[yy] = 0.f;
  for (int aw = 0; aw < 3; aw++){
    for (int idx = t; idx < 3072; idx += 320) wsl[idx] = wt2[aw * 3072 + idx];
    __syncthreads();
    if (xsl < 8){
      for (int i2 = 0; i2 < 32; i2++){
        const uint4* rp = (const uint4*)(tt + (i2 * 10 + xsl + aw) * 40);
        uint4 r0 = rp[0], r1 = rp[1], r2 = rp[2], r3 = rp[3], r4 = rp[4];
        float g[40];
        dec8(r0, g); dec8(r1, g + 8); dec8(r2, g + 16); dec8(r3, g + 24); dec8(r4, g + 32);
        float w0 = bf2f(wsl[i2 * 32 + o]);
        float w1 = bf2f(wsl[i2 * 32 + o + 1024]);
        float w2 = bf2f(wsl[i2 * 32 + o + 2048]);
        #pragma unroll
        for (int yy = 0; yy < 32; yy++)
          acc2[yy] = fmaf(g[yy], w0, fmaf(g[yy + 1], w1, fmaf(g[yy + 2], w2, acc2[yy])));
      }
    }
    __syncthreads();
  }
  if (xsl < 8){
    int x = x0 + xsl;
    float m[32];
    {
      const float4* mp = (const float4*)(Mf + b * 1024 + o * 32);
      #pragma unroll
      for (int k = 0; k < 8; k++){
        float4 f = mp[k];
        m[4 * k] = f.x; m[4 * k + 1] = f.y; m[4 * k + 2] = f.z; m[4 * k + 3] = f.w;
      }
    }
    float pb = projb[o];
    float b2v = pos2b[o];
    float outv[32];
    #pragma unroll
    for (int yy = 0; yy < 32; yy++){
      size_t n = (size_t)b * NN + (size_t)(y0 + yy) * NS + x;
      const uint4* xp = (const uint4*)(vspec_g + n * NC);
      uint4 u0 = xp[0], u1 = xp[1], u2 = xp[2], u3 = xp[3];
      float xr[32];
      dec8(u0, xr); dec8(u1, xr + 8); dec8(u2, xr + 16); dec8(u3, xr + 24);
      float s = pb;
      #pragma unroll
      for (int i2 = 0; i2 < 32; i2++) s += m[i2] * xr[i2];
      outv[yy] = acc2[yy] + b2v + gelu_exact(s);
    }
    float4* dp = (float4*)(outp + (((size_t)(b * 32 + o) * NS) + x) * NS + y0);
    #pragma unroll
    for (int k = 0; k < 8; k++)
      dp[k] = make_float4(outv[4 * k], outv[4 * k + 1], outv[4 * k + 2], outv[4 * k + 3]);
  }
}

// ---------------------------------------------------------------------- launch
extern "C" void kernel_launch(void* const* d_in, const int* in_sizes, int n_in,
                              void* d_out, int out_size, void* d_ws, size_t ws_size,
                              hipStream_t stream){
  (void)in_sizes; (void)n_in; (void)out_size;
  const float* xfu   = (const float*)d_in[0];
  const float* xmsi  = (const float*)d_in[1];
  const float* xhsi  = (const float*)d_in[2];
  const float* Wq    = (const float*)d_in[3];
  const float* Wk    = (const float*)d_in[4];
  const float* Wv    = (const float*)d_in[5];
  const float* projW = (const float*)d_in[6];
  const float* projb = (const float*)d_in[7];
  const float* pos1W = (const float*)d_in[8];
  const float* pos1b = (const float*)d_in[9];
  const float* pos2W = (const float*)d_in[10];
  const float* pos2b = (const float*)d_in[11];
  const float* cafc1 = (const float*)d_in[12];
  const float* cafc2 = (const float*)d_in[13];
  const float* sac1a = (const float*)d_in[14];
  const float* sac1b = (const float*)d_in[15];
  const float* sac2a = (const float*)d_in[16];
  const float* sac2b = (const float*)d_in[17];
  const float* sac3  = (const float*)d_in[18];
  const float* attnW = (const float*)d_in[19];

  float* out = (float*)d_out;
  float* out_main = out;                  // (b,c,w,h) 8388608 f32
  float* out_cm   = out + 8388608;        // 128
  float* out_sm   = out + 8388736;        // 262144

  // workspace map (R7): sums[0,512) S[1024,17408) cmask[17920] W1[18432] W2[20480]
  // Mf[28672,45056) wt1[45056] wt2[63488] wA1[81920] wA2[100352] Mbf[118784,126976)
  // vspec [131072,+16M), t/gv [+16M,+32M)  (gv aliases t_g: disjoint lifetimes)
  char* ws = (char*)d_ws;
  float* sums   = (float*)(ws + 0);         // 128 f (zeroed with S: 4352 f total)
  float* Sm     = (float*)(ws + 1024);      // 4096 f = [4][32][32]
  float* cmaskf = (float*)(ws + 17920);     // 128 f
  float* W1     = (float*)(ws + 18432);     // 288 f
  float* W2     = (float*)(ws + 20480);     // 1568 f
  float* Mf     = (float*)(ws + 28672);     // 4096 f
  u16*   wt1    = (u16*)(ws + 45056);       // 9216 bf16 [r][i][o] (fallback) / wAv (split)
  u16*   wt2    = (u16*)(ws + 63488);       // 9216 bf16
  u16*   wA1    = (u16*)(ws + 81920);       // 9216 bf16 [r][o][i] (MFMA)
  u16*   wA2    = (u16*)(ws + 100352);      // 9216 bf16
  u16*   Mbf    = (u16*)(ws + 118784);      // 4096 bf16 [b][o][i]
  u16*   vspec  = (u16*)(ws + 131072);      // 16 MB bf16 (b,n,c)
  u16*   t_g    = (u16*)(ws + 131072 + 16777216);   // 16 MB bf16 (split path only)
  const bool split = ws_size >= (size_t)(131072 + 2 * 16777216);
  u16*   wAv    = split ? wt1 : wA1;        // split: wt1 slot free; fallback: dummy
  u16*   gvbuf  = t_g;                      // gv dies before pos1 writes t_g

  pre_kernel<<<1, 256, 0, stream>>>(sac1a, sac1b, sac2a, sac2b, pos1W, pos2W, attnW,
                                    sums, W1, W2, wt1, wt2, wA1, wA2, wAv,
                                    split ? 0 : 1);
  channel_sum_kernel<<<256, 256, 0, stream>>>(xhsi, sums);
  spatial_mask_kernel<<<dim3(16, 16, NB), 256, 0, stream>>>(xmsi, W1, W2, sac3, out_sm);
  x2_kernel<<<1024, 256, 0, stream>>>(xfu, Sm);
  mid_kernel<<<1, 256, 0, stream>>>(sums, cafc1, cafc2, cmaskf, out_cm,
                                    Sm, Wq, Wk, projW, Mf, Mbf);
  if (split){
    vgate_kernel<<<512, 256, 0, stream>>>(xfu, Wv, out_sm, cmaskf, gvbuf);
    vconv_mfma_kernel<<<1024, 256, 0, stream>>>(gvbuf, wAv, xhsi, vspec);
    pos1_mfma_kernel<<<1024, 256, 0, stream>>>(vspec, wA1, pos1b, t_g);
    pos2_mfma_kernel<<<1024, 256, 0, stream>>>(t_g, vspec, wA2, pos2b, Mbf, projb, out_main);
  } else {
    vspec_kernel<<<dim3(32, 8, NB), 256, 0, stream>>>(
        xfu, Wv, attnW, out_sm, cmaskf, xhsi, vspec);
    pos_out_kernel<<<dim3(32, 8, NB), 320, 0, stream>>>(
        vspec, wt1, wt2, pos1b, pos2b, Mf, projb, out_main);
  }
}

// Round 6
// 501.078 us; speedup vs baseline: 1.2346x; 1.0134x over previous
//
#include <hip/hip_runtime.h>
#include <hip/hip_bf16.h>

// Self_mask_Spectral_MSA on MI355X — Round 9: x2_kernel ILP restructure.
// B=4, H=W=256, C=32, heads=4, d=8. f32 I/O, fp32 accumulation, bf16 intermediates.
//
// R9 changes vs R8 (passed, 507us, absmax 0.015625):
//  - x2_kernel (115us, VALUBusy 3.5%, VGPR_Count 32!) was load-latency-serialized:
//    compiler allocated minimal registers -> each of 5 loads/row waited full L2/L3
//    latency before its 4 FMAs. Fix: explicit 4-row load batching into named
//    registers (20 loads in flight, ~100 VGPR) then 64 FMAs. Same math, same
//    per-lane accumulation order (bit-identical). Grid/reduce/atomics unchanged.
//  - Everything else unchanged from R8.

#define NB 4
#define NC 32
#define NS 256
#define NN 65536

typedef unsigned short u16;
typedef unsigned int u32;
typedef __bf16 bf16x8 __attribute__((ext_vector_type(8)));
typedef float f32x4 __attribute__((ext_vector_type(4)));

__device__ __forceinline__ float bf2f(u16 s){ return __uint_as_float(((u32)s) << 16); }
__device__ __forceinline__ u16 f2bf(float x){
  u32 u = __float_as_uint(x);
  u32 r = (u + 0x7fffu + ((u >> 16) & 1u)) >> 16;   // RNE
  return (u16)r;
}
__device__ __forceinline__ void dec8(uint4 u, float* f){
  f[0] = __uint_as_float((u.x & 0xffffu) << 16);
  f[1] = __uint_as_float(u.x & 0xffff0000u);
  f[2] = __uint_as_float((u.y & 0xffffu) << 16);
  f[3] = __uint_as_float(u.y & 0xffff0000u);
  f[4] = __uint_as_float((u.z & 0xffffu) << 16);
  f[5] = __uint_as_float(u.z & 0xffff0000u);
  f[6] = __uint_as_float((u.w & 0xffffu) << 16);
  f[7] = __uint_as_float(u.w & 0xffff0000u);
}
__device__ __forceinline__ void ld32f(const float* __restrict__ p, float* x){
  const float4* q = (const float4*)p;
  #pragma unroll
  for (int k = 0; k < 8; k++){
    float4 f = q[k];
    x[4 * k] = f.x; x[4 * k + 1] = f.y; x[4 * k + 2] = f.z; x[4 * k + 3] = f.w;
  }
}
__device__ __forceinline__ uint4 pack8(const float* f){
  uint4 u;
  u.x = (u32)f2bf(f[0]) | ((u32)f2bf(f[1]) << 16);
  u.y = (u32)f2bf(f[2]) | ((u32)f2bf(f[3]) << 16);
  u.z = (u32)f2bf(f[4]) | ((u32)f2bf(f[5]) << 16);
  u.w = (u32)f2bf(f[6]) | ((u32)f2bf(f[7]) << 16);
  return u;
}
__device__ __forceinline__ float gelu_exact(float x){
  return 0.5f * x * (1.0f + erff(x * 0.70710678118654752f));
}
__device__ __forceinline__ float sigmoidf_(float x){ return 1.0f / (1.0f + expf(-x)); }

// ---------------------- pre: zero accumulators + fold SA weights + transpose pos weights
__global__ __launch_bounds__(256) void pre_kernel(
    const float* __restrict__ c1a, const float* __restrict__ c1b,
    const float* __restrict__ c2a, const float* __restrict__ c2b,
    const float* __restrict__ p1, const float* __restrict__ p2,
    const float* __restrict__ aw,
    float* __restrict__ zbase, float* __restrict__ W1, float* __restrict__ W2,
    u16* __restrict__ wt1, u16* __restrict__ wt2,
    u16* __restrict__ wA1, u16* __restrict__ wA2,
    u16* __restrict__ wAv, int fb){
  int t = threadIdx.x;
  for (int i = t; i < 4352; i += 256) zbase[i] = 0.f;          // sums(128) + S(4096 @ +256)
  for (int idx = t; idx < 288; idx += 256){                    // W1[r*32+j]
    int r = idx >> 5, j = idx & 31;
    float s = 0.f;
    for (int i = 0; i < 32; i++) s += c1b[i] * c1a[(i * 32 + j) * 9 + r];
    W1[idx] = s;
  }
  for (int idx = t; idx < 1568; idx += 256){                   // W2[r*32+j]
    int r = idx >> 5, j = idx & 31;
    float s = 0.f;
    for (int i = 0; i < 32; i++) s += c2b[i] * c2a[(i * 32 + j) * 49 + r];
    W2[idx] = s;
  }
  for (int idx = t; idx < 9216; idx += 256){                   // OIHW -> layouts
    int o = idx / 288;
    int rem = idx - o * 288;
    int i = rem / 9;
    int r = rem - i * 9;
    u16 w1v = f2bf(p1[idx]);
    u16 w2v = f2bf(p2[idx]);
    if (fb){
      wt1[(r * 32 + i) * 32 + o] = w1v;    // [r][i][o]  (fallback path only)
      wt2[(r * 32 + i) * 32 + o] = w2v;
    }
    wA1[(r * 32 + o) * 32 + i] = w1v;      // [r][o][i]  (MFMA A-fragments)
    wA2[(r * 32 + o) * 32 + i] = w2v;
    wAv[(r * 32 + o) * 32 + i] = f2bf(aw[idx]);
  }
}

// ---------------------------------------------------------------- channel sums
__global__ __launch_bounds__(256) void channel_sum_kernel(const float* __restrict__ xhsi,
                                                          float* __restrict__ sums){
  int b = blockIdx.x >> 6;
  int blk = blockIdx.x & 63;
  const float* p = xhsi + (size_t)b * NN * NC;
  int t = threadIdx.x;
  int base = blk * 32768;
  float acc = 0.f;
  for (int k = 0; k < 128; k++) acc += p[base + t + k * 256];
  __shared__ float red[256];
  red[t] = acc;
  __syncthreads();
  if (t < 32){
    float s = 0.f;
    #pragma unroll
    for (int k = 0; k < 8; k++) s += red[t + k * 32];     // channel of red[j] is j&31
    atomicAdd(&sums[b * 32 + t], s);
  }
}

// -------------------------------- R7/R9: S = X^T X per batch (second-moment matrix)
// Lane owns 16 entries: o = lane&31, e = (lane>>5)*16 + j. 64 rows per wave.
// R9: 4-row load batches into named registers -> 20 loads in flight, latency hidden.
__global__ __launch_bounds__(256) void x2_kernel(const float* __restrict__ xfu,
                                                 float* __restrict__ S){
  int t = threadIdx.x;
  int wv = t >> 6, l = t & 63;
  int o = l & 31, ebase = (l >> 5) * 16;
  int b = blockIdx.x >> 8;                       // 256 blocks per batch
  const float* rp = xfu + (size_t)(blockIdx.x * 256 + wv * 64) * NC;
  float acc[16];
  #pragma unroll
  for (int j = 0; j < 16; j++) acc[j] = 0.f;
  for (int r0 = 0; r0 < 64; r0 += 4){
    float sc0, sc1, sc2, sc3;
    float4 e00, e01, e02, e03, e10, e11, e12, e13;
    float4 e20, e21, e22, e23, e30, e31, e32, e33;
    {
      const float* row = rp + (r0 + 0) * NC;
      const float4* ep = (const float4*)(row + ebase);
      sc0 = row[o]; e00 = ep[0]; e01 = ep[1]; e02 = ep[2]; e03 = ep[3];
    }
    {
      const float* row = rp + (r0 + 1) * NC;
      const float4* ep = (const float4*)(row + ebase);
      sc1 = row[o]; e10 = ep[0]; e11 = ep[1]; e12 = ep[2]; e13 = ep[3];
    }
    {
      const float* row = rp + (r0 + 2) * NC;
      const float4* ep = (const float4*)(row + ebase);
      sc2 = row[o]; e20 = ep[0]; e21 = ep[1]; e22 = ep[2]; e23 = ep[3];
    }
    {
      const float* row = rp + (r0 + 3) * NC;
      const float4* ep = (const float4*)(row + ebase);
      sc3 = row[o]; e30 = ep[0]; e31 = ep[1]; e32 = ep[2]; e33 = ep[3];
    }
    acc[0]  += sc0 * e00.x; acc[1]  += sc0 * e00.y; acc[2]  += sc0 * e00.z; acc[3]  += sc0 * e00.w;
    acc[4]  += sc0 * e01.x; acc[5]  += sc0 * e01.y; acc[6]  += sc0 * e01.z; acc[7]  += sc0 * e01.w;
    acc[8]  += sc0 * e02.x; acc[9]  += sc0 * e02.y; acc[10] += sc0 * e02.z; acc[11] += sc0 * e02.w;
    acc[12] += sc0 * e03.x; acc[13] += sc0 * e03.y; acc[14] += sc0 * e03.z; acc[15] += sc0 * e03.w;
    acc[0]  += sc1 * e10.x; acc[1]  += sc1 * e10.y; acc[2]  += sc1 * e10.z; acc[3]  += sc1 * e10.w;
    acc[4]  += sc1 * e11.x; acc[5]  += sc1 * e11.y; acc[6]  += sc1 * e11.z; acc[7]  += sc1 * e11.w;
    acc[8]  += sc1 * e12.x; acc[9]  += sc1 * e12.y; acc[10] += sc1 * e12.z; acc[11] += sc1 * e12.w;
    acc[12] += sc1 * e13.x; acc[13] += sc1 * e13.y; acc[14] += sc1 * e13.z; acc[15] += sc1 * e13.w;
    acc[0]  += sc2 * e20.x; acc[1]  += sc2 * e20.y; acc[2]  += sc2 * e20.z; acc[3]  += sc2 * e20.w;
    acc[4]  += sc2 * e21.x; acc[5]  += sc2 * e21.y; acc[6]  += sc2 * e21.z; acc[7]  += sc2 * e21.w;
    acc[8]  += sc2 * e22.x; acc[9]  += sc2 * e22.y; acc[10] += sc2 * e22.z; acc[11] += sc2 * e22.w;
    acc[12] += sc2 * e23.x; acc[13] += sc2 * e23.y; acc[14] += sc2 * e23.z; acc[15] += sc2 * e23.w;
    acc[0]  += sc3 * e30.x; acc[1]  += sc3 * e30.y; acc[2]  += sc3 * e30.z; acc[3]  += sc3 * e30.w;
    acc[4]  += sc3 * e31.x; acc[5]  += sc3 * e31.y; acc[6]  += sc3 * e31.z; acc[7]  += sc3 * e31.w;
    acc[8]  += sc3 * e32.x; acc[9]  += sc3 * e32.y; acc[10] += sc3 * e32.z; acc[11] += sc3 * e32.w;
    acc[12] += sc3 * e33.x; acc[13] += sc3 * e33.y; acc[14] += sc3 * e33.z; acc[15] += sc3 * e33.w;
  }
  __shared__ float red[4][64][17];               // pad 17: spread write banks
  #pragma unroll
  for (int j = 0; j < 16; j++) red[wv][l][j] = acc[j];
  __syncthreads();
  #pragma unroll
  for (int k = 0; k < 4; k++){
    int idx = t * 4 + k;
    int ll = idx >> 4, j = idx & 15;
    float s = red[0][ll][j] + red[1][ll][j] + red[2][ll][j] + red[3][ll][j];
    int oo = ll & 31, eb = (ll >> 5) * 16;
    atomicAdd(&S[b * 1024 + oo * 32 + eb + j], s);
  }
}

// --- mid: channel mask (sigmoid MLP) + attention softmax from S + M fold
// R8: all stride-32 LDS arrays padded to 33 (bank-conflict fix).
__global__ __launch_bounds__(256) void mid_kernel(
    const float* __restrict__ sums, const float* __restrict__ fc1,
    const float* __restrict__ fc2, float* __restrict__ cmaskf, float* __restrict__ out_cm,
    const float* __restrict__ S, const float* __restrict__ Wq, const float* __restrict__ Wk,
    const float* __restrict__ projW, float* __restrict__ Mf, u16* __restrict__ Mbf){
  __shared__ float avg[NB][NC], hid[NB][NC];
  __shared__ float attn_s[16][65];
  __shared__ float Wqs[32][33], Wks[32][33];
  __shared__ float Ss[4][32][33];
  __shared__ float Ts[4][32][33], Us[4][32][33];
  __shared__ float nq2[4][32], nk2[4][32];
  int t = threadIdx.x;
  for (int idx = t; idx < 1024; idx += 256){
    Wqs[idx >> 5][idx & 31] = Wq[idx];
    Wks[idx >> 5][idx & 31] = Wk[idx];
  }
  for (int idx = t; idx < 4096; idx += 256)
    Ss[idx >> 10][(idx >> 5) & 31][idx & 31] = S[idx];
  if (t < 128){
    int b = t >> 5, o = t & 31;
    avg[b][o] = sums[t] * (1.0f / 65536.0f);
  }
  __syncthreads();
  // T = S·Wq^T, U = S·Wk^T  (T[b][i][c] = sum_j S[b][i][j]·Wq[c][j])
  for (int idx = t; idx < 8192; idx += 256){
    int which = idx >> 12;
    int b = (idx >> 10) & 3, i = (idx >> 5) & 31, c = idx & 31;
    const float* wrow = which ? &Wks[c][0] : &Wqs[c][0];
    const float* srow = &Ss[b][i][0];
    float s = 0.f;
    #pragma unroll
    for (int j = 0; j < 32; j++) s += srow[j] * wrow[j];
    if (which) Us[b][i][c] = s; else Ts[b][i][c] = s;
  }
  if (t < 128){
    int b = t >> 5, o = t & 31;
    float s = 0.f;
    for (int j = 0; j < 32; j++) s += fc1[o * 32 + j] * avg[b][j];
    hid[b][o] = fmaxf(s, 0.f);
  }
  __syncthreads();
  // norms: ||q_c||^2 = Wq_c·T[:,c], ||k_o||^2 = Wk_o·U[:,o]
  if (t < 128){
    int b = t >> 5, c = t & 31;
    float sq = 0.f, sk = 0.f;
    #pragma unroll
    for (int i = 0; i < 32; i++){
      sq += Wqs[c][i] * Ts[b][i][c];
      sk += Wks[c][i] * Us[b][i][c];
    }
    nq2[b][c] = sq; nk2[b][c] = sk;
  }
  __syncthreads();
  // softmax over normalized gram; G[o][c] = Wk_o · T[:,c]
  if (t < 128){
    int bh = t >> 3, d = t & 7;   // bh = b*4+h
    int b = bh >> 2, h = bh & 3;
    int o = h * 8 + d;
    float nk = fmaxf(sqrtf(nk2[b][o]), 1e-12f);
    float l[8];
    float mx = -1e30f;
    #pragma unroll
    for (int e = 0; e < 8; e++){
      int c = h * 8 + e;
      float G = 0.f;
      #pragma unroll
      for (int i = 0; i < 32; i++) G += Wks[o][i] * Ts[b][i][c];
      float nq = fmaxf(sqrtf(nq2[b][c]), 1e-12f);
      l[e] = G / (nk * nq);
      mx = fmaxf(mx, l[e]);
    }
    float se = 0.f;
    #pragma unroll
    for (int e = 0; e < 8; e++){ l[e] = expf(l[e] - mx); se += l[e]; }
    float inv = 1.f / se;
    #pragma unroll
    for (int e = 0; e < 8; e++) attn_s[bh][d * 8 + e] = l[e] * inv;
  }
  if (t < 128){
    int b = t >> 5, o = t & 31;
    float s2 = 0.f;
    for (int i = 0; i < 32; i++) s2 += fc2[o * 32 + i] * hid[b][i];
    float m = sigmoidf_(s2);
    cmaskf[t] = m;
    out_cm[t] = m;
  }
  __syncthreads();
  for (int idx = t; idx < 4096; idx += 256){        // M[b][o][i]
    int b = idx >> 10, o = (idx >> 5) & 31, i = idx & 31;
    int hd = i >> 3, e = i & 7;
    float s = 0.f;
    #pragma unroll
    for (int d = 0; d < 8; d++)
      s += projW[o * 32 + hd * 8 + d] * attn_s[b * 4 + hd][d * 8 + e];
    Mf[idx] = s;
    Mbf[idx] = f2bf(s);
  }
}

// tile: [c8][xl][yl] uint4 (8 bf16 channels per uint4). 16x16 output px, halo 3.
__global__ __launch_bounds__(256) void spatial_mask_kernel(
    const float* __restrict__ xmsi, const float* __restrict__ W1, const float* __restrict__ W2,
    const float* __restrict__ sac3, float* __restrict__ out_sm){
  __shared__ uint4 tile[4][22][25];
  __shared__ float W1s[9 * 32], W2s[49 * 32];
  int t = threadIdx.x;
  int b = blockIdx.z;
  int x0 = blockIdx.x * 16, y0 = blockIdx.y * 16;
  for (int idx = t; idx < 9 * 32;  idx += 256) W1s[idx] = W1[idx];
  for (int idx = t; idx < 49 * 32; idx += 256) W2s[idx] = W2[idx];
  for (int p = t; p < 484; p += 256){
    int xl = p / 22, yl = p - xl * 22;
    int X = x0 - 3 + xl, Y = y0 - 3 + yl;
    uint4 u0, u1, u2, u3;
    if (X >= 0 && X < NS && Y >= 0 && Y < NS){
      float xr[32];
      ld32f(xmsi + ((size_t)b * NN + (size_t)Y * NS + X) * NC, xr);
      u0 = pack8(xr); u1 = pack8(xr + 8); u2 = pack8(xr + 16); u3 = pack8(xr + 24);
    } else {
      u0 = u1 = u2 = u3 = make_uint4(0, 0, 0, 0);
    }
    tile[0][xl][yl] = u0; tile[1][xl][yl] = u1; tile[2][xl][yl] = u2; tile[3][xl][yl] = u3;
  }
  __syncthreads();
  int j = t & 15, i = t >> 4;     // j: y (h), i: x (w)
  float m1 = 0.f, m2 = 0.f;
  for (int aw = 0; aw < 7; aw++){
    for (int ah = 0; ah < 7; ah++){
      const float* wr = &W2s[(aw * 7 + ah) * 32];
      float s = 0.f;
      #pragma unroll
      for (int c = 0; c < 4; c++){
        uint4 u = tile[c][i + aw][j + ah];
        float g[8]; dec8(u, g);
        #pragma unroll
        for (int k = 0; k < 8; k++) s += g[k] * wr[c * 8 + k];
      }
      m2 += s;
    }
  }
  for (int aw = 0; aw < 3; aw++){
    for (int ah = 0; ah < 3; ah++){
      const float* wr = &W1s[(aw * 3 + ah) * 32];
      float s = 0.f;
      #pragma unroll
      for (int c = 0; c < 4; c++){
        uint4 u = tile[c][i + aw + 2][j + ah + 2];
        float g[8]; dec8(u, g);
        #pragma unroll
        for (int k = 0; k < 8; k++) s += g[k] * wr[c * 8 + k];
      }
      m1 += s;
    }
  }
  float m = sac3[0] * m1 + sac3[1] * m2;
  float sg = sigmoidf_(m);
  int x = x0 + i, y = y0 + j;
  out_sm[(size_t)b * NN + (size_t)x * NS + y] = sg;   // (b,1,w,h): w-major
}

// ----------------------- R6 SPLIT: vgate — f32 V-proj + gate, 2 px/thread, no halo
__global__ __launch_bounds__(256) void vgate_kernel(
    const float* __restrict__ xfu, const float* __restrict__ Wv,
    const float* __restrict__ out_sm, const float* __restrict__ cmaskf,
    u16* __restrict__ gv){
  __shared__ alignas(16) float WvL[1024];       // [i][o]
  __shared__ float cml[NC];
  int t = threadIdx.x;
  int b = blockIdx.x >> 7;                      // 512 blocks: 128 per batch, 2 rows each
  int px0 = blockIdx.x * 512 + t;               // (X = t, Y = 2*(blk&127))
  int px1 = px0 + 256;                          // (X = t, Y+1)
  int X = t;
  int Y0 = (px0 >> 8) & 255;

  for (int idx = t; idx < 1024; idx += 256){
    int oo = idx >> 5, ii = idx & 31;
    WvL[ii * 32 + oo] = Wv[idx];                // Wv[o][i] -> [i][o]
  }
  if (t < 32) cml[t] = cmaskf[b * 32 + t];
  __syncthreads();

  float xr0[32], xr1[32];
  ld32f(xfu + (size_t)px0 * NC, xr0);
  ld32f(xfu + (size_t)px1 * NC, xr1);
  float sm0 = out_sm[(size_t)b * NN + (size_t)X * NS + Y0];
  float sm1 = out_sm[(size_t)b * NN + (size_t)X * NS + Y0 + 1];

  float vo0[32], vo1[32];
  #pragma unroll
  for (int q = 0; q < 32; q++){ vo0[q] = 0.f; vo1[q] = 0.f; }
  for (int i = 0; i < 32; i++){
    const float4* wr = (const float4*)&WvL[i * 32];
    float a0 = xr0[i], a1 = xr1[i];
    #pragma unroll
    for (int q = 0; q < 8; q++){
      float4 w4 = wr[q];
      vo0[4 * q]     += a0 * w4.x;  vo1[4 * q]     += a1 * w4.x;
      vo0[4 * q + 1] += a0 * w4.y;  vo1[4 * q + 1] += a1 * w4.y;
      vo0[4 * q + 2] += a0 * w4.z;  vo1[4 * q + 2] += a1 * w4.z;
      vo0[4 * q + 3] += a0 * w4.w;  vo1[4 * q + 3] += a1 * w4.w;
    }
  }
  float g0[32], g1[32];
  #pragma unroll
  for (int c = 0; c < 32; c++){
    float cm = cml[c];
    g0[c] = vo0[c] * sm0 * cm;
    g1[c] = vo1[c] * sm1 * cm;
  }
  uint4* d0 = (uint4*)(gv + (size_t)px0 * NC);
  uint4* d1 = (uint4*)(gv + (size_t)px1 * NC);
  d0[0] = pack8(g0);  d0[1] = pack8(g0 + 8);  d0[2] = pack8(g0 + 16);  d0[3] = pack8(g0 + 24);
  d1[0] = pack8(g1);  d1[1] = pack8(g1 + 8);  d1[2] = pack8(g1 + 16);  d1[3] = pack8(g1 + 24);
}

// ------------------- R6 SPLIT: vconv — pos1-pattern MFMA conv3x3 + xhsi residual
__global__ __launch_bounds__(256) void vconv_mfma_kernel(
    const u16* __restrict__ gv, const u16* __restrict__ wAv,
    const float* __restrict__ xhsi, u16* __restrict__ vspec_g){
  int t = threadIdx.x;
  int wv = t >> 6, l = t & 63;
  int lp = l & 15, lk = l >> 4;                 // fragment pixel / k-chunk
  int b = blockIdx.x >> 8, Y = blockIdx.x & 255;

  bf16x8 wf[9][2];
  #pragma unroll
  for (int r = 0; r < 9; r++){
    wf[r][0] = *(const bf16x8*)(wAv + ((r * 32 + lp) * 32 + lk * 8));
    wf[r][1] = *(const bf16x8*)(wAv + ((r * 32 + 16 + lp) * 32 + lk * 8));
  }

  const u16* src = gv + (size_t)b * NN * NC;
  const float* res = xhsi + (size_t)b * NN * NC;
  u16* dst = vspec_g + (size_t)b * NN * NC;

  for (int g = 0; g < 4; g++){
    int X0 = wv * 64 + g * 16;
    f32x4 acc0 = {0.f, 0.f, 0.f, 0.f};
    f32x4 acc1 = {0.f, 0.f, 0.f, 0.f};
    #pragma unroll
    for (int dh = -1; dh <= 1; dh++){
      int Yi = Y + dh;
      if ((unsigned)Yi < NS){                   // uniform skip = zero-pad rows
        const u16* row = src + (size_t)Yi * (NS * NC) + lk * 8;
        #pragma unroll
        for (int dw = -1; dw <= 1; dw++){
          int Xi = X0 + lp + dw;
          uint4 u = make_uint4(0, 0, 0, 0);
          if (dw == 0 || (unsigned)Xi < NS) u = *(const uint4*)(row + Xi * NC);
          bf16x8 bfr = __builtin_bit_cast(bf16x8, u);
          const int r = (dw + 1) * 3 + (dh + 1);
          acc0 = __builtin_amdgcn_mfma_f32_16x16x32_bf16(wf[r][0], bfr, acc0, 0, 0, 0);
          acc1 = __builtin_amdgcn_mfma_f32_16x16x32_bf16(wf[r][1], bfr, acc1, 0, 0, 0);
        }
      }
    }
    // D: col=lp=pixel, rows = lk*4+j (+16 for tile 1) = out channel; + residual
    size_t n = (size_t)Y * NS + (X0 + lp);
    float4 rA = *(const float4*)(res + n * NC + lk * 4);
    float4 rB = *(const float4*)(res + n * NC + lk * 4 + 16);
    float v0 = acc0.x + rA.x;
    float v1 = acc0.y + rA.y;
    float v2 = acc0.z + rA.z;
    float v3 = acc0.w + rA.w;
    float v4 = acc1.x + rB.x;
    float v5 = acc1.y + rB.y;
    float v6 = acc1.z + rB.z;
    float v7 = acc1.w + rB.w;
    u16* dp = dst + n * NC + lk * 4;
    *(uint2*)dp = make_uint2((u32)f2bf(v0) | ((u32)f2bf(v1) << 16),
                             (u32)f2bf(v2) | ((u32)f2bf(v3) << 16));
    *(uint2*)(dp + 16) = make_uint2((u32)f2bf(v4) | ((u32)f2bf(v5) << 16),
                                    (u32)f2bf(v6) | ((u32)f2bf(v7) << 16));
  }
}

// ---------------- FALLBACK: fused V-proj + gate + conv + residual (R4, proven)
__global__ __launch_bounds__(256) void vspec_kernel(
    const float* __restrict__ xfu, const float* __restrict__ Wv,
    const float* __restrict__ attnW, const float* __restrict__ out_sm,
    const float* __restrict__ cmaskf, const float* __restrict__ xhsi,
    u16* __restrict__ vspec_g){
  __shared__ u16 gv[32 * 10 * 40];              // [c][xl][yl(34,pad40)] gated v, bf16
  __shared__ u16 Wl[9 * 32 * 32];               // [r][i][o] bf16, r = aw*3+ah
  __shared__ alignas(16) float WvL[1024];       // [i][o]
  __shared__ float cml[32];
  int t = threadIdx.x;
  int b = blockIdx.z;
  int x0 = blockIdx.x * 8, y0 = blockIdx.y * 32;

  for (int idx = t; idx < 1024; idx += 256){
    int oo = idx >> 5, ii = idx & 31;
    WvL[ii * 32 + oo] = Wv[idx];                // Wv[o][i] -> [i][o]
  }
  if (t < 32) cml[t] = cmaskf[b * 32 + t];
  __syncthreads();

  for (int idx = t; idx < 9216; idx += 256){
    int oo = idx / 288;
    int rem = idx - oo * 288;
    int ii = rem / 9;
    int r = rem - ii * 9;
    Wl[(r * 32 + ii) * 32 + oo] = f2bf(attnW[idx]);
  }
  for (int p = t; p < 340; p += 256){           // 10 x 34 halo tile
    int xl = p / 34, yl = p - xl * 34;
    int X = x0 - 1 + xl, Y = y0 - 1 + yl;       // X: w, Y: h
    u16* dst = &gv[xl * 40 + yl];               // + c*400 per channel
    if (X >= 0 && X < NS && Y >= 0 && Y < NS){
      float xr[32];
      ld32f(xfu + ((size_t)b * NN + (size_t)Y * NS + X) * NC, xr);
      float sm = out_sm[(size_t)b * NN + (size_t)X * NS + Y];
      float vo[32];
      #pragma unroll
      for (int q = 0; q < 32; q++) vo[q] = 0.f;
      for (int i = 0; i < 32; i++){
        const float4* wr = (const float4*)&WvL[i * 32];
        float xv = xr[i];
        #pragma unroll
        for (int q = 0; q < 8; q++){
          float4 w4 = wr[q];
          vo[4 * q]     += xv * w4.x;
          vo[4 * q + 1] += xv * w4.y;
          vo[4 * q + 2] += xv * w4.z;
          vo[4 * q + 3] += xv * w4.w;
        }
      }
      #pragma unroll
      for (int c = 0; c < 32; c++) dst[c * 400] = f2bf(vo[c] * sm * cml[c]);
    } else {
      #pragma unroll
      for (int c = 0; c < 32; c++) dst[c * 400] = 0;
    }
  }
  __syncthreads();

  int o = t & 31, xs = t >> 5;
  float acc[32];
  #pragma unroll
  for (int yy = 0; yy < 32; yy++) acc[yy] = 0.f;
  #pragma unroll
  for (int aw = 0; aw < 3; aw++){
    for (int i2 = 0; i2 < 32; i2++){
      const uint4* rp = (const uint4*)(gv + (i2 * 10 + xs + aw) * 40);
      uint4 r0 = rp[0], r1 = rp[1], r2 = rp[2], r3 = rp[3], r4 = rp[4];
      float g[40];
      dec8(r0, g); dec8(r1, g + 8); dec8(r2, g + 16); dec8(r3, g + 24); dec8(r4, g + 32);
      const int wb = (aw * 3 * 32 + i2) * 32 + o;
      float w0 = bf2f(Wl[wb]);
      float w1 = bf2f(Wl[wb + 1024]);
      float w2 = bf2f(Wl[wb + 2048]);
      #pragma unroll
      for (int yy = 0; yy < 32; yy++)
        acc[yy] = fmaf(g[yy], w0, fmaf(g[yy + 1], w1, fmaf(g[yy + 2], w2, acc[yy])));
    }
  }
  int x = x0 + xs;
  #pragma unroll
  for (int yy = 0; yy < 32; yy++){
    size_t n = (size_t)b * NN + (size_t)(y0 + yy) * NS + x;
    vspec_g[n * NC + o] = f2bf(acc[yy] + xhsi[n * NC + o]);
  }
}

// ------------------------- SPLIT PATH R5: MFMA pos1 (vspec -> t), no LDS
// Wave handles 4 groups of 16 consecutive X at fixed Y. A=W[r][o][i], B=vspec px.
__global__ __launch_bounds__(256) void pos1_mfma_kernel(
    const u16* __restrict__ vspec_g, const u16* __restrict__ wA,
    const float* __restrict__ pos1b, u16* __restrict__ t_g){
  int t = threadIdx.x;
  int wv = t >> 6, l = t & 63;
  int lp = l & 15, lk = l >> 4;                 // fragment pixel / k-chunk
  int b = blockIdx.x >> 8, Y = blockIdx.x & 255;

  bf16x8 wf[9][2];
  #pragma unroll
  for (int r = 0; r < 9; r++){
    wf[r][0] = *(const bf16x8*)(wA + ((r * 32 + lp) * 32 + lk * 8));
    wf[r][1] = *(const bf16x8*)(wA + ((r * 32 + 16 + lp) * 32 + lk * 8));
  }
  float bs[8];
  #pragma unroll
  for (int j = 0; j < 4; j++){
    bs[j]     = pos1b[lk * 4 + j];
    bs[4 + j] = pos1b[16 + lk * 4 + j];
  }

  const u16* src = vspec_g + (size_t)b * NN * NC;
  u16* dst = t_g + (size_t)b * NN * NC;

  for (int g = 0; g < 4; g++){
    int X0 = wv * 64 + g * 16;
    f32x4 acc0 = {0.f, 0.f, 0.f, 0.f};
    f32x4 acc1 = {0.f, 0.f, 0.f, 0.f};
    #pragma unroll
    for (int dh = -1; dh <= 1; dh++){
      int Yi = Y + dh;
      if ((unsigned)Yi < NS){                   // uniform skip = zero-pad rows
        const u16* row = src + (size_t)Yi * (NS * NC) + lk * 8;
        #pragma unroll
        for (int dw = -1; dw <= 1; dw++){
          int Xi = X0 + lp + dw;
          uint4 u = make_uint4(0, 0, 0, 0);
          if (dw == 0 || (unsigned)Xi < NS) u = *(const uint4*)(row + Xi * NC);
          bf16x8 bfr = __builtin_bit_cast(bf16x8, u);
          const int r = (dw + 1) * 3 + (dh + 1);
          acc0 = __builtin_amdgcn_mfma_f32_16x16x32_bf16(wf[r][0], bfr, acc0, 0, 0, 0);
          acc1 = __builtin_amdgcn_mfma_f32_16x16x32_bf16(wf[r][1], bfr, acc1, 0, 0, 0);
        }
      }
    }
    // D: col=lp=pixel, rows = lk*4+j (+16 for tile 1) = out channel
    float v0 = gelu_exact(acc0.x + bs[0]);
    float v1 = gelu_exact(acc0.y + bs[1]);
    float v2 = gelu_exact(acc0.z + bs[2]);
    float v3 = gelu_exact(acc0.w + bs[3]);
    float v4 = gelu_exact(acc1.x + bs[4]);
    float v5 = gelu_exact(acc1.y + bs[5]);
    float v6 = gelu_exact(acc1.z + bs[6]);
    float v7 = gelu_exact(acc1.w + bs[7]);
    u16* dp = dst + ((size_t)Y * NS + (X0 + lp)) * NC + lk * 4;
    *(uint2*)dp = make_uint2((u32)f2bf(v0) | ((u32)f2bf(v1) << 16),
                             (u32)f2bf(v2) | ((u32)f2bf(v3) << 16));
    *(uint2*)(dp + 16) = make_uint2((u32)f2bf(v4) | ((u32)f2bf(v5) << 16),
                                    (u32)f2bf(v6) | ((u32)f2bf(v7) << 16));
  }
}

// -------------------- SPLIT PATH R5: MFMA pos2 (t -> out, + out1 epilogue), no LDS
// Wave handles 4 groups of 16 consecutive Y at fixed X (store (b,c,w,h) coalesced in h).
__global__ __launch_bounds__(256) void pos2_mfma_kernel(
    const u16* __restrict__ t_g, const u16* __restrict__ vspec_g,
    const u16* __restrict__ wA, const float* __restrict__ pos2b,
    const u16* __restrict__ Mbf, const float* __restrict__ projb,
    float* __restrict__ outp){
  int t = threadIdx.x;
  int wv = t >> 6, l = t & 63;
  int lp = l & 15, lk = l >> 4;
  int b = blockIdx.x >> 8, X = blockIdx.x & 255;

  bf16x8 wf[9][2];
  #pragma unroll
  for (int r = 0; r < 9; r++){
    wf[r][0] = *(const bf16x8*)(wA + ((r * 32 + lp) * 32 + lk * 8));
    wf[r][1] = *(const bf16x8*)(wA + ((r * 32 + 16 + lp) * 32 + lk * 8));
  }
  bf16x8 mf0 = *(const bf16x8*)(Mbf + ((b * 32 + lp) * 32 + lk * 8));
  bf16x8 mf1 = *(const bf16x8*)(Mbf + ((b * 32 + 16 + lp) * 32 + lk * 8));
  float b2s[8], pbs[8];
  #pragma unroll
  for (int j = 0; j < 4; j++){
    b2s[j]     = pos2b[lk * 4 + j];
    b2s[4 + j] = pos2b[16 + lk * 4 + j];
    pbs[j]     = projb[lk * 4 + j];
    pbs[4 + j] = projb[16 + lk * 4 + j];
  }

  const u16* tsrc = t_g + (size_t)b * NN * NC;
  const u16* vsrc = vspec_g + (size_t)b * NN * NC;
  float* ob0 = outp + (size_t)b * 32 * NN + (size_t)X * NS;

  for (int g = 0; g < 4; g++){
    int Y0 = wv * 64 + g * 16;
    int Yp = Y0 + lp;
    // epilogue GEMM first (independent chain): P = M @ vspec[px]
    f32x4 e0 = {0.f, 0.f, 0.f, 0.f};
    f32x4 e1 = {0.f, 0.f, 0.f, 0.f};
    {
      uint4 u = *(const uint4*)(vsrc + ((size_t)Yp * NS + X) * NC + lk * 8);
      bf16x8 bfr = __builtin_bit_cast(bf16x8, u);
      e0 = __builtin_amdgcn_mfma_f32_16x16x32_bf16(mf0, bfr, e0, 0, 0, 0);
      e1 = __builtin_amdgcn_mfma_f32_16x16x32_bf16(mf1, bfr, e1, 0, 0, 0);
    }
    f32x4 acc0 = {0.f, 0.f, 0.f, 0.f};
    f32x4 acc1 = {0.f, 0.f, 0.f, 0.f};
    #pragma unroll
    for (int dw = -1; dw <= 1; dw++){
      int Xi = X + dw;
      if ((unsigned)Xi < NS){                   // uniform skip = zero-pad cols
        const u16* col = tsrc + (size_t)Xi * NC + lk * 8;
        #pragma unroll
        for (int dh = -1; dh <= 1; dh++){
          int Yi = Yp + dh;
          uint4 u = make_uint4(0, 0, 0, 0);
          if (dh == 0 || (unsigned)Yi < NS) u = *(const uint4*)(col + (size_t)Yi * (NS * NC));
          bf16x8 bfr = __builtin_bit_cast(bf16x8, u);
          const int r = (dw + 1) * 3 + (dh + 1);
          acc0 = __builtin_amdgcn_mfma_f32_16x16x32_bf16(wf[r][0], bfr, acc0, 0, 0, 0);
          acc1 = __builtin_amdgcn_mfma_f32_16x16x32_bf16(wf[r][1], bfr, acc1, 0, 0, 0);
        }
      }
    }
    float r0 = acc0.x + b2s[0] + gelu_exact(e0.x + pbs[0]);
    float r1 = acc0.y + b2s[1] + gelu_exact(e0.y + pbs[1]);
    float r2 = acc0.z + b2s[2] + gelu_exact(e0.z + pbs[2]);
    float r3 = acc0.w + b2s[3] + gelu_exact(e0.w + pbs[3]);
    float r4 = acc1.x + b2s[4] + gelu_exact(e1.x + pbs[4]);
    float r5 = acc1.y + b2s[5] + gelu_exact(e1.y + pbs[5]);
    float r6 = acc1.z + b2s[6] + gelu_exact(e1.z + pbs[6]);
    float r7 = acc1.w + b2s[7] + gelu_exact(e1.w + pbs[7]);
    float* ob = ob0 + Yp + (size_t)(lk * 4) * NN;   // channel lk*4, + c*NN per channel
    ob[0]                 = r0;
    ob[(size_t)NN]        = r1;
    ob[(size_t)2 * NN]    = r2;
    ob[(size_t)3 * NN]    = r3;
    float* ob2 = ob + (size_t)16 * NN;
    ob2[0]                = r4;
    ob2[(size_t)NN]       = r5;
    ob2[(size_t)2 * NN]   = r6;
    ob2[(size_t)3 * NN]   = r7;
  }
}

// ------------------------- FALLBACK PATH (ws too small): R3's fused pos_out, proven
__global__ __launch_bounds__(320) void pos_out_kernel(
    const u16* __restrict__ vspec_g, const u16* __restrict__ wt1,
    const u16* __restrict__ wt2, const float* __restrict__ pos1b,
    const float* __restrict__ pos2b, const float* __restrict__ Mf,
    const float* __restrict__ projb, float* __restrict__ outp){
  __shared__ u16 vs[32 * 12 * 40];    // [i][vxl(12)][vyl(36,pad40)]
  __shared__ u16 tt[32 * 10 * 40];    // [o][txl(10)][tyl(34,pad40)]
  __shared__ u16 wsl[3072];           // one aw-slice: [ah][i][o]
  int t = threadIdx.x;
  int b = blockIdx.z;
  int x0 = blockIdx.x * 8, y0 = blockIdx.y * 32;
  int o = t & 31, xsl = t >> 5;       // xsl in [0,10)

  for (int p = t; p < 12 * 36; p += 320){
    int vxl = p / 36, vyl = p - vxl * 36;
    int X = x0 - 2 + vxl, Y = y0 - 2 + vyl;
    u16* dst = &vs[vxl * 40 + vyl];
    if (X >= 0 && X < NS && Y >= 0 && Y < NS){
      const uint4* src = (const uint4*)(vspec_g + ((size_t)b * NN + (size_t)Y * NS + X) * NC);
      uint4 u0 = src[0], u1 = src[1], u2 = src[2], u3 = src[3];
      alignas(16) u16 raw[32];
      *(uint4*)(raw) = u0; *(uint4*)(raw + 8) = u1;
      *(uint4*)(raw + 16) = u2; *(uint4*)(raw + 24) = u3;
      #pragma unroll
      for (int i = 0; i < 32; i++) dst[i * 480] = raw[i];
    } else {
      #pragma unroll
      for (int i = 0; i < 32; i++) dst[i * 480] = 0;
    }
  }
  __syncthreads();

  float ta[34];
  #pragma unroll
  for (int k = 0; k < 34; k++) ta[k] = 0.f;
  for (int aw = 0; aw < 3; aw++){
    for (int idx = t; idx < 3072; idx += 320) wsl[idx] = wt1[aw * 3072 + idx];
    __syncthreads();
    for (int i2 = 0; i2 < 32; i2++){
      const uint4* rp = (const uint4*)(vs + (i2 * 12 + xsl + aw) * 40);
      uint4 r0 = rp[0], r1 = rp[1], r2 = rp[2], r3 = rp[3], r4 = rp[4];
      float g[40];
      dec8(r0, g); dec8(r1, g + 8); dec8(r2, g + 16); dec8(r3, g + 24); dec8(r4, g + 32);
      float w0 = bf2f(wsl[i2 * 32 + o]);
      float w1 = bf2f(wsl[i2 * 32 + o + 1024]);
      float w2 = bf2f(wsl[i2 * 32 + o + 2048]);
      #pragma unroll
      for (int yl = 0; yl < 34; yl++)
        ta[yl] = fmaf(g[yl], w0, fmaf(g[yl + 1], w1, fmaf(g[yl + 2], w2, ta[yl])));
    }
    __syncthreads();
  }
  {
    float b1 = pos1b[o];
    int X = x0 - 1 + xsl;
    bool colOK = (X >= 0 && X < NS);
    u16* trow = &tt[(o * 10 + xsl) * 40];
    #pragma unroll
    for (int yl = 0; yl < 34; yl++){
      int Y = y0 - 1 + yl;
      float val = (colOK && Y >= 0 && Y < NS) ? gelu_exact(ta[yl] + b1) : 0.f;
      trow[yl] = f2bf(val);
    }
  }
  __syncthreads();

  float acc2[32];
  #pragma unroll
  for (int yy = 0; yy < 32; yy++) acc2[yy] = 0.f;
  for (int aw = 0; aw < 3; aw++){
    for (int idx = t; idx < 3072; idx += 320) wsl[idx] = wt2[aw * 3072 + idx];
    __syncthreads();
    if (xsl < 8){
      for (int i2 = 0; i2 < 32; i2++){
        const uint4* rp = (const uint4*)(tt + (i2 * 10 + xsl + aw) * 40);
        uint4 r0 = rp[0], r1 = rp[1], r2 = rp[2], r3 = rp[3], r4 = rp[4];
        float g[40];
        dec8(r0, g); dec8(r1, g + 8); dec8(r2, g + 16); dec8(r3, g + 24); dec8(r4, g + 32);
        float w0 = bf2f(wsl[i2 * 32 + o]);
        float w1 = bf2f(wsl[i2 * 32 + o + 1024]);
        float w2 = bf2f(wsl[i2 * 32 + o + 2048]);
        #pragma unroll
        for (int yy = 0; yy < 32; yy++)
          acc2[yy] = fmaf(g[yy], w0, fmaf(g[yy + 1], w1, fmaf(g[yy + 2], w2, acc2[yy])));
      }
    }
    __syncthreads();
  }
  if (xsl < 8){
    int x = x0 + xsl;
    float m[32];
    {
      const float4* mp = (const float4*)(Mf + b * 1024 + o * 32);
      #pragma unroll
      for (int k = 0; k < 8; k++){
        float4 f = mp[k];
        m[4 * k] = f.x; m[4 * k + 1] = f.y; m[4 * k + 2] = f.z; m[4 * k + 3] = f.w;
      }
    }
    float pb = projb[o];
    float b2v = pos2b[o];
    float outv[32];
    #pragma unroll
    for (int yy = 0; yy < 32; yy++){
      size_t n = (size_t)b * NN + (size_t)(y0 + yy) * NS + x;
      const uint4* xp = (const uint4*)(vspec_g + n * NC);
      uint4 u0 = xp[0], u1 = xp[1], u2 = xp[2], u3 = xp[3];
      float xr[32];
      dec8(u0, xr); dec8(u1, xr + 8); dec8(u2, xr + 16); dec8(u3, xr + 24);
      float s = pb;
      #pragma unroll
      for (int i2 = 0; i2 < 32; i2++) s += m[i2] * xr[i2];
      outv[yy] = acc2[yy] + b2v + gelu_exact(s);
    }
    float4* dp = (float4*)(outp + (((size_t)(b * 32 + o) * NS) + x) * NS + y0);
    #pragma unroll
    for (int k = 0; k < 8; k++)
      dp[k] = make_float4(outv[4 * k], outv[4 * k + 1], outv[4 * k + 2], outv[4 * k + 3]);
  }
}

// ---------------------------------------------------------------------- launch
extern "C" void kernel_launch(void* const* d_in, const int* in_sizes, int n_in,
                              void* d_out, int out_size, void* d_ws, size_t ws_size,
                              hipStream_t stream){
  (void)in_sizes; (void)n_in; (void)out_size;
  const float* xfu   = (const float*)d_in[0];
  const float* xmsi  = (const float*)d_in[1];
  const float* xhsi  = (const float*)d_in[2];
  const float* Wq    = (const float*)d_in[3];
  const float* Wk    = (const float*)d_in[4];
  const float* Wv    = (const float*)d_in[5];
  const float* projW = (const float*)d_in[6];
  const float* projb = (const float*)d_in[7];
  const float* pos1W = (const float*)d_in[8];
  const float* pos1b = (const float*)d_in[9];
  const float* pos2W = (const float*)d_in[10];
  const float* pos2b = (const float*)d_in[11];
  const float* cafc1 = (const float*)d_in[12];
  const float* cafc2 = (const float*)d_in[13];
  const float* sac1a = (const float*)d_in[14];
  const float* sac1b = (const float*)d_in[15];
  const float* sac2a = (const float*)d_in[16];
  const float* sac2b = (const float*)d_in[17];
  const float* sac3  = (const float*)d_in[18];
  const float* attnW = (const float*)d_in[19];

  float* out = (float*)d_out;
  float* out_main = out;                  // (b,c,w,h) 8388608 f32
  float* out_cm   = out + 8388608;        // 128
  float* out_sm   = out + 8388736;        // 262144

  // workspace map (R7): sums[0,512) S[1024,17408) cmask[17920] W1[18432] W2[20480]
  // Mf[28672,45056) wt1[45056] wt2[63488] wA1[81920] wA2[100352] Mbf[118784,126976)
  // vspec [131072,+16M), t/gv [+16M,+32M)  (gv aliases t_g: disjoint lifetimes)
  char* ws = (char*)d_ws;
  float* sums   = (float*)(ws + 0);         // 128 f (zeroed with S: 4352 f total)
  float* Sm     = (float*)(ws + 1024);      // 4096 f = [4][32][32]
  float* cmaskf = (float*)(ws + 17920);     // 128 f
  float* W1     = (float*)(ws + 18432);     // 288 f
  float* W2     = (float*)(ws + 20480);     // 1568 f
  float* Mf     = (float*)(ws + 28672);     // 4096 f
  u16*   wt1    = (u16*)(ws + 45056);       // 9216 bf16 [r][i][o] (fallback) / wAv (split)
  u16*   wt2    = (u16*)(ws + 63488);       // 9216 bf16
  u16*   wA1    = (u16*)(ws + 81920);       // 9216 bf16 [r][o][i] (MFMA)
  u16*   wA2    = (u16*)(ws + 100352);      // 9216 bf16
  u16*   Mbf    = (u16*)(ws + 118784);      // 4096 bf16 [b][o][i]
  u16*   vspec  = (u16*)(ws + 131072);      // 16 MB bf16 (b,n,c)
  u16*   t_g    = (u16*)(ws + 131072 + 16777216);   // 16 MB bf16 (split path only)
  const bool split = ws_size >= (size_t)(131072 + 2 * 16777216);
  u16*   wAv    = split ? wt1 : wA1;        // split: wt1 slot free; fallback: dummy
  u16*   gvbuf  = t_g;                      // gv dies before pos1 writes t_g

  pre_kernel<<<1, 256, 0, stream>>>(sac1a, sac1b, sac2a, sac2b, pos1W, pos2W, attnW,
                                    sums, W1, W2, wt1, wt2, wA1, wA2, wAv,
                                    split ? 0 : 1);
  channel_sum_kernel<<<256, 256, 0, stream>>>(xhsi, sums);
  spatial_mask_kernel<<<dim3(16, 16, NB), 256, 0, stream>>>(xmsi, W1, W2, sac3, out_sm);
  x2_kernel<<<1024, 256, 0, stream>>>(xfu, Sm);
  mid_kernel<<<1, 256, 0, stream>>>(sums, cafc1, cafc2, cmaskf, out_cm,
                                    Sm, Wq, Wk, projW, Mf, Mbf);
  if (split){
    vgate_kernel<<<512, 256, 0, stream>>>(xfu, Wv, out_sm, cmaskf, gvbuf);
    vconv_mfma_kernel<<<1024, 256, 0, stream>>>(gvbuf, wAv, xhsi, vspec);
    pos1_mfma_kernel<<<1024, 256, 0, stream>>>(vspec, wA1, pos1b, t_g);
    pos2_mfma_kernel<<<1024, 256, 0, stream>>>(t_g, vspec, wA2, pos2b, Mbf, projb, out_main);
  } else {
    vspec_kernel<<<dim3(32, 8, NB), 256, 0, stream>>>(
        xfu, Wv, attnW, out_sm, cmaskf, xhsi, vspec);
    pos_out_kernel<<<dim3(32, 8, NB), 320, 0, stream>>>(
        vspec, wt1, wt2, pos1b, pos2b, Mf, projb, out_main);
  }
}

// Round 7
// 469.694 us; speedup vs baseline: 1.3171x; 1.0668x over previous
//
#include <hip/hip_runtime.h>
#include <hip/hip_bf16.h>

// Self_mask_Spectral_MSA on MI355X — Round 10: x2_kernel via LDS staging.
// B=4, H=W=256, C=32, heads=4, d=8. f32 I/O, fp32 accumulation, bf16 intermediates.
//
// R10 changes vs R9 (passed, 501us; x2 still 100us, VGPR_Count STILL 32):
//  - R9 post-mortem: the compiler SANK the named-register batch loads back to
//    just-before-use (legal), keeping VGPR=32 and a ~700cyc-latency serial chain:
//    320 loads x 700cyc = 93us — matches measurement. Source-level ILP via named
//    registers is not binding; scheduler re-sinks under its pressure heuristic.
//  - Fix: stage the block's 256-row chunk (32KB) in LDS (dword-interleaved,
//    coalesced, conflict-free), then run the identical FMA sequence reading LDS
//    (broadcast reads, conflict-free; lgkmcnt-pipelined, ~12cyc/b128 throughput).
//    Bit-identical accumulation order. Reduce/atomics unchanged. LDS 50KB.
//  - Everything else unchanged from R9.

#define NB 4
#define NC 32
#define NS 256
#define NN 65536

typedef unsigned short u16;
typedef unsigned int u32;
typedef __bf16 bf16x8 __attribute__((ext_vector_type(8)));
typedef float f32x4 __attribute__((ext_vector_type(4)));

__device__ __forceinline__ float bf2f(u16 s){ return __uint_as_float(((u32)s) << 16); }
__device__ __forceinline__ u16 f2bf(float x){
  u32 u = __float_as_uint(x);
  u32 r = (u + 0x7fffu + ((u >> 16) & 1u)) >> 16;   // RNE
  return (u16)r;
}
__device__ __forceinline__ void dec8(uint4 u, float* f){
  f[0] = __uint_as_float((u.x & 0xffffu) << 16);
  f[1] = __uint_as_float(u.x & 0xffff0000u);
  f[2] = __uint_as_float((u.y & 0xffffu) << 16);
  f[3] = __uint_as_float(u.y & 0xffff0000u);
  f[4] = __uint_as_float((u.z & 0xffffu) << 16);
  f[5] = __uint_as_float(u.z & 0xffff0000u);
  f[6] = __uint_as_float((u.w & 0xffffu) << 16);
  f[7] = __uint_as_float(u.w & 0xffff0000u);
}
__device__ __forceinline__ void ld32f(const float* __restrict__ p, float* x){
  const float4* q = (const float4*)p;
  #pragma unroll
  for (int k = 0; k < 8; k++){
    float4 f = q[k];
    x[4 * k] = f.x; x[4 * k + 1] = f.y; x[4 * k + 2] = f.z; x[4 * k + 3] = f.w;
  }
}
__device__ __forceinline__ uint4 pack8(const float* f){
  uint4 u;
  u.x = (u32)f2bf(f[0]) | ((u32)f2bf(f[1]) << 16);
  u.y = (u32)f2bf(f[2]) | ((u32)f2bf(f[3]) << 16);
  u.z = (u32)f2bf(f[4]) | ((u32)f2bf(f[5]) << 16);
  u.w = (u32)f2bf(f[6]) | ((u32)f2bf(f[7]) << 16);
  return u;
}
__device__ __forceinline__ float gelu_exact(float x){
  return 0.5f * x * (1.0f + erff(x * 0.70710678118654752f));
}
__device__ __forceinline__ float sigmoidf_(float x){ return 1.0f / (1.0f + expf(-x)); }

// ---------------------- pre: zero accumulators + fold SA weights + transpose pos weights
__global__ __launch_bounds__(256) void pre_kernel(
    const float* __restrict__ c1a, const float* __restrict__ c1b,
    const float* __restrict__ c2a, const float* __restrict__ c2b,
    const float* __restrict__ p1, const float* __restrict__ p2,
    const float* __restrict__ aw,
    float* __restrict__ zbase, float* __restrict__ W1, float* __restrict__ W2,
    u16* __restrict__ wt1, u16* __restrict__ wt2,
    u16* __restrict__ wA1, u16* __restrict__ wA2,
    u16* __restrict__ wAv, int fb){
  int t = threadIdx.x;
  for (int i = t; i < 4352; i += 256) zbase[i] = 0.f;          // sums(128) + S(4096 @ +256)
  for (int idx = t; idx < 288; idx += 256){                    // W1[r*32+j]
    int r = idx >> 5, j = idx & 31;
    float s = 0.f;
    for (int i = 0; i < 32; i++) s += c1b[i] * c1a[(i * 32 + j) * 9 + r];
    W1[idx] = s;
  }
  for (int idx = t; idx < 1568; idx += 256){                   // W2[r*32+j]
    int r = idx >> 5, j = idx & 31;
    float s = 0.f;
    for (int i = 0; i < 32; i++) s += c2b[i] * c2a[(i * 32 + j) * 49 + r];
    W2[idx] = s;
  }
  for (int idx = t; idx < 9216; idx += 256){                   // OIHW -> layouts
    int o = idx / 288;
    int rem = idx - o * 288;
    int i = rem / 9;
    int r = rem - i * 9;
    u16 w1v = f2bf(p1[idx]);
    u16 w2v = f2bf(p2[idx]);
    if (fb){
      wt1[(r * 32 + i) * 32 + o] = w1v;    // [r][i][o]  (fallback path only)
      wt2[(r * 32 + i) * 32 + o] = w2v;
    }
    wA1[(r * 32 + o) * 32 + i] = w1v;      // [r][o][i]  (MFMA A-fragments)
    wA2[(r * 32 + o) * 32 + i] = w2v;
    wAv[(r * 32 + o) * 32 + i] = f2bf(aw[idx]);
  }
}

// ---------------------------------------------------------------- channel sums
__global__ __launch_bounds__(256) void channel_sum_kernel(const float* __restrict__ xhsi,
                                                          float* __restrict__ sums){
  int b = blockIdx.x >> 6;
  int blk = blockIdx.x & 63;
  const float* p = xhsi + (size_t)b * NN * NC;
  int t = threadIdx.x;
  int base = blk * 32768;
  float acc = 0.f;
  for (int k = 0; k < 128; k++) acc += p[base + t + k * 256];
  __shared__ float red[256];
  red[t] = acc;
  __syncthreads();
  if (t < 32){
    float s = 0.f;
    #pragma unroll
    for (int k = 0; k < 8; k++) s += red[t + k * 32];     // channel of red[j] is j&31
    atomicAdd(&sums[b * 32 + t], s);
  }
}

// ------------------- R7/R10: S = X^T X per batch (second-moment matrix), LDS-staged
// Lane owns 16 entries: o = lane&31, e = (lane>>5)*16 + j. 64 rows per wave.
// R10: stage the 256-row chunk in LDS first (coalesced, conflict-free), then the
// FMA loop reads LDS (broadcasts, lgkmcnt-pipelined) — no long-latency serial chain.
__global__ __launch_bounds__(256) void x2_kernel(const float* __restrict__ xfu,
                                                 float* __restrict__ S){
  __shared__ float xs[256 * NC];                 // 32KB: [row][ch]
  __shared__ float red[4][64][17];               // pad 17: spread write banks
  int t = threadIdx.x;
  int b = blockIdx.x >> 8;                       // 256 blocks per batch
  const float* src = xfu + (size_t)blockIdx.x * 256 * NC;
  #pragma unroll
  for (int j = 0; j < 32; j++) xs[t + j * 256] = src[t + j * 256];
  __syncthreads();

  int wv = t >> 6, l = t & 63;
  int o = l & 31, ebase = (l >> 5) * 16;
  const float* rp = xs + wv * 64 * NC;
  float acc[16];
  #pragma unroll
  for (int j = 0; j < 16; j++) acc[j] = 0.f;
  #pragma unroll 4
  for (int r = 0; r < 64; r++){
    const float* row = rp + r * NC;
    float xo = row[o];
    const float4* ep = (const float4*)(row + ebase);
    float4 e0 = ep[0], e1 = ep[1], e2 = ep[2], e3 = ep[3];
    acc[0]  += xo * e0.x; acc[1]  += xo * e0.y; acc[2]  += xo * e0.z; acc[3]  += xo * e0.w;
    acc[4]  += xo * e1.x; acc[5]  += xo * e1.y; acc[6]  += xo * e1.z; acc[7]  += xo * e1.w;
    acc[8]  += xo * e2.x; acc[9]  += xo * e2.y; acc[10] += xo * e2.z; acc[11] += xo * e2.w;
    acc[12] += xo * e3.x; acc[13] += xo * e3.y; acc[14] += xo * e3.z; acc[15] += xo * e3.w;
  }
  __syncthreads();                               // xs dead; reuse barrier before red
  #pragma unroll
  for (int j = 0; j < 16; j++) red[wv][l][j] = acc[j];
  __syncthreads();
  #pragma unroll
  for (int k = 0; k < 4; k++){
    int idx = t * 4 + k;
    int ll = idx >> 4, j = idx & 15;
    float s = red[0][ll][j] + red[1][ll][j] + red[2][ll][j] + red[3][ll][j];
    int oo = ll & 31, eb = (ll >> 5) * 16;
    atomicAdd(&S[b * 1024 + oo * 32 + eb + j], s);
  }
}

// --- mid: channel mask (sigmoid MLP) + attention softmax from S + M fold
// R8: all stride-32 LDS arrays padded to 33 (bank-conflict fix).
__global__ __launch_bounds__(256) void mid_kernel(
    const float* __restrict__ sums, const float* __restrict__ fc1,
    const float* __restrict__ fc2, float* __restrict__ cmaskf, float* __restrict__ out_cm,
    const float* __restrict__ S, const float* __restrict__ Wq, const float* __restrict__ Wk,
    const float* __restrict__ projW, float* __restrict__ Mf, u16* __restrict__ Mbf){
  __shared__ float avg[NB][NC], hid[NB][NC];
  __shared__ float attn_s[16][65];
  __shared__ float Wqs[32][33], Wks[32][33];
  __shared__ float Ss[4][32][33];
  __shared__ float Ts[4][32][33], Us[4][32][33];
  __shared__ float nq2[4][32], nk2[4][32];
  int t = threadIdx.x;
  for (int idx = t; idx < 1024; idx += 256){
    Wqs[idx >> 5][idx & 31] = Wq[idx];
    Wks[idx >> 5][idx & 31] = Wk[idx];
  }
  for (int idx = t; idx < 4096; idx += 256)
    Ss[idx >> 10][(idx >> 5) & 31][idx & 31] = S[idx];
  if (t < 128){
    int b = t >> 5, o = t & 31;
    avg[b][o] = sums[t] * (1.0f / 65536.0f);
  }
  __syncthreads();
  // T = S·Wq^T, U = S·Wk^T  (T[b][i][c] = sum_j S[b][i][j]·Wq[c][j])
  for (int idx = t; idx < 8192; idx += 256){
    int which = idx >> 12;
    int b = (idx >> 10) & 3, i = (idx >> 5) & 31, c = idx & 31;
    const float* wrow = which ? &Wks[c][0] : &Wqs[c][0];
    const float* srow = &Ss[b][i][0];
    float s = 0.f;
    #pragma unroll
    for (int j = 0; j < 32; j++) s += srow[j] * wrow[j];
    if (which) Us[b][i][c] = s; else Ts[b][i][c] = s;
  }
  if (t < 128){
    int b = t >> 5, o = t & 31;
    float s = 0.f;
    for (int j = 0; j < 32; j++) s += fc1[o * 32 + j] * avg[b][j];
    hid[b][o] = fmaxf(s, 0.f);
  }
  __syncthreads();
  // norms: ||q_c||^2 = Wq_c·T[:,c], ||k_o||^2 = Wk_o·U[:,o]
  if (t < 128){
    int b = t >> 5, c = t & 31;
    float sq = 0.f, sk = 0.f;
    #pragma unroll
    for (int i = 0; i < 32; i++){
      sq += Wqs[c][i] * Ts[b][i][c];
      sk += Wks[c][i] * Us[b][i][c];
    }
    nq2[b][c] = sq; nk2[b][c] = sk;
  }
  __syncthreads();
  // softmax over normalized gram; G[o][c] = Wk_o · T[:,c]
  if (t < 128){
    int bh = t >> 3, d = t & 7;   // bh = b*4+h
    int b = bh >> 2, h = bh & 3;
    int o = h * 8 + d;
    float nk = fmaxf(sqrtf(nk2[b][o]), 1e-12f);
    float l[8];
    float mx = -1e30f;
    #pragma unroll
    for (int e = 0; e < 8; e++){
      int c = h * 8 + e;
      float G = 0.f;
      #pragma unroll
      for (int i = 0; i < 32; i++) G += Wks[o][i] * Ts[b][i][c];
      float nq = fmaxf(sqrtf(nq2[b][c]), 1e-12f);
      l[e] = G / (nk * nq);
      mx = fmaxf(mx, l[e]);
    }
    float se = 0.f;
    #pragma unroll
    for (int e = 0; e < 8; e++){ l[e] = expf(l[e] - mx); se += l[e]; }
    float inv = 1.f / se;
    #pragma unroll
    for (int e = 0; e < 8; e++) attn_s[bh][d * 8 + e] = l[e] * inv;
  }
  if (t < 128){
    int b = t >> 5, o = t & 31;
    float s2 = 0.f;
    for (int i = 0; i < 32; i++) s2 += fc2[o * 32 + i] * hid[b][i];
    float m = sigmoidf_(s2);
    cmaskf[t] = m;
    out_cm[t] = m;
  }
  __syncthreads();
  for (int idx = t; idx < 4096; idx += 256){        // M[b][o][i]
    int b = idx >> 10, o = (idx >> 5) & 31, i = idx & 31;
    int hd = i >> 3, e = i & 7;
    float s = 0.f;
    #pragma unroll
    for (int d = 0; d < 8; d++)
      s += projW[o * 32 + hd * 8 + d] * attn_s[b * 4 + hd][d * 8 + e];
    Mf[idx] = s;
    Mbf[idx] = f2bf(s);
  }
}

// tile: [c8][xl][yl] uint4 (8 bf16 channels per uint4). 16x16 output px, halo 3.
__global__ __launch_bounds__(256) void spatial_mask_kernel(
    const float* __restrict__ xmsi, const float* __restrict__ W1, const float* __restrict__ W2,
    const float* __restrict__ sac3, float* __restrict__ out_sm){
  __shared__ uint4 tile[4][22][25];
  __shared__ float W1s[9 * 32], W2s[49 * 32];
  int t = threadIdx.x;
  int b = blockIdx.z;
  int x0 = blockIdx.x * 16, y0 = blockIdx.y * 16;
  for (int idx = t; idx < 9 * 32;  idx += 256) W1s[idx] = W1[idx];
  for (int idx = t; idx < 49 * 32; idx += 256) W2s[idx] = W2[idx];
  for (int p = t; p < 484; p += 256){
    int xl = p / 22, yl = p - xl * 22;
    int X = x0 - 3 + xl, Y = y0 - 3 + yl;
    uint4 u0, u1, u2, u3;
    if (X >= 0 && X < NS && Y >= 0 && Y < NS){
      float xr[32];
      ld32f(xmsi + ((size_t)b * NN + (size_t)Y * NS + X) * NC, xr);
      u0 = pack8(xr); u1 = pack8(xr + 8); u2 = pack8(xr + 16); u3 = pack8(xr + 24);
    } else {
      u0 = u1 = u2 = u3 = make_uint4(0, 0, 0, 0);
    }
    tile[0][xl][yl] = u0; tile[1][xl][yl] = u1; tile[2][xl][yl] = u2; tile[3][xl][yl] = u3;
  }
  __syncthreads();
  int j = t & 15, i = t >> 4;     // j: y (h), i: x (w)
  float m1 = 0.f, m2 = 0.f;
  for (int aw = 0; aw < 7; aw++){
    for (int ah = 0; ah < 7; ah++){
      const float* wr = &W2s[(aw * 7 + ah) * 32];
      float s = 0.f;
      #pragma unroll
      for (int c = 0; c < 4; c++){
        uint4 u = tile[c][i + aw][j + ah];
        float g[8]; dec8(u, g);
        #pragma unroll
        for (int k = 0; k < 8; k++) s += g[k] * wr[c * 8 + k];
      }
      m2 += s;
    }
  }
  for (int aw = 0; aw < 3; aw++){
    for (int ah = 0; ah < 3; ah++){
      const float* wr = &W1s[(aw * 3 + ah) * 32];
      float s = 0.f;
      #pragma unroll
      for (int c = 0; c < 4; c++){
        uint4 u = tile[c][i + aw + 2][j + ah + 2];
        float g[8]; dec8(u, g);
        #pragma unroll
        for (int k = 0; k < 8; k++) s += g[k] * wr[c * 8 + k];
      }
      m1 += s;
    }
  }
  float m = sac3[0] * m1 + sac3[1] * m2;
  float sg = sigmoidf_(m);
  int x = x0 + i, y = y0 + j;
  out_sm[(size_t)b * NN + (size_t)x * NS + y] = sg;   // (b,1,w,h): w-major
}

// ----------------------- R6 SPLIT: vgate — f32 V-proj + gate, 2 px/thread, no halo
__global__ __launch_bounds__(256) void vgate_kernel(
    const float* __restrict__ xfu, const float* __restrict__ Wv,
    const float* __restrict__ out_sm, const float* __restrict__ cmaskf,
    u16* __restrict__ gv){
  __shared__ alignas(16) float WvL[1024];       // [i][o]
  __shared__ float cml[NC];
  int t = threadIdx.x;
  int b = blockIdx.x >> 7;                      // 512 blocks: 128 per batch, 2 rows each
  int px0 = blockIdx.x * 512 + t;               // (X = t, Y = 2*(blk&127))
  int px1 = px0 + 256;                          // (X = t, Y+1)
  int X = t;
  int Y0 = (px0 >> 8) & 255;

  for (int idx = t; idx < 1024; idx += 256){
    int oo = idx >> 5, ii = idx & 31;
    WvL[ii * 32 + oo] = Wv[idx];                // Wv[o][i] -> [i][o]
  }
  if (t < 32) cml[t] = cmaskf[b * 32 + t];
  __syncthreads();

  float xr0[32], xr1[32];
  ld32f(xfu + (size_t)px0 * NC, xr0);
  ld32f(xfu + (size_t)px1 * NC, xr1);
  float sm0 = out_sm[(size_t)b * NN + (size_t)X * NS + Y0];
  float sm1 = out_sm[(size_t)b * NN + (size_t)X * NS + Y0 + 1];

  float vo0[32], vo1[32];
  #pragma unroll
  for (int q = 0; q < 32; q++){ vo0[q] = 0.f; vo1[q] = 0.f; }
  for (int i = 0; i < 32; i++){
    const float4* wr = (const float4*)&WvL[i * 32];
    float a0 = xr0[i], a1 = xr1[i];
    #pragma unroll
    for (int q = 0; q < 8; q++){
      float4 w4 = wr[q];
      vo0[4 * q]     += a0 * w4.x;  vo1[4 * q]     += a1 * w4.x;
      vo0[4 * q + 1] += a0 * w4.y;  vo1[4 * q + 1] += a1 * w4.y;
      vo0[4 * q + 2] += a0 * w4.z;  vo1[4 * q + 2] += a1 * w4.z;
      vo0[4 * q + 3] += a0 * w4.w;  vo1[4 * q + 3] += a1 * w4.w;
    }
  }
  float g0[32], g1[32];
  #pragma unroll
  for (int c = 0; c < 32; c++){
    float cm = cml[c];
    g0[c] = vo0[c] * sm0 * cm;
    g1[c] = vo1[c] * sm1 * cm;
  }
  uint4* d0 = (uint4*)(gv + (size_t)px0 * NC);
  uint4* d1 = (uint4*)(gv + (size_t)px1 * NC);
  d0[0] = pack8(g0);  d0[1] = pack8(g0 + 8);  d0[2] = pack8(g0 + 16);  d0[3] = pack8(g0 + 24);
  d1[0] = pack8(g1);  d1[1] = pack8(g1 + 8);  d1[2] = pack8(g1 + 16);  d1[3] = pack8(g1 + 24);
}

// ------------------- R6 SPLIT: vconv — pos1-pattern MFMA conv3x3 + xhsi residual
__global__ __launch_bounds__(256) void vconv_mfma_kernel(
    const u16* __restrict__ gv, const u16* __restrict__ wAv,
    const float* __restrict__ xhsi, u16* __restrict__ vspec_g){
  int t = threadIdx.x;
  int wv = t >> 6, l = t & 63;
  int lp = l & 15, lk = l >> 4;                 // fragment pixel / k-chunk
  int b = blockIdx.x >> 8, Y = blockIdx.x & 255;

  bf16x8 wf[9][2];
  #pragma unroll
  for (int r = 0; r < 9; r++){
    wf[r][0] = *(const bf16x8*)(wAv + ((r * 32 + lp) * 32 + lk * 8));
    wf[r][1] = *(const bf16x8*)(wAv + ((r * 32 + 16 + lp) * 32 + lk * 8));
  }

  const u16* src = gv + (size_t)b * NN * NC;
  const float* res = xhsi + (size_t)b * NN * NC;
  u16* dst = vspec_g + (size_t)b * NN * NC;

  for (int g = 0; g < 4; g++){
    int X0 = wv * 64 + g * 16;
    f32x4 acc0 = {0.f, 0.f, 0.f, 0.f};
    f32x4 acc1 = {0.f, 0.f, 0.f, 0.f};
    #pragma unroll
    for (int dh = -1; dh <= 1; dh++){
      int Yi = Y + dh;
      if ((unsigned)Yi < NS){                   // uniform skip = zero-pad rows
        const u16* row = src + (size_t)Yi * (NS * NC) + lk * 8;
        #pragma unroll
        for (int dw = -1; dw <= 1; dw++){
          int Xi = X0 + lp + dw;
          uint4 u = make_uint4(0, 0, 0, 0);
          if (dw == 0 || (unsigned)Xi < NS) u = *(const uint4*)(row + Xi * NC);
          bf16x8 bfr = __builtin_bit_cast(bf16x8, u);
          const int r = (dw + 1) * 3 + (dh + 1);
          acc0 = __builtin_amdgcn_mfma_f32_16x16x32_bf16(wf[r][0], bfr, acc0, 0, 0, 0);
          acc1 = __builtin_amdgcn_mfma_f32_16x16x32_bf16(wf[r][1], bfr, acc1, 0, 0, 0);
        }
      }
    }
    // D: col=lp=pixel, rows = lk*4+j (+16 for tile 1) = out channel; + residual
    size_t n = (size_t)Y * NS + (X0 + lp);
    float4 rA = *(const float4*)(res + n * NC + lk * 4);
    float4 rB = *(const float4*)(res + n * NC + lk * 4 + 16);
    float v0 = acc0.x + rA.x;
    float v1 = acc0.y + rA.y;
    float v2 = acc0.z + rA.z;
    float v3 = acc0.w + rA.w;
    float v4 = acc1.x + rB.x;
    float v5 = acc1.y + rB.y;
    float v6 = acc1.z + rB.z;
    float v7 = acc1.w + rB.w;
    u16* dp = dst + n * NC + lk * 4;
    *(uint2*)dp = make_uint2((u32)f2bf(v0) | ((u32)f2bf(v1) << 16),
                             (u32)f2bf(v2) | ((u32)f2bf(v3) << 16));
    *(uint2*)(dp + 16) = make_uint2((u32)f2bf(v4) | ((u32)f2bf(v5) << 16),
                                    (u32)f2bf(v6) | ((u32)f2bf(v7) << 16));
  }
}

// ---------------- FALLBACK: fused V-proj + gate + conv + residual (R4, proven)
__global__ __launch_bounds__(256) void vspec_kernel(
    const float* __restrict__ xfu, const float* __restrict__ Wv,
    const float* __restrict__ attnW, const float* __restrict__ out_sm,
    const float* __restrict__ cmaskf, const float* __restrict__ xhsi,
    u16* __restrict__ vspec_g){
  __shared__ u16 gv[32 * 10 * 40];              // [c][xl][yl(34,pad40)] gated v, bf16
  __shared__ u16 Wl[9 * 32 * 32];               // [r][i][o] bf16, r = aw*3+ah
  __shared__ alignas(16) float WvL[1024];       // [i][o]
  __shared__ float cml[32];
  int t = threadIdx.x;
  int b = blockIdx.z;
  int x0 = blockIdx.x * 8, y0 = blockIdx.y * 32;

  for (int idx = t; idx < 1024; idx += 256){
    int oo = idx >> 5, ii = idx & 31;
    WvL[ii * 32 + oo] = Wv[idx];                // Wv[o][i] -> [i][o]
  }
  if (t < 32) cml[t] = cmaskf[b * 32 + t];
  __syncthreads();

  for (int idx = t; idx < 9216; idx += 256){
    int oo = idx / 288;
    int rem = idx - oo * 288;
    int ii = rem / 9;
    int r = rem - ii * 9;
    Wl[(r * 32 + ii) * 32 + oo] = f2bf(attnW[idx]);
  }
  for (int p = t; p < 340; p += 256){           // 10 x 34 halo tile
    int xl = p / 34, yl = p - xl * 34;
    int X = x0 - 1 + xl, Y = y0 - 1 + yl;       // X: w, Y: h
    u16* dst = &gv[xl * 40 + yl];               // + c*400 per channel
    if (X >= 0 && X < NS && Y >= 0 && Y < NS){
      float xr[32];
      ld32f(xfu + ((size_t)b * NN + (size_t)Y * NS + X) * NC, xr);
      float sm = out_sm[(size_t)b * NN + (size_t)X * NS + Y];
      float vo[32];
      #pragma unroll
      for (int q = 0; q < 32; q++) vo[q] = 0.f;
      for (int i = 0; i < 32; i++){
        const float4* wr = (const float4*)&WvL[i * 32];
        float xv = xr[i];
        #pragma unroll
        for (int q = 0; q < 8; q++){
          float4 w4 = wr[q];
          vo[4 * q]     += xv * w4.x;
          vo[4 * q + 1] += xv * w4.y;
          vo[4 * q + 2] += xv * w4.z;
          vo[4 * q + 3] += xv * w4.w;
        }
      }
      #pragma unroll
      for (int c = 0; c < 32; c++) dst[c * 400] = f2bf(vo[c] * sm * cml[c]);
    } else {
      #pragma unroll
      for (int c = 0; c < 32; c++) dst[c * 400] = 0;
    }
  }
  __syncthreads();

  int o = t & 31, xs = t >> 5;
  float acc[32];
  #pragma unroll
  for (int yy = 0; yy < 32; yy++) acc[yy] = 0.f;
  #pragma unroll
  for (int aw = 0; aw < 3; aw++){
    for (int i2 = 0; i2 < 32; i2++){
      const uint4* rp = (const uint4*)(gv + (i2 * 10 + xs + aw) * 40);
      uint4 r0 = rp[0], r1 = rp[1], r2 = rp[2], r3 = rp[3], r4 = rp[4];
      float g[40];
      dec8(r0, g); dec8(r1, g + 8); dec8(r2, g + 16); dec8(r3, g + 24); dec8(r4, g + 32);
      const int wb = (aw * 3 * 32 + i2) * 32 + o;
      float w0 = bf2f(Wl[wb]);
      float w1 = bf2f(Wl[wb + 1024]);
      float w2 = bf2f(Wl[wb + 2048]);
      #pragma unroll
      for (int yy = 0; yy < 32; yy++)
        acc[yy] = fmaf(g[yy], w0, fmaf(g[yy + 1], w1, fmaf(g[yy + 2], w2, acc[yy])));
    }
  }
  int x = x0 + xs;
  #pragma unroll
  for (int yy = 0; yy < 32; yy++){
    size_t n = (size_t)b * NN + (size_t)(y0 + yy) * NS + x;
    vspec_g[n * NC + o] = f2bf(acc[yy] + xhsi[n * NC + o]);
  }
}

// ------------------------- SPLIT PATH R5: MFMA pos1 (vspec -> t), no LDS
// Wave handles 4 groups of 16 consecutive X at fixed Y. A=W[r][o][i], B=vspec px.
__global__ __launch_bounds__(256) void pos1_mfma_kernel(
    const u16* __restrict__ vspec_g, const u16* __restrict__ wA,
    const float* __restrict__ pos1b, u16* __restrict__ t_g){
  int t = threadIdx.x;
  int wv = t >> 6, l = t & 63;
  int lp = l & 15, lk = l >> 4;                 // fragment pixel / k-chunk
  int b = blockIdx.x >> 8, Y = blockIdx.x & 255;

  bf16x8 wf[9][2];
  #pragma unroll
  for (int r = 0; r < 9; r++){
    wf[r][0] = *(const bf16x8*)(wA + ((r * 32 + lp) * 32 + lk * 8));
    wf[r][1] = *(const bf16x8*)(wA + ((r * 32 + 16 + lp) * 32 + lk * 8));
  }
  float bs[8];
  #pragma unroll
  for (int j = 0; j < 4; j++){
    bs[j]     = pos1b[lk * 4 + j];
    bs[4 + j] = pos1b[16 + lk * 4 + j];
  }

  const u16* src = vspec_g + (size_t)b * NN * NC;
  u16* dst = t_g + (size_t)b * NN * NC;

  for (int g = 0; g < 4; g++){
    int X0 = wv * 64 + g * 16;
    f32x4 acc0 = {0.f, 0.f, 0.f, 0.f};
    f32x4 acc1 = {0.f, 0.f, 0.f, 0.f};
    #pragma unroll
    for (int dh = -1; dh <= 1; dh++){
      int Yi = Y + dh;
      if ((unsigned)Yi < NS){                   // uniform skip = zero-pad rows
        const u16* row = src + (size_t)Yi * (NS * NC) + lk * 8;
        #pragma unroll
        for (int dw = -1; dw <= 1; dw++){
          int Xi = X0 + lp + dw;
          uint4 u = make_uint4(0, 0, 0, 0);
          if (dw == 0 || (unsigned)Xi < NS) u = *(const uint4*)(row + Xi * NC);
          bf16x8 bfr = __builtin_bit_cast(bf16x8, u);
          const int r = (dw + 1) * 3 + (dh + 1);
          acc0 = __builtin_amdgcn_mfma_f32_16x16x32_bf16(wf[r][0], bfr, acc0, 0, 0, 0);
          acc1 = __builtin_amdgcn_mfma_f32_16x16x32_bf16(wf[r][1], bfr, acc1, 0, 0, 0);
        }
      }
    }
    // D: col=lp=pixel, rows = lk*4+j (+16 for tile 1) = out channel
    float v0 = gelu_exact(acc0.x + bs[0]);
    float v1 = gelu_exact(acc0.y + bs[1]);
    float v2 = gelu_exact(acc0.z + bs[2]);
    float v3 = gelu_exact(acc0.w + bs[3]);
    float v4 = gelu_exact(acc1.x + bs[4]);
    float v5 = gelu_exact(acc1.y + bs[5]);
    float v6 = gelu_exact(acc1.z + bs[6]);
    float v7 = gelu_exact(acc1.w + bs[7]);
    u16* dp = dst + ((size_t)Y * NS + (X0 + lp)) * NC + lk * 4;
    *(uint2*)dp = make_uint2((u32)f2bf(v0) | ((u32)f2bf(v1) << 16),
                             (u32)f2bf(v2) | ((u32)f2bf(v3) << 16));
    *(uint2*)(dp + 16) = make_uint2((u32)f2bf(v4) | ((u32)f2bf(v5) << 16),
                                    (u32)f2bf(v6) | ((u32)f2bf(v7) << 16));
  }
}

// -------------------- SPLIT PATH R5: MFMA pos2 (t -> out, + out1 epilogue), no LDS
// Wave handles 4 groups of 16 consecutive Y at fixed X (store (b,c,w,h) coalesced in h).
__global__ __launch_bounds__(256) void pos2_mfma_kernel(
    const u16* __restrict__ t_g, const u16* __restrict__ vspec_g,
    const u16* __restrict__ wA, const float* __restrict__ pos2b,
    const u16* __restrict__ Mbf, const float* __restrict__ projb,
    float* __restrict__ outp){
  int t = threadIdx.x;
  int wv = t >> 6, l = t & 63;
  int lp = l & 15, lk = l >> 4;
  int b = blockIdx.x >> 8, X = blockIdx.x & 255;

  bf16x8 wf[9][2];
  #pragma unroll
  for (int r = 0; r < 9; r++){
    wf[r][0] = *(const bf16x8*)(wA + ((r * 32 + lp) * 32 + lk * 8));
    wf[r][1] = *(const bf16x8*)(wA + ((r * 32 + 16 + lp) * 32 + lk * 8));
  }
  bf16x8 mf0 = *(const bf16x8*)(Mbf + ((b * 32 + lp) * 32 + lk * 8));
  bf16x8 mf1 = *(const bf16x8*)(Mbf + ((b * 32 + 16 + lp) * 32 + lk * 8));
  float b2s[8], pbs[8];
  #pragma unroll
  for (int j = 0; j < 4; j++){
    b2s[j]     = pos2b[lk * 4 + j];
    b2s[4 + j] = pos2b[16 + lk * 4 + j];
    pbs[j]     = projb[lk * 4 + j];
    pbs[4 + j] = projb[16 + lk * 4 + j];
  }

  const u16* tsrc = t_g + (size_t)b * NN * NC;
  const u16* vsrc = vspec_g + (size_t)b * NN * NC;
  float* ob0 = outp + (size_t)b * 32 * NN + (size_t)X * NS;

  for (int g = 0; g < 4; g++){
    int Y0 = wv * 64 + g * 16;
    int Yp = Y0 + lp;
    // epilogue GEMM first (independent chain): P = M @ vspec[px]
    f32x4 e0 = {0.f, 0.f, 0.f, 0.f};
    f32x4 e1 = {0.f, 0.f, 0.f, 0.f};
    {
      uint4 u = *(const uint4*)(vsrc + ((size_t)Yp * NS + X) * NC + lk * 8);
      bf16x8 bfr = __builtin_bit_cast(bf16x8, u);
      e0 = __builtin_amdgcn_mfma_f32_16x16x32_bf16(mf0, bfr, e0, 0, 0, 0);
      e1 = __builtin_amdgcn_mfma_f32_16x16x32_bf16(mf1, bfr, e1, 0, 0, 0);
    }
    f32x4 acc0 = {0.f, 0.f, 0.f, 0.f};
    f32x4 acc1 = {0.f, 0.f, 0.f, 0.f};
    #pragma unroll
    for (int dw = -1; dw <= 1; dw++){
      int Xi = X + dw;
      if ((unsigned)Xi < NS){                   // uniform skip = zero-pad cols
        const u16* col = tsrc + (size_t)Xi * NC + lk * 8;
        #pragma unroll
        for (int dh = -1; dh <= 1; dh++){
          int Yi = Yp + dh;
          uint4 u = make_uint4(0, 0, 0, 0);
          if (dh == 0 || (unsigned)Yi < NS) u = *(const uint4*)(col + (size_t)Yi * (NS * NC));
          bf16x8 bfr = __builtin_bit_cast(bf16x8, u);
          const int r = (dw + 1) * 3 + (dh + 1);
          acc0 = __builtin_amdgcn_mfma_f32_16x16x32_bf16(wf[r][0], bfr, acc0, 0, 0, 0);
          acc1 = __builtin_amdgcn_mfma_f32_16x16x32_bf16(wf[r][1], bfr, acc1, 0, 0, 0);
        }
      }
    }
    float r0 = acc0.x + b2s[0] + gelu_exact(e0.x + pbs[0]);
    float r1 = acc0.y + b2s[1] + gelu_exact(e0.y + pbs[1]);
    float r2 = acc0.z + b2s[2] + gelu_exact(e0.z + pbs[2]);
    float r3 = acc0.w + b2s[3] + gelu_exact(e0.w + pbs[3]);
    float r4 = acc1.x + b2s[4] + gelu_exact(e1.x + pbs[4]);
    float r5 = acc1.y + b2s[5] + gelu_exact(e1.y + pbs[5]);
    float r6 = acc1.z + b2s[6] + gelu_exact(e1.z + pbs[6]);
    float r7 = acc1.w + b2s[7] + gelu_exact(e1.w + pbs[7]);
    float* ob = ob0 + Yp + (size_t)(lk * 4) * NN;   // channel lk*4, + c*NN per channel
    ob[0]                 = r0;
    ob[(size_t)NN]        = r1;
    ob[(size_t)2 * NN]    = r2;
    ob[(size_t)3 * NN]    = r3;
    float* ob2 = ob + (size_t)16 * NN;
    ob2[0]                = r4;
    ob2[(size_t)NN]       = r5;
    ob2[(size_t)2 * NN]   = r6;
    ob2[(size_t)3 * NN]   = r7;
  }
}

// ------------------------- FALLBACK PATH (ws too small): R3's fused pos_out, proven
__global__ __launch_bounds__(320) void pos_out_kernel(
    const u16* __restrict__ vspec_g, const u16* __restrict__ wt1,
    const u16* __restrict__ wt2, const float* __restrict__ pos1b,
    const float* __restrict__ pos2b, const float* __restrict__ Mf,
    const float* __restrict__ projb, float* __restrict__ outp){
  __shared__ u16 vs[32 * 12 * 40];    // [i][vxl(12)][vyl(36,pad40)]
  __shared__ u16 tt[32 * 10 * 40];    // [o][txl(10)][tyl(34,pad40)]
  __shared__ u16 wsl[3072];           // one aw-slice: [ah][i][o]
  int t = threadIdx.x;
  int b = blockIdx.z;
  int x0 = blockIdx.x * 8, y0 = blockIdx.y * 32;
  int o = t & 31, xsl = t >> 5;       // xsl in [0,10)

  for (int p = t; p < 12 * 36; p += 320){
    int vxl = p / 36, vyl = p - vxl * 36;
    int X = x0 - 2 + vxl, Y = y0 - 2 + vyl;
    u16* dst = &vs[vxl * 40 + vyl];
    if (X >= 0 && X < NS && Y >= 0 && Y < NS){
      const uint4* src = (const uint4*)(vspec_g + ((size_t)b * NN + (size_t)Y * NS + X) * NC);
      uint4 u0 = src[0], u1 = src[1], u2 = src[2], u3 = src[3];
      alignas(16) u16 raw[32];
      *(uint4*)(raw) = u0; *(uint4*)(raw + 8) = u1;
      *(uint4*)(raw + 16) = u2; *(uint4*)(raw + 24) = u3;
      #pragma unroll
      for (int i = 0; i < 32; i++) dst[i * 480] = raw[i];
    } else {
      #pragma unroll
      for (int i = 0; i < 32; i++) dst[i * 480] = 0;
    }
  }
  __syncthreads();

  float ta[34];
  #pragma unroll
  for (int k = 0; k < 34; k++) ta[k] = 0.f;
  for (int aw = 0; aw < 3; aw++){
    for (int idx = t; idx < 3072; idx += 320) wsl[idx] = wt1[aw * 3072 + idx];
    __syncthreads();
    for (int i2 = 0; i2 < 32; i2++){
      const uint4* rp = (const uint4*)(vs + (i2 * 12 + xsl + aw) * 40);
      uint4 r0 = rp[0], r1 = rp[1], r2 = rp[2], r3 = rp[3], r4 = rp[4];
      float g[40];
      dec8(r0, g); dec8(r1, g + 8); dec8(r2, g + 16); dec8(r3, g + 24); dec8(r4, g + 32);
      float w0 = bf2f(wsl[i2 * 32 + o]);
      float w1 = bf2f(wsl[i2 * 32 + o + 1024]);
      float w2 = bf2f(wsl[i2 * 32 + o + 2048]);
      #pragma unroll
      for (int yl = 0; yl < 34; yl++)
        ta[yl] = fmaf(g[yl], w0, fmaf(g[yl + 1], w1, fmaf(g[yl + 2], w2, ta[yl])));
    }
    __syncthreads();
  }
  {
    float b1 = pos1b[o];
    int X = x0 - 1 + xsl;
    bool colOK = (X >= 0 && X < NS);
    u16* trow = &tt[(o * 10 + xsl) * 40];
    #pragma unroll
    for (int yl = 0; yl < 34; yl++){
      int Y = y0 - 1 + yl;
      float val = (colOK && Y >= 0 && Y < NS) ? gelu_exact(ta[yl] + b1) : 0.f;
      trow[yl] = f2bf(val);
    }
  }
  __syncthreads();

  float acc2[32];
  #pragma unroll
  for (int yy = 0; yy < 32; yy++) acc2[yy] = 0.f;
  for (int aw = 0; aw < 3; aw++){
    for (int idx = t; idx < 3072; idx += 320) wsl[idx] = wt2[aw * 3072 + idx];
    __syncthreads();
    if (xsl < 8){
      for (int i2 = 0; i2 < 32; i2++){
        const uint4* rp = (const uint4*)(tt + (i2 * 10 + xsl + aw) * 40);
        uint4 r0 = rp[0], r1 = rp[1], r2 = rp[2], r3 = rp[3], r4 = rp[4];
        float g[40];
        dec8(r0, g); dec8(r1, g + 8); dec8(r2, g + 16); dec8(r3, g + 24); dec8(r4, g + 32);
        float w0 = bf2f(wsl[i2 * 32 + o]);
        float w1 = bf2f(wsl[i2 * 32 + o + 1024]);
        float w2 = bf2f(wsl[i2 * 32 + o + 2048]);
        #pragma unroll
        for (int yy = 0; yy < 32; yy++)
          acc2[yy] = fmaf(g[yy], w0, fmaf(g[yy + 1], w1, fmaf(g[yy + 2], w2, acc2[yy])));
      }
    }
    __syncthreads();
  }
  if (xsl < 8){
    int x = x0 + xsl;
    float m[32];
    {
      const float4* mp = (const float4*)(Mf + b * 1024 + o * 32);
      #pragma unroll
      for (int k = 0; k < 8; k++){
        float4 f = mp[k];
        m[4 * k] = f.x; m[4 * k + 1] = f.y; m[4 * k + 2] = f.z; m[4 * k + 3] = f.w;
      }
    }
    float pb = projb[o];
    float b2v = pos2b[o];
    float outv[32];
    #pragma unroll
    for (int yy = 0; yy < 32; yy++){
      size_t n = (size_t)b * NN + (size_t)(y0 + yy) * NS + x;
      const uint4* xp = (const uint4*)(vspec_g + n * NC);
      uint4 u0 = xp[0], u1 = xp[1], u2 = xp[2], u3 = xp[3];
      float xr[32];
      dec8(u0, xr); dec8(u1, xr + 8); dec8(u2, xr + 16); dec8(u3, xr + 24);
      float s = pb;
      #pragma unroll
      for (int i2 = 0; i2 < 32; i2++) s += m[i2] * xr[i2];
      outv[yy] = acc2[yy] + b2v + gelu_exact(s);
    }
    float4* dp = (float4*)(outp + (((size_t)(b * 32 + o) * NS) + x) * NS + y0);
    #pragma unroll
    for (int k = 0; k < 8; k++)
      dp[k] = make_float4(outv[4 * k], outv[4 * k + 1], outv[4 * k + 2], outv[4 * k + 3]);
  }
}

// ---------------------------------------------------------------------- launch
extern "C" void kernel_launch(void* const* d_in, const int* in_sizes, int n_in,
                              void* d_out, int out_size, void* d_ws, size_t ws_size,
                              hipStream_t stream){
  (void)in_sizes; (void)n_in; (void)out_size;
  const float* xfu   = (const float*)d_in[0];
  const float* xmsi  = (const float*)d_in[1];
  const float* xhsi  = (const float*)d_in[2];
  const float* Wq    = (const float*)d_in[3];
  const float* Wk    = (const float*)d_in[4];
  const float* Wv    = (const float*)d_in[5];
  const float* projW = (const float*)d_in[6];
  const float* projb = (const float*)d_in[7];
  const float* pos1W = (const float*)d_in[8];
  const float* pos1b = (const float*)d_in[9];
  const float* pos2W = (const float*)d_in[10];
  const float* pos2b = (const float*)d_in[11];
  const float* cafc1 = (const float*)d_in[12];
  const float* cafc2 = (const float*)d_in[13];
  const float* sac1a = (const float*)d_in[14];
  const float* sac1b = (const float*)d_in[15];
  const float* sac2a = (const float*)d_in[16];
  const float* sac2b = (const float*)d_in[17];
  const float* sac3  = (const float*)d_in[18];
  const float* attnW = (const float*)d_in[19];

  float* out = (float*)d_out;
  float* out_main = out;                  // (b,c,w,h) 8388608 f32
  float* out_cm   = out + 8388608;        // 128
  float* out_sm   = out + 8388736;        // 262144

  // workspace map (R7): sums[0,512) S[1024,17408) cmask[17920] W1[18432] W2[20480]
  // Mf[28672,45056) wt1[45056] wt2[63488] wA1[81920] wA2[100352] Mbf[118784,126976)
  // vspec [131072,+16M), t/gv [+16M,+32M)  (gv aliases t_g: disjoint lifetimes)
  char* ws = (char*)d_ws;
  float* sums   = (float*)(ws + 0);         // 128 f (zeroed with S: 4352 f total)
  float* Sm     = (float*)(ws + 1024);      // 4096 f = [4][32][32]
  float* cmaskf = (float*)(ws + 17920);     // 128 f
  float* W1     = (float*)(ws + 18432);     // 288 f
  float* W2     = (float*)(ws + 20480);     // 1568 f
  float* Mf     = (float*)(ws + 28672);     // 4096 f
  u16*   wt1    = (u16*)(ws + 45056);       // 9216 bf16 [r][i][o] (fallback) / wAv (split)
  u16*   wt2    = (u16*)(ws + 63488);       // 9216 bf16
  u16*   wA1    = (u16*)(ws + 81920);       // 9216 bf16 [r][o][i] (MFMA)
  u16*   wA2    = (u16*)(ws + 100352);      // 9216 bf16
  u16*   Mbf    = (u16*)(ws + 118784);      // 4096 bf16 [b][o][i]
  u16*   vspec  = (u16*)(ws + 131072);      // 16 MB bf16 (b,n,c)
  u16*   t_g    = (u16*)(ws + 131072 + 16777216);   // 16 MB bf16 (split path only)
  const bool split = ws_size >= (size_t)(131072 + 2 * 16777216);
  u16*   wAv    = split ? wt1 : wA1;        // split: wt1 slot free; fallback: dummy
  u16*   gvbuf  = t_g;                      // gv dies before pos1 writes t_g

  pre_kernel<<<1, 256, 0, stream>>>(sac1a, sac1b, sac2a, sac2b, pos1W, pos2W, attnW,
                                    sums, W1, W2, wt1, wt2, wA1, wA2, wAv,
                                    split ? 0 : 1);
  channel_sum_kernel<<<256, 256, 0, stream>>>(xhsi, sums);
  spatial_mask_kernel<<<dim3(16, 16, NB), 256, 0, stream>>>(xmsi, W1, W2, sac3, out_sm);
  x2_kernel<<<1024, 256, 0, stream>>>(xfu, Sm);
  mid_kernel<<<1, 256, 0, stream>>>(sums, cafc1, cafc2, cmaskf, out_cm,
                                    Sm, Wq, Wk, projW, Mf, Mbf);
  if (split){
    vgate_kernel<<<512, 256, 0, stream>>>(xfu, Wv, out_sm, cmaskf, gvbuf);
    vconv_mfma_kernel<<<1024, 256, 0, stream>>>(gvbuf, wAv, xhsi, vspec);
    pos1_mfma_kernel<<<1024, 256, 0, stream>>>(vspec, wA1, pos1b, t_g);
    pos2_mfma_kernel<<<1024, 256, 0, stream>>>(t_g, vspec, wA2, pos2b, Mbf, projb, out_main);
  } else {
    vspec_kernel<<<dim3(32, 8, NB), 256, 0, stream>>>(
        xfu, Wv, attnW, out_sm, cmaskf, xhsi, vspec);
    pos_out_kernel<<<dim3(32, 8, NB), 320, 0, stream>>>(
        vspec, wt1, wt2, pos1b, pos2b, Mf, projb, out_main);
  }
}

// Round 8
// 417.677 us; speedup vs baseline: 1.4811x; 1.1245x over previous
//
#include <hip/hip_runtime.h>
#include <hip/hip_bf16.h>

// Self_mask_Spectral_MSA on MI355X — Round 11: x2 atomic elimination (2-stage reduce).
// B=4, H=W=256, C=32, heads=4, d=8. f32 I/O, fp32 accumulation, bf16 intermediates.
//
// R11 changes vs R10 (passed, 470us; x2 = 73us):
//  - R10 post-mortem: WRITE_SIZE = 16MB = 1,048,576 atomicAdds x 16B, CONSTANT across
//    R8/R9/R10. Device-scope atomics execute memory-side (per-XCD L2s not coherent);
//    1M atomics / 4096 addresses (256-way contention) = ~65us drain floor in every
//    round: R8 max(~100 compute, 65)=115, R9 ~100, R10 max(~8, 65)=73. All match.
//  - Fix: NO global atomics. x2 -> 512 blocks (2 chunks each, acc carried), each
//    block plain-stores 1024 partials to pbufT[e][j] (transposed, 2MB, in the
//    dead-until-vconv vspec region). New x2r_kernel: 4096 outputs, each sums its
//    128 contiguous floats (32 indep float4 loads, 4 acc chains) -> S.
//    Deterministic f32 order; absmax unchanged (gram-path noise << bf16 quant).
//  - Everything else unchanged from R10.

#define NB 4
#define NC 32
#define NS 256
#define NN 65536

typedef unsigned short u16;
typedef unsigned int u32;
typedef __bf16 bf16x8 __attribute__((ext_vector_type(8)));
typedef float f32x4 __attribute__((ext_vector_type(4)));

__device__ __forceinline__ float bf2f(u16 s){ return __uint_as_float(((u32)s) << 16); }
__device__ __forceinline__ u16 f2bf(float x){
  u32 u = __float_as_uint(x);
  u32 r = (u + 0x7fffu + ((u >> 16) & 1u)) >> 16;   // RNE
  return (u16)r;
}
__device__ __forceinline__ void dec8(uint4 u, float* f){
  f[0] = __uint_as_float((u.x & 0xffffu) << 16);
  f[1] = __uint_as_float(u.x & 0xffff0000u);
  f[2] = __uint_as_float((u.y & 0xffffu) << 16);
  f[3] = __uint_as_float(u.y & 0xffff0000u);
  f[4] = __uint_as_float((u.z & 0xffffu) << 16);
  f[5] = __uint_as_float(u.z & 0xffff0000u);
  f[6] = __uint_as_float((u.w & 0xffffu) << 16);
  f[7] = __uint_as_float(u.w & 0xffff0000u);
}
__device__ __forceinline__ void ld32f(const float* __restrict__ p, float* x){
  const float4* q = (const float4*)p;
  #pragma unroll
  for (int k = 0; k < 8; k++){
    float4 f = q[k];
    x[4 * k] = f.x; x[4 * k + 1] = f.y; x[4 * k + 2] = f.z; x[4 * k + 3] = f.w;
  }
}
__device__ __forceinline__ uint4 pack8(const float* f){
  uint4 u;
  u.x = (u32)f2bf(f[0]) | ((u32)f2bf(f[1]) << 16);
  u.y = (u32)f2bf(f[2]) | ((u32)f2bf(f[3]) << 16);
  u.z = (u32)f2bf(f[4]) | ((u32)f2bf(f[5]) << 16);
  u.w = (u32)f2bf(f[6]) | ((u32)f2bf(f[7]) << 16);
  return u;
}
__device__ __forceinline__ float gelu_exact(float x){
  return 0.5f * x * (1.0f + erff(x * 0.70710678118654752f));
}
__device__ __forceinline__ float sigmoidf_(float x){ return 1.0f / (1.0f + expf(-x)); }

// ---------------------- pre: zero accumulators + fold SA weights + transpose pos weights
__global__ __launch_bounds__(256) void pre_kernel(
    const float* __restrict__ c1a, const float* __restrict__ c1b,
    const float* __restrict__ c2a, const float* __restrict__ c2b,
    const float* __restrict__ p1, const float* __restrict__ p2,
    const float* __restrict__ aw,
    float* __restrict__ zbase, float* __restrict__ W1, float* __restrict__ W2,
    u16* __restrict__ wt1, u16* __restrict__ wt2,
    u16* __restrict__ wA1, u16* __restrict__ wA2,
    u16* __restrict__ wAv, int fb){
  int t = threadIdx.x;
  for (int i = t; i < 4352; i += 256) zbase[i] = 0.f;          // sums(128) + S(4096 @ +256)
  for (int idx = t; idx < 288; idx += 256){                    // W1[r*32+j]
    int r = idx >> 5, j = idx & 31;
    float s = 0.f;
    for (int i = 0; i < 32; i++) s += c1b[i] * c1a[(i * 32 + j) * 9 + r];
    W1[idx] = s;
  }
  for (int idx = t; idx < 1568; idx += 256){                   // W2[r*32+j]
    int r = idx >> 5, j = idx & 31;
    float s = 0.f;
    for (int i = 0; i < 32; i++) s += c2b[i] * c2a[(i * 32 + j) * 49 + r];
    W2[idx] = s;
  }
  for (int idx = t; idx < 9216; idx += 256){                   // OIHW -> layouts
    int o = idx / 288;
    int rem = idx - o * 288;
    int i = rem / 9;
    int r = rem - i * 9;
    u16 w1v = f2bf(p1[idx]);
    u16 w2v = f2bf(p2[idx]);
    if (fb){
      wt1[(r * 32 + i) * 32 + o] = w1v;    // [r][i][o]  (fallback path only)
      wt2[(r * 32 + i) * 32 + o] = w2v;
    }
    wA1[(r * 32 + o) * 32 + i] = w1v;      // [r][o][i]  (MFMA A-fragments)
    wA2[(r * 32 + o) * 32 + i] = w2v;
    wAv[(r * 32 + o) * 32 + i] = f2bf(aw[idx]);
  }
}

// ---------------------------------------------------------------- channel sums
__global__ __launch_bounds__(256) void channel_sum_kernel(const float* __restrict__ xhsi,
                                                          float* __restrict__ sums){
  int b = blockIdx.x >> 6;
  int blk = blockIdx.x & 63;
  const float* p = xhsi + (size_t)b * NN * NC;
  int t = threadIdx.x;
  int base = blk * 32768;
  float acc = 0.f;
  for (int k = 0; k < 128; k++) acc += p[base + t + k * 256];
  __shared__ float red[256];
  red[t] = acc;
  __syncthreads();
  if (t < 32){
    float s = 0.f;
    #pragma unroll
    for (int k = 0; k < 8; k++) s += red[t + k * 32];     // channel of red[j] is j&31
    atomicAdd(&sums[b * 32 + t], s);
  }
}

// -------- R11: S = X^T X per batch, stage 1: per-block partials, NO atomics.
// 512 blocks, 2 chunks of 256 rows each (acc carried across chunks). Partials go
// to pbufT[e_global][j] (j = block-within-batch, 128 contiguous per entry).
__global__ __launch_bounds__(256) void x2_kernel(const float* __restrict__ xfu,
                                                 float* __restrict__ pbufT){
  __shared__ float xs[256 * NC];                 // 32KB: [row][ch]
  __shared__ float red[4][64][17];               // pad 17: spread write banks
  int t = threadIdx.x;
  int bid = blockIdx.x;
  int b = bid >> 7, j = bid & 127;               // 128 blocks per batch
  int wv = t >> 6, l = t & 63;
  int o = l & 31, ebase = (l >> 5) * 16;
  float acc[16];
  #pragma unroll
  for (int q = 0; q < 16; q++) acc[q] = 0.f;
  for (int c = 0; c < 2; c++){
    const float* src = xfu + (size_t)(bid * 2 + c) * 256 * NC;
    #pragma unroll
    for (int q = 0; q < 32; q++) xs[t + q * 256] = src[t + q * 256];
    __syncthreads();
    const float* rp = xs + wv * 64 * NC;
    #pragma unroll 4
    for (int r = 0; r < 64; r++){
      const float* row = rp + r * NC;
      float xo = row[o];
      const float4* ep = (const float4*)(row + ebase);
      float4 e0 = ep[0], e1 = ep[1], e2 = ep[2], e3 = ep[3];
      acc[0]  += xo * e0.x; acc[1]  += xo * e0.y; acc[2]  += xo * e0.z; acc[3]  += xo * e0.w;
      acc[4]  += xo * e1.x; acc[5]  += xo * e1.y; acc[6]  += xo * e1.z; acc[7]  += xo * e1.w;
      acc[8]  += xo * e2.x; acc[9]  += xo * e2.y; acc[10] += xo * e2.z; acc[11] += xo * e2.w;
      acc[12] += xo * e3.x; acc[13] += xo * e3.y; acc[14] += xo * e3.z; acc[15] += xo * e3.w;
    }
    __syncthreads();                             // xs dead before next stage
  }
  #pragma unroll
  for (int q = 0; q < 16; q++) red[wv][l][q] = acc[q];
  __syncthreads();
  #pragma unroll
  for (int k = 0; k < 4; k++){
    int idx = t * 4 + k;
    int ll = idx >> 4, jj = idx & 15;
    float s = red[0][ll][jj] + red[1][ll][jj] + red[2][ll][jj] + red[3][ll][jj];
    int oo = ll & 31, eb = (ll >> 5) * 16;
    int e = oo * 32 + eb + jj;
    pbufT[((size_t)b * 1024 + e) * 128 + j] = s;   // plain store, no atomic
  }
}

// -------- R11: stage 2 — sum 128 contiguous partials per entry -> S[4096].
__global__ __launch_bounds__(64) void x2r_kernel(const float* __restrict__ pbufT,
                                                 float* __restrict__ S){
  int out = blockIdx.x * 64 + threadIdx.x;       // [0,4096)
  const float4* pp = (const float4*)(pbufT + (size_t)out * 128);
  float a0 = 0.f, a1 = 0.f, a2 = 0.f, a3 = 0.f;  // 4 independent chains
  #pragma unroll
  for (int k = 0; k < 32; k += 4){
    float4 v0 = pp[k], v1 = pp[k + 1], v2 = pp[k + 2], v3 = pp[k + 3];
    a0 += v0.x + v0.y + v0.z + v0.w;
    a1 += v1.x + v1.y + v1.z + v1.w;
    a2 += v2.x + v2.y + v2.z + v2.w;
    a3 += v3.x + v3.y + v3.z + v3.w;
  }
  S[out] = (a0 + a1) + (a2 + a3);
}

// --- mid: channel mask (sigmoid MLP) + attention softmax from S + M fold
// R8: all stride-32 LDS arrays padded to 33 (bank-conflict fix).
__global__ __launch_bounds__(256) void mid_kernel(
    const float* __restrict__ sums, const float* __restrict__ fc1,
    const float* __restrict__ fc2, float* __restrict__ cmaskf, float* __restrict__ out_cm,
    const float* __restrict__ S, const float* __restrict__ Wq, const float* __restrict__ Wk,
    const float* __restrict__ projW, float* __restrict__ Mf, u16* __restrict__ Mbf){
  __shared__ float avg[NB][NC], hid[NB][NC];
  __shared__ float attn_s[16][65];
  __shared__ float Wqs[32][33], Wks[32][33];
  __shared__ float Ss[4][32][33];
  __shared__ float Ts[4][32][33], Us[4][32][33];
  __shared__ float nq2[4][32], nk2[4][32];
  int t = threadIdx.x;
  for (int idx = t; idx < 1024; idx += 256){
    Wqs[idx >> 5][idx & 31] = Wq[idx];
    Wks[idx >> 5][idx & 31] = Wk[idx];
  }
  for (int idx = t; idx < 4096; idx += 256)
    Ss[idx >> 10][(idx >> 5) & 31][idx & 31] = S[idx];
  if (t < 128){
    int b = t >> 5, o = t & 31;
    avg[b][o] = sums[t] * (1.0f / 65536.0f);
  }
  __syncthreads();
  // T = S·Wq^T, U = S·Wk^T  (T[b][i][c] = sum_j S[b][i][j]·Wq[c][j])
  for (int idx = t; idx < 8192; idx += 256){
    int which = idx >> 12;
    int b = (idx >> 10) & 3, i = (idx >> 5) & 31, c = idx & 31;
    const float* wrow = which ? &Wks[c][0] : &Wqs[c][0];
    const float* srow = &Ss[b][i][0];
    float s = 0.f;
    #pragma unroll
    for (int j = 0; j < 32; j++) s += srow[j] * wrow[j];
    if (which) Us[b][i][c] = s; else Ts[b][i][c] = s;
  }
  if (t < 128){
    int b = t >> 5, o = t & 31;
    float s = 0.f;
    for (int j = 0; j < 32; j++) s += fc1[o * 32 + j] * avg[b][j];
    hid[b][o] = fmaxf(s, 0.f);
  }
  __syncthreads();
  // norms: ||q_c||^2 = Wq_c·T[:,c], ||k_o||^2 = Wk_o·U[:,o]
  if (t < 128){
    int b = t >> 5, c = t & 31;
    float sq = 0.f, sk = 0.f;
    #pragma unroll
    for (int i = 0; i < 32; i++){
      sq += Wqs[c][i] * Ts[b][i][c];
      sk += Wks[c][i] * Us[b][i][c];
    }
    nq2[b][c] = sq; nk2[b][c] = sk;
  }
  __syncthreads();
  // softmax over normalized gram; G[o][c] = Wk_o · T[:,c]
  if (t < 128){
    int bh = t >> 3, d = t & 7;   // bh = b*4+h
    int b = bh >> 2, h = bh & 3;
    int o = h * 8 + d;
    float nk = fmaxf(sqrtf(nk2[b][o]), 1e-12f);
    float l[8];
    float mx = -1e30f;
    #pragma unroll
    for (int e = 0; e < 8; e++){
      int c = h * 8 + e;
      float G = 0.f;
      #pragma unroll
      for (int i = 0; i < 32; i++) G += Wks[o][i] * Ts[b][i][c];
      float nq = fmaxf(sqrtf(nq2[b][c]), 1e-12f);
      l[e] = G / (nk * nq);
      mx = fmaxf(mx, l[e]);
    }
    float se = 0.f;
    #pragma unroll
    for (int e = 0; e < 8; e++){ l[e] = expf(l[e] - mx); se += l[e]; }
    float inv = 1.f / se;
    #pragma unroll
    for (int e = 0; e < 8; e++) attn_s[bh][d * 8 + e] = l[e] * inv;
  }
  if (t < 128){
    int b = t >> 5, o = t & 31;
    float s2 = 0.f;
    for (int i = 0; i < 32; i++) s2 += fc2[o * 32 + i] * hid[b][i];
    float m = sigmoidf_(s2);
    cmaskf[t] = m;
    out_cm[t] = m;
  }
  __syncthreads();
  for (int idx = t; idx < 4096; idx += 256){        // M[b][o][i]
    int b = idx >> 10, o = (idx >> 5) & 31, i = idx & 31;
    int hd = i >> 3, e = i & 7;
    float s = 0.f;
    #pragma unroll
    for (int d = 0; d < 8; d++)
      s += projW[o * 32 + hd * 8 + d] * attn_s[b * 4 + hd][d * 8 + e];
    Mf[idx] = s;
    Mbf[idx] = f2bf(s);
  }
}

// tile: [c8][xl][yl] uint4 (8 bf16 channels per uint4). 16x16 output px, halo 3.
__global__ __launch_bounds__(256) void spatial_mask_kernel(
    const float* __restrict__ xmsi, const float* __restrict__ W1, const float* __restrict__ W2,
    const float* __restrict__ sac3, float* __restrict__ out_sm){
  __shared__ uint4 tile[4][22][25];
  __shared__ float W1s[9 * 32], W2s[49 * 32];
  int t = threadIdx.x;
  int b = blockIdx.z;
  int x0 = blockIdx.x * 16, y0 = blockIdx.y * 16;
  for (int idx = t; idx < 9 * 32;  idx += 256) W1s[idx] = W1[idx];
  for (int idx = t; idx < 49 * 32; idx += 256) W2s[idx] = W2[idx];
  for (int p = t; p < 484; p += 256){
    int xl = p / 22, yl = p - xl * 22;
    int X = x0 - 3 + xl, Y = y0 - 3 + yl;
    uint4 u0, u1, u2, u3;
    if (X >= 0 && X < NS && Y >= 0 && Y < NS){
      float xr[32];
      ld32f(xmsi + ((size_t)b * NN + (size_t)Y * NS + X) * NC, xr);
      u0 = pack8(xr); u1 = pack8(xr + 8); u2 = pack8(xr + 16); u3 = pack8(xr + 24);
    } else {
      u0 = u1 = u2 = u3 = make_uint4(0, 0, 0, 0);
    }
    tile[0][xl][yl] = u0; tile[1][xl][yl] = u1; tile[2][xl][yl] = u2; tile[3][xl][yl] = u3;
  }
  __syncthreads();
  int j = t & 15, i = t >> 4;     // j: y (h), i: x (w)
  float m1 = 0.f, m2 = 0.f;
  for (int aw = 0; aw < 7; aw++){
    for (int ah = 0; ah < 7; ah++){
      const float* wr = &W2s[(aw * 7 + ah) * 32];
      float s = 0.f;
      #pragma unroll
      for (int c = 0; c < 4; c++){
        uint4 u = tile[c][i + aw][j + ah];
        float g[8]; dec8(u, g);
        #pragma unroll
        for (int k = 0; k < 8; k++) s += g[k] * wr[c * 8 + k];
      }
      m2 += s;
    }
  }
  for (int aw = 0; aw < 3; aw++){
    for (int ah = 0; ah < 3; ah++){
      const float* wr = &W1s[(aw * 3 + ah) * 32];
      float s = 0.f;
      #pragma unroll
      for (int c = 0; c < 4; c++){
        uint4 u = tile[c][i + aw + 2][j + ah + 2];
        float g[8]; dec8(u, g);
        #pragma unroll
        for (int k = 0; k < 8; k++) s += g[k] * wr[c * 8 + k];
      }
      m1 += s;
    }
  }
  float m = sac3[0] * m1 + sac3[1] * m2;
  float sg = sigmoidf_(m);
  int x = x0 + i, y = y0 + j;
  out_sm[(size_t)b * NN + (size_t)x * NS + y] = sg;   // (b,1,w,h): w-major
}

// ----------------------- R6 SPLIT: vgate — f32 V-proj + gate, 2 px/thread, no halo
__global__ __launch_bounds__(256) void vgate_kernel(
    const float* __restrict__ xfu, const float* __restrict__ Wv,
    const float* __restrict__ out_sm, const float* __restrict__ cmaskf,
    u16* __restrict__ gv){
  __shared__ alignas(16) float WvL[1024];       // [i][o]
  __shared__ float cml[NC];
  int t = threadIdx.x;
  int b = blockIdx.x >> 7;                      // 512 blocks: 128 per batch, 2 rows each
  int px0 = blockIdx.x * 512 + t;               // (X = t, Y = 2*(blk&127))
  int px1 = px0 + 256;                          // (X = t, Y+1)
  int X = t;
  int Y0 = (px0 >> 8) & 255;

  for (int idx = t; idx < 1024; idx += 256){
    int oo = idx >> 5, ii = idx & 31;
    WvL[ii * 32 + oo] = Wv[idx];                // Wv[o][i] -> [i][o]
  }
  if (t < 32) cml[t] = cmaskf[b * 32 + t];
  __syncthreads();

  float xr0[32], xr1[32];
  ld32f(xfu + (size_t)px0 * NC, xr0);
  ld32f(xfu + (size_t)px1 * NC, xr1);
  float sm0 = out_sm[(size_t)b * NN + (size_t)X * NS + Y0];
  float sm1 = out_sm[(size_t)b * NN + (size_t)X * NS + Y0 + 1];

  float vo0[32], vo1[32];
  #pragma unroll
  for (int q = 0; q < 32; q++){ vo0[q] = 0.f; vo1[q] = 0.f; }
  for (int i = 0; i < 32; i++){
    const float4* wr = (const float4*)&WvL[i * 32];
    float a0 = xr0[i], a1 = xr1[i];
    #pragma unroll
    for (int q = 0; q < 8; q++){
      float4 w4 = wr[q];
      vo0[4 * q]     += a0 * w4.x;  vo1[4 * q]     += a1 * w4.x;
      vo0[4 * q + 1] += a0 * w4.y;  vo1[4 * q + 1] += a1 * w4.y;
      vo0[4 * q + 2] += a0 * w4.z;  vo1[4 * q + 2] += a1 * w4.z;
      vo0[4 * q + 3] += a0 * w4.w;  vo1[4 * q + 3] += a1 * w4.w;
    }
  }
  float g0[32], g1[32];
  #pragma unroll
  for (int c = 0; c < 32; c++){
    float cm = cml[c];
    g0[c] = vo0[c] * sm0 * cm;
    g1[c] = vo1[c] * sm1 * cm;
  }
  uint4* d0 = (uint4*)(gv + (size_t)px0 * NC);
  uint4* d1 = (uint4*)(gv + (size_t)px1 * NC);
  d0[0] = pack8(g0);  d0[1] = pack8(g0 + 8);  d0[2] = pack8(g0 + 16);  d0[3] = pack8(g0 + 24);
  d1[0] = pack8(g1);  d1[1] = pack8(g1 + 8);  d1[2] = pack8(g1 + 16);  d1[3] = pack8(g1 + 24);
}

// ------------------- R6 SPLIT: vconv — pos1-pattern MFMA conv3x3 + xhsi residual
__global__ __launch_bounds__(256) void vconv_mfma_kernel(
    const u16* __restrict__ gv, const u16* __restrict__ wAv,
    const float* __restrict__ xhsi, u16* __restrict__ vspec_g){
  int t = threadIdx.x;
  int wv = t >> 6, l = t & 63;
  int lp = l & 15, lk = l >> 4;                 // fragment pixel / k-chunk
  int b = blockIdx.x >> 8, Y = blockIdx.x & 255;

  bf16x8 wf[9][2];
  #pragma unroll
  for (int r = 0; r < 9; r++){
    wf[r][0] = *(const bf16x8*)(wAv + ((r * 32 + lp) * 32 + lk * 8));
    wf[r][1] = *(const bf16x8*)(wAv + ((r * 32 + 16 + lp) * 32 + lk * 8));
  }

  const u16* src = gv + (size_t)b * NN * NC;
  const float* res = xhsi + (size_t)b * NN * NC;
  u16* dst = vspec_g + (size_t)b * NN * NC;

  for (int g = 0; g < 4; g++){
    int X0 = wv * 64 + g * 16;
    f32x4 acc0 = {0.f, 0.f, 0.f, 0.f};
    f32x4 acc1 = {0.f, 0.f, 0.f, 0.f};
    #pragma unroll
    for (int dh = -1; dh <= 1; dh++){
      int Yi = Y + dh;
      if ((unsigned)Yi < NS){                   // uniform skip = zero-pad rows
        const u16* row = src + (size_t)Yi * (NS * NC) + lk * 8;
        #pragma unroll
        for (int dw = -1; dw <= 1; dw++){
          int Xi = X0 + lp + dw;
          uint4 u = make_uint4(0, 0, 0, 0);
          if (dw == 0 || (unsigned)Xi < NS) u = *(const uint4*)(row + Xi * NC);
          bf16x8 bfr = __builtin_bit_cast(bf16x8, u);
          const int r = (dw + 1) * 3 + (dh + 1);
          acc0 = __builtin_amdgcn_mfma_f32_16x16x32_bf16(wf[r][0], bfr, acc0, 0, 0, 0);
          acc1 = __builtin_amdgcn_mfma_f32_16x16x32_bf16(wf[r][1], bfr, acc1, 0, 0, 0);
        }
      }
    }
    // D: col=lp=pixel, rows = lk*4+j (+16 for tile 1) = out channel; + residual
    size_t n = (size_t)Y * NS + (X0 + lp);
    float4 rA = *(const float4*)(res + n * NC + lk * 4);
    float4 rB = *(const float4*)(res + n * NC + lk * 4 + 16);
    float v0 = acc0.x + rA.x;
    float v1 = acc0.y + rA.y;
    float v2 = acc0.z + rA.z;
    float v3 = acc0.w + rA.w;
    float v4 = acc1.x + rB.x;
    float v5 = acc1.y + rB.y;
    float v6 = acc1.z + rB.z;
    float v7 = acc1.w + rB.w;
    u16* dp = dst + n * NC + lk * 4;
    *(uint2*)dp = make_uint2((u32)f2bf(v0) | ((u32)f2bf(v1) << 16),
                             (u32)f2bf(v2) | ((u32)f2bf(v3) << 16));
    *(uint2*)(dp + 16) = make_uint2((u32)f2bf(v4) | ((u32)f2bf(v5) << 16),
                                    (u32)f2bf(v6) | ((u32)f2bf(v7) << 16));
  }
}

// ---------------- FALLBACK: fused V-proj + gate + conv + residual (R4, proven)
__global__ __launch_bounds__(256) void vspec_kernel(
    const float* __restrict__ xfu, const float* __restrict__ Wv,
    const float* __restrict__ attnW, const float* __restrict__ out_sm,
    const float* __restrict__ cmaskf, const float* __restrict__ xhsi,
    u16* __restrict__ vspec_g){
  __shared__ u16 gv[32 * 10 * 40];              // [c][xl][yl(34,pad40)] gated v, bf16
  __shared__ u16 Wl[9 * 32 * 32];               // [r][i][o] bf16, r = aw*3+ah
  __shared__ alignas(16) float WvL[1024];       // [i][o]
  __shared__ float cml[32];
  int t = threadIdx.x;
  int b = blockIdx.z;
  int x0 = blockIdx.x * 8, y0 = blockIdx.y * 32;

  for (int idx = t; idx < 1024; idx += 256){
    int oo = idx >> 5, ii = idx & 31;
    WvL[ii * 32 + oo] = Wv[idx];                // Wv[o][i] -> [i][o]
  }
  if (t < 32) cml[t] = cmaskf[b * 32 + t];
  __syncthreads();

  for (int idx = t; idx < 9216; idx += 256){
    int oo = idx / 288;
    int rem = idx - oo * 288;
    int ii = rem / 9;
    int r = rem - ii * 9;
    Wl[(r * 32 + ii) * 32 + oo] = f2bf(attnW[idx]);
  }
  for (int p = t; p < 340; p += 256){           // 10 x 34 halo tile
    int xl = p / 34, yl = p - xl * 34;
    int X = x0 - 1 + xl, Y = y0 - 1 + yl;       // X: w, Y: h
    u16* dst = &gv[xl * 40 + yl];               // + c*400 per channel
    if (X >= 0 && X < NS && Y >= 0 && Y < NS){
      float xr[32];
      ld32f(xfu + ((size_t)b * NN + (size_t)Y * NS + X) * NC, xr);
      float sm = out_sm[(size_t)b * NN + (size_t)X * NS + Y];
      float vo[32];
      #pragma unroll
      for (int q = 0; q < 32; q++) vo[q] = 0.f;
      for (int i = 0; i < 32; i++){
        const float4* wr = (const float4*)&WvL[i * 32];
        float xv = xr[i];
        #pragma unroll
        for (int q = 0; q < 8; q++){
          float4 w4 = wr[q];
          vo[4 * q]     += xv * w4.x;
          vo[4 * q + 1] += xv * w4.y;
          vo[4 * q + 2] += xv * w4.z;
          vo[4 * q + 3] += xv * w4.w;
        }
      }
      #pragma unroll
      for (int c = 0; c < 32; c++) dst[c * 400] = f2bf(vo[c] * sm * cml[c]);
    } else {
      #pragma unroll
      for (int c = 0; c < 32; c++) dst[c * 400] = 0;
    }
  }
  __syncthreads();

  int o = t & 31, xs = t >> 5;
  float acc[32];
  #pragma unroll
  for (int yy = 0; yy < 32; yy++) acc[yy] = 0.f;
  #pragma unroll
  for (int aw = 0; aw < 3; aw++){
    for (int i2 = 0; i2 < 32; i2++){
      const uint4* rp = (const uint4*)(gv + (i2 * 10 + xs + aw) * 40);
      uint4 r0 = rp[0], r1 = rp[1], r2 = rp[2], r3 = rp[3], r4 = rp[4];
      float g[40];
      dec8(r0, g); dec8(r1, g + 8); dec8(r2, g + 16); dec8(r3, g + 24); dec8(r4, g + 32);
      const int wb = (aw * 3 * 32 + i2) * 32 + o;
      float w0 = bf2f(Wl[wb]);
      float w1 = bf2f(Wl[wb + 1024]);
      float w2 = bf2f(Wl[wb + 2048]);
      #pragma unroll
      for (int yy = 0; yy < 32; yy++)
        acc[yy] = fmaf(g[yy], w0, fmaf(g[yy + 1], w1, fmaf(g[yy + 2], w2, acc[yy])));
    }
  }
  int x = x0 + xs;
  #pragma unroll
  for (int yy = 0; yy < 32; yy++){
    size_t n = (size_t)b * NN + (size_t)(y0 + yy) * NS + x;
    vspec_g[n * NC + o] = f2bf(acc[yy] + xhsi[n * NC + o]);
  }
}

// ------------------------- SPLIT PATH R5: MFMA pos1 (vspec -> t), no LDS
// Wave handles 4 groups of 16 consecutive X at fixed Y. A=W[r][o][i], B=vspec px.
__global__ __launch_bounds__(256) void pos1_mfma_kernel(
    const u16* __restrict__ vspec_g, const u16* __restrict__ wA,
    const float* __restrict__ pos1b, u16* __restrict__ t_g){
  int t = threadIdx.x;
  int wv = t >> 6, l = t & 63;
  int lp = l & 15, lk = l >> 4;                 // fragment pixel / k-chunk
  int b = blockIdx.x >> 8, Y = blockIdx.x & 255;

  bf16x8 wf[9][2];
  #pragma unroll
  for (int r = 0; r < 9; r++){
    wf[r][0] = *(const bf16x8*)(wA + ((r * 32 + lp) * 32 + lk * 8));
    wf[r][1] = *(const bf16x8*)(wA + ((r * 32 + 16 + lp) * 32 + lk * 8));
  }
  float bs[8];
  #pragma unroll
  for (int j = 0; j < 4; j++){
    bs[j]     = pos1b[lk * 4 + j];
    bs[4 + j] = pos1b[16 + lk * 4 + j];
  }

  const u16* src = vspec_g + (size_t)b * NN * NC;
  u16* dst = t_g + (size_t)b * NN * NC;

  for (int g = 0; g < 4; g++){
    int X0 = wv * 64 + g * 16;
    f32x4 acc0 = {0.f, 0.f, 0.f, 0.f};
    f32x4 acc1 = {0.f, 0.f, 0.f, 0.f};
    #pragma unroll
    for (int dh = -1; dh <= 1; dh++){
      int Yi = Y + dh;
      if ((unsigned)Yi < NS){                   // uniform skip = zero-pad rows
        const u16* row = src + (size_t)Yi * (NS * NC) + lk * 8;
        #pragma unroll
        for (int dw = -1; dw <= 1; dw++){
          int Xi = X0 + lp + dw;
          uint4 u = make_uint4(0, 0, 0, 0);
          if (dw == 0 || (unsigned)Xi < NS) u = *(const uint4*)(row + Xi * NC);
          bf16x8 bfr = __builtin_bit_cast(bf16x8, u);
          const int r = (dw + 1) * 3 + (dh + 1);
          acc0 = __builtin_amdgcn_mfma_f32_16x16x32_bf16(wf[r][0], bfr, acc0, 0, 0, 0);
          acc1 = __builtin_amdgcn_mfma_f32_16x16x32_bf16(wf[r][1], bfr, acc1, 0, 0, 0);
        }
      }
    }
    // D: col=lp=pixel, rows = lk*4+j (+16 for tile 1) = out channel
    float v0 = gelu_exact(acc0.x + bs[0]);
    float v1 = gelu_exact(acc0.y + bs[1]);
    float v2 = gelu_exact(acc0.z + bs[2]);
    float v3 = gelu_exact(acc0.w + bs[3]);
    float v4 = gelu_exact(acc1.x + bs[4]);
    float v5 = gelu_exact(acc1.y + bs[5]);
    float v6 = gelu_exact(acc1.z + bs[6]);
    float v7 = gelu_exact(acc1.w + bs[7]);
    u16* dp = dst + ((size_t)Y * NS + (X0 + lp)) * NC + lk * 4;
    *(uint2*)dp = make_uint2((u32)f2bf(v0) | ((u32)f2bf(v1) << 16),
                             (u32)f2bf(v2) | ((u32)f2bf(v3) << 16));
    *(uint2*)(dp + 16) = make_uint2((u32)f2bf(v4) | ((u32)f2bf(v5) << 16),
                                    (u32)f2bf(v6) | ((u32)f2bf(v7) << 16));
  }
}

// -------------------- SPLIT PATH R5: MFMA pos2 (t -> out, + out1 epilogue), no LDS
// Wave handles 4 groups of 16 consecutive Y at fixed X (store (b,c,w,h) coalesced in h).
__global__ __launch_bounds__(256) void pos2_mfma_kernel(
    const u16* __restrict__ t_g, const u16* __restrict__ vspec_g,
    const u16* __restrict__ wA, const float* __restrict__ pos2b,
    const u16* __restrict__ Mbf, const float* __restrict__ projb,
    float* __restrict__ outp){
  int t = threadIdx.x;
  int wv = t >> 6, l = t & 63;
  int lp = l & 15, lk = l >> 4;
  int b = blockIdx.x >> 8, X = blockIdx.x & 255;

  bf16x8 wf[9][2];
  #pragma unroll
  for (int r = 0; r < 9; r++){
    wf[r][0] = *(const bf16x8*)(wA + ((r * 32 + lp) * 32 + lk * 8));
    wf[r][1] = *(const bf16x8*)(wA + ((r * 32 + 16 + lp) * 32 + lk * 8));
  }
  bf16x8 mf0 = *(const bf16x8*)(Mbf + ((b * 32 + lp) * 32 + lk * 8));
  bf16x8 mf1 = *(const bf16x8*)(Mbf + ((b * 32 + 16 + lp) * 32 + lk * 8));
  float b2s[8], pbs[8];
  #pragma unroll
  for (int j = 0; j < 4; j++){
    b2s[j]     = pos2b[lk * 4 + j];
    b2s[4 + j] = pos2b[16 + lk * 4 + j];
    pbs[j]     = projb[lk * 4 + j];
    pbs[4 + j] = projb[16 + lk * 4 + j];
  }

  const u16* tsrc = t_g + (size_t)b * NN * NC;
  const u16* vsrc = vspec_g + (size_t)b * NN * NC;
  float* ob0 = outp + (size_t)b * 32 * NN + (size_t)X * NS;

  for (int g = 0; g < 4; g++){
    int Y0 = wv * 64 + g * 16;
    int Yp = Y0 + lp;
    // epilogue GEMM first (independent chain): P = M @ vspec[px]
    f32x4 e0 = {0.f, 0.f, 0.f, 0.f};
    f32x4 e1 = {0.f, 0.f, 0.f, 0.f};
    {
      uint4 u = *(const uint4*)(vsrc + ((size_t)Yp * NS + X) * NC + lk * 8);
      bf16x8 bfr = __builtin_bit_cast(bf16x8, u);
      e0 = __builtin_amdgcn_mfma_f32_16x16x32_bf16(mf0, bfr, e0, 0, 0, 0);
      e1 = __builtin_amdgcn_mfma_f32_16x16x32_bf16(mf1, bfr, e1, 0, 0, 0);
    }
    f32x4 acc0 = {0.f, 0.f, 0.f, 0.f};
    f32x4 acc1 = {0.f, 0.f, 0.f, 0.f};
    #pragma unroll
    for (int dw = -1; dw <= 1; dw++){
      int Xi = X + dw;
      if ((unsigned)Xi < NS){                   // uniform skip = zero-pad cols
        const u16* col = tsrc + (size_t)Xi * NC + lk * 8;
        #pragma unroll
        for (int dh = -1; dh <= 1; dh++){
          int Yi = Yp + dh;
          uint4 u = make_uint4(0, 0, 0, 0);
          if (dh == 0 || (unsigned)Yi < NS) u = *(const uint4*)(col + (size_t)Yi * (NS * NC));
          bf16x8 bfr = __builtin_bit_cast(bf16x8, u);
          const int r = (dw + 1) * 3 + (dh + 1);
          acc0 = __builtin_amdgcn_mfma_f32_16x16x32_bf16(wf[r][0], bfr, acc0, 0, 0, 0);
          acc1 = __builtin_amdgcn_mfma_f32_16x16x32_bf16(wf[r][1], bfr, acc1, 0, 0, 0);
        }
      }
    }
    float r0 = acc0.x + b2s[0] + gelu_exact(e0.x + pbs[0]);
    float r1 = acc0.y + b2s[1] + gelu_exact(e0.y + pbs[1]);
    float r2 = acc0.z + b2s[2] + gelu_exact(e0.z + pbs[2]);
    float r3 = acc0.w + b2s[3] + gelu_exact(e0.w + pbs[3]);
    float r4 = acc1.x + b2s[4] + gelu_exact(e1.x + pbs[4]);
    float r5 = acc1.y + b2s[5] + gelu_exact(e1.y + pbs[5]);
    float r6 = acc1.z + b2s[6] + gelu_exact(e1.z + pbs[6]);
    float r7 = acc1.w + b2s[7] + gelu_exact(e1.w + pbs[7]);
    float* ob = ob0 + Yp + (size_t)(lk * 4) * NN;   // channel lk*4, + c*NN per channel
    ob[0]                 = r0;
    ob[(size_t)NN]        = r1;
    ob[(size_t)2 * NN]    = r2;
    ob[(size_t)3 * NN]    = r3;
    float* ob2 = ob + (size_t)16 * NN;
    ob2[0]                = r4;
    ob2[(size_t)NN]       = r5;
    ob2[(size_t)2 * NN]   = r6;
    ob2[(size_t)3 * NN]   = r7;
  }
}

// ------------------------- FALLBACK PATH (ws too small): R3's fused pos_out, proven
__global__ __launch_bounds__(320) void pos_out_kernel(
    const u16* __restrict__ vspec_g, const u16* __restrict__ wt1,
    const u16* __restrict__ wt2, const float* __restrict__ pos1b,
    const float* __restrict__ pos2b, const float* __restrict__ Mf,
    const float* __restrict__ projb, float* __restrict__ outp){
  __shared__ u16 vs[32 * 12 * 40];    // [i][vxl(12)][vyl(36,pad40)]
  __shared__ u16 tt[32 * 10 * 40];    // [o][txl(10)][tyl(34,pad40)]
  __shared__ u16 wsl[3072];           // one aw-slice: [ah][i][o]
  int t = threadIdx.x;
  int b = blockIdx.z;
  int x0 = blockIdx.x * 8, y0 = blockIdx.y * 32;
  int o = t & 31, xsl = t >> 5;       // xsl in [0,10)

  for (int p = t; p < 12 * 36; p += 320){
    int vxl = p / 36, vyl = p - vxl * 36;
    int X = x0 - 2 + vxl, Y = y0 - 2 + vyl;
    u16* dst = &vs[vxl * 40 + vyl];
    if (X >= 0 && X < NS && Y >= 0 && Y < NS){
      const uint4* src = (const uint4*)(vspec_g + ((size_t)b * NN + (size_t)Y * NS + X) * NC);
      uint4 u0 = src[0], u1 = src[1], u2 = src[2], u3 = src[3];
      alignas(16) u16 raw[32];
      *(uint4*)(raw) = u0; *(uint4*)(raw + 8) = u1;
      *(uint4*)(raw + 16) = u2; *(uint4*)(raw + 24) = u3;
      #pragma unroll
      for (int i = 0; i < 32; i++) dst[i * 480] = raw[i];
    } else {
      #pragma unroll
      for (int i = 0; i < 32; i++) dst[i * 480] = 0;
    }
  }
  __syncthreads();

  float ta[34];
  #pragma unroll
  for (int k = 0; k < 34; k++) ta[k] = 0.f;
  for (int aw = 0; aw < 3; aw++){
    for (int idx = t; idx < 3072; idx += 320) wsl[idx] = wt1[aw * 3072 + idx];
    __syncthreads();
    for (int i2 = 0; i2 < 32; i2++){
      const uint4* rp = (const uint4*)(vs + (i2 * 12 + xsl + aw) * 40);
      uint4 r0 = rp[0], r1 = rp[1], r2 = rp[2], r3 = rp[3], r4 = rp[4];
      float g[40];
      dec8(r0, g); dec8(r1, g + 8); dec8(r2, g + 16); dec8(r3, g + 24); dec8(r4, g + 32);
      float w0 = bf2f(wsl[i2 * 32 + o]);
      float w1 = bf2f(wsl[i2 * 32 + o + 1024]);
      float w2 = bf2f(wsl[i2 * 32 + o + 2048]);
      #pragma unroll
      for (int yl = 0; yl < 34; yl++)
        ta[yl] = fmaf(g[yl], w0, fmaf(g[yl + 1], w1, fmaf(g[yl + 2], w2, ta[yl])));
    }
    __syncthreads();
  }
  {
    float b1 = pos1b[o];
    int X = x0 - 1 + xsl;
    bool colOK = (X >= 0 && X < NS);
    u16* trow = &tt[(o * 10 + xsl) * 40];
    #pragma unroll
    for (int yl = 0; yl < 34; yl++){
      int Y = y0 - 1 + yl;
      float val = (colOK && Y >= 0 && Y < NS) ? gelu_exact(ta[yl] + b1) : 0.f;
      trow[yl] = f2bf(val);
    }
  }
  __syncthreads();

  float acc2[32];
  #pragma unroll
  for (int yy = 0; yy < 32; yy++) acc2[yy] = 0.f;
  for (int aw = 0; aw < 3; aw++){
    for (int idx = t; idx < 3072; idx += 320) wsl[idx] = wt2[aw * 3072 + idx];
    __syncthreads();
    if (xsl < 8){
      for (int i2 = 0; i2 < 32; i2++){
        const uint4* rp = (const uint4*)(tt + (i2 * 10 + xsl + aw) * 40);
        uint4 r0 = rp[0], r1 = rp[1], r2 = rp[2], r3 = rp[3], r4 = rp[4];
        float g[40];
        dec8(r0, g); dec8(r1, g + 8); dec8(r2, g + 16); dec8(r3, g + 24); dec8(r4, g + 32);
        float w0 = bf2f(wsl[i2 * 32 + o]);
        float w1 = bf2f(wsl[i2 * 32 + o + 1024]);
        float w2 = bf2f(wsl[i2 * 32 + o + 2048]);
        #pragma unroll
        for (int yy = 0; yy < 32; yy++)
          acc2[yy] = fmaf(g[yy], w0, fmaf(g[yy + 1], w1, fmaf(g[yy + 2], w2, acc2[yy])));
      }
    }
    __syncthreads();
  }
  if (xsl < 8){
    int x = x0 + xsl;
    float m[32];
    {
      const float4* mp = (const float4*)(Mf + b * 1024 + o * 32);
      #pragma unroll
      for (int k = 0; k < 8; k++){
        float4 f = mp[k];
        m[4 * k] = f.x; m[4 * k + 1] = f.y; m[4 * k + 2] = f.z; m[4 * k + 3] = f.w;
      }
    }
    float pb = projb[o];
    float b2v = pos2b[o];
    float outv[32];
    #pragma unroll
    for (int yy = 0; yy < 32; yy++){
      size_t n = (size_t)b * NN + (size_t)(y0 + yy) * NS + x;
      const uint4* xp = (const uint4*)(vspec_g + n * NC);
      uint4 u0 = xp[0], u1 = xp[1], u2 = xp[2], u3 = xp[3];
      float xr[32];
      dec8(u0, xr); dec8(u1, xr + 8); dec8(u2, xr + 16); dec8(u3, xr + 24);
      float s = pb;
      #pragma unroll
      for (int i2 = 0; i2 < 32; i2++) s += m[i2] * xr[i2];
      outv[yy] = acc2[yy] + b2v + gelu_exact(s);
    }
    float4* dp = (float4*)(outp + (((size_t)(b * 32 + o) * NS) + x) * NS + y0);
    #pragma unroll
    for (int k = 0; k < 8; k++)
      dp[k] = make_float4(outv[4 * k], outv[4 * k + 1], outv[4 * k + 2], outv[4 * k + 3]);
  }
}

// ---------------------------------------------------------------------- launch
extern "C" void kernel_launch(void* const* d_in, const int* in_sizes, int n_in,
                              void* d_out, int out_size, void* d_ws, size_t ws_size,
                              hipStream_t stream){
  (void)in_sizes; (void)n_in; (void)out_size;
  const float* xfu   = (const float*)d_in[0];
  const float* xmsi  = (const float*)d_in[1];
  const float* xhsi  = (const float*)d_in[2];
  const float* Wq    = (const float*)d_in[3];
  const float* Wk    = (const float*)d_in[4];
  const float* Wv    = (const float*)d_in[5];
  const float* projW = (const float*)d_in[6];
  const float* projb = (const float*)d_in[7];
  const float* pos1W = (const float*)d_in[8];
  const float* pos1b = (const float*)d_in[9];
  const float* pos2W = (const float*)d_in[10];
  const float* pos2b = (const float*)d_in[11];
  const float* cafc1 = (const float*)d_in[12];
  const float* cafc2 = (const float*)d_in[13];
  const float* sac1a = (const float*)d_in[14];
  const float* sac1b = (const float*)d_in[15];
  const float* sac2a = (const float*)d_in[16];
  const float* sac2b = (const float*)d_in[17];
  const float* sac3  = (const float*)d_in[18];
  const float* attnW = (const float*)d_in[19];

  float* out = (float*)d_out;
  float* out_main = out;                  // (b,c,w,h) 8388608 f32
  float* out_cm   = out + 8388608;        // 128
  float* out_sm   = out + 8388736;        // 262144

  // workspace map: sums[0,512) S[1024,17408) cmask[17920] W1[18432] W2[20480]
  // Mf[28672,45056) wt1[45056] wt2[63488] wA1[81920] wA2[100352] Mbf[118784,126976)
  // vspec [131072,+16M) (first 2MB doubles as pbufT, dead before vconv),
  // t/gv [+16M,+32M)  (gv aliases t_g: disjoint lifetimes)
  char* ws = (char*)d_ws;
  float* sums   = (float*)(ws + 0);         // 128 f (zeroed with S: 4352 f total)
  float* Sm     = (float*)(ws + 1024);      // 4096 f = [4][32][32]
  float* cmaskf = (float*)(ws + 17920);     // 128 f
  float* W1     = (float*)(ws + 18432);     // 288 f
  float* W2     = (float*)(ws + 20480);     // 1568 f
  float* Mf     = (float*)(ws + 28672);     // 4096 f
  u16*   wt1    = (u16*)(ws + 45056);       // 9216 bf16 [r][i][o] (fallback) / wAv (split)
  u16*   wt2    = (u16*)(ws + 63488);       // 9216 bf16
  u16*   wA1    = (u16*)(ws + 81920);       // 9216 bf16 [r][o][i] (MFMA)
  u16*   wA2    = (u16*)(ws + 100352);      // 9216 bf16
  u16*   Mbf    = (u16*)(ws + 118784);      // 4096 bf16 [b][o][i]
  u16*   vspec  = (u16*)(ws + 131072);      // 16 MB bf16 (b,n,c)
  float* pbufT  = (float*)(ws + 131072);    // 2 MB partials [4096][128] (dead pre-vconv)
  u16*   t_g    = (u16*)(ws + 131072 + 16777216);   // 16 MB bf16 (split path only)
  const bool split = ws_size >= (size_t)(131072 + 2 * 16777216);
  u16*   wAv    = split ? wt1 : wA1;        // split: wt1 slot free; fallback: dummy
  u16*   gvbuf  = t_g;                      // gv dies before pos1 writes t_g

  pre_kernel<<<1, 256, 0, stream>>>(sac1a, sac1b, sac2a, sac2b, pos1W, pos2W, attnW,
                                    sums, W1, W2, wt1, wt2, wA1, wA2, wAv,
                                    split ? 0 : 1);
  channel_sum_kernel<<<256, 256, 0, stream>>>(xhsi, sums);
  spatial_mask_kernel<<<dim3(16, 16, NB), 256, 0, stream>>>(xmsi, W1, W2, sac3, out_sm);
  x2_kernel<<<512, 256, 0, stream>>>(xfu, pbufT);
  x2r_kernel<<<64, 64, 0, stream>>>(pbufT, Sm);
  mid_kernel<<<1, 256, 0, stream>>>(sums, cafc1, cafc2, cmaskf, out_cm,
                                    Sm, Wq, Wk, projW, Mf, Mbf);
  if (split){
    vgate_kernel<<<512, 256, 0, stream>>>(xfu, Wv, out_sm, cmaskf, gvbuf);
    vconv_mfma_kernel<<<1024, 256, 0, stream>>>(gvbuf, wAv, xhsi, vspec);
    pos1_mfma_kernel<<<1024, 256, 0, stream>>>(vspec, wA1, pos1b, t_g);
    pos2_mfma_kernel<<<1024, 256, 0, stream>>>(t_g, vspec, wA2, pos2b, Mbf, projb, out_main);
  } else {
    vspec_kernel<<<dim3(32, 8, NB), 256, 0, stream>>>(
        xfu, Wv, attnW, out_sm, cmaskf, xhsi, vspec);
    pos_out_kernel<<<dim3(32, 8, NB), 320, 0, stream>>>(
        vspec, wt1, wt2, pos1b, pos2b, Mf, projb, out_main);
  }
}

// Round 9
// 361.834 us; speedup vs baseline: 1.7097x; 1.1543x over previous
//
#include <hip/hip_runtime.h>
#include <hip/hip_bf16.h>

// Self_mask_Spectral_MSA on MI355X — Round 12: parallelize pre_kernel + spatial_mask pad.
// B=4, H=W=256, C=32, heads=4, d=8. f32 I/O, fp32 accumulation, bf16 intermediates.
//
// R12 changes vs R11 (passed, 418us):
//  - pre_kernel (66us!, 1 block, VALUBusy 0.016%, VGPR 28): W2-fold ran ~192
//    latency-serialized cold loads/thread on a single CU (same pathology as R9 x2).
//    Fix: 64 blocks (16K threads, <=1 output/thread), 4-chain partials for ILP.
//    (f32 sum-order change in the weight FOLD only: ~1e-7 << tolerance.)
//  - spatial_mask (68us, 3.87M bank conflicts): tile[4][22][25] uint4 read bank =
//    4*(i+j) mod 32 -> 8-way conflict. Pad 25->26: bank = (8i+4j) mod 32 ->
//    i-groups land 8 banks apart; residual ~2-way (free). LDS 44KB, occ unchanged.
//  - Everything else unchanged from R11.

#define NB 4
#define NC 32
#define NS 256
#define NN 65536

typedef unsigned short u16;
typedef unsigned int u32;
typedef __bf16 bf16x8 __attribute__((ext_vector_type(8)));
typedef float f32x4 __attribute__((ext_vector_type(4)));

__device__ __forceinline__ float bf2f(u16 s){ return __uint_as_float(((u32)s) << 16); }
__device__ __forceinline__ u16 f2bf(float x){
  u32 u = __float_as_uint(x);
  u32 r = (u + 0x7fffu + ((u >> 16) & 1u)) >> 16;   // RNE
  return (u16)r;
}
__device__ __forceinline__ void dec8(uint4 u, float* f){
  f[0] = __uint_as_float((u.x & 0xffffu) << 16);
  f[1] = __uint_as_float(u.x & 0xffff0000u);
  f[2] = __uint_as_float((u.y & 0xffffu) << 16);
  f[3] = __uint_as_float(u.y & 0xffff0000u);
  f[4] = __uint_as_float((u.z & 0xffffu) << 16);
  f[5] = __uint_as_float(u.z & 0xffff0000u);
  f[6] = __uint_as_float((u.w & 0xffffu) << 16);
  f[7] = __uint_as_float(u.w & 0xffff0000u);
}
__device__ __forceinline__ void ld32f(const float* __restrict__ p, float* x){
  const float4* q = (const float4*)p;
  #pragma unroll
  for (int k = 0; k < 8; k++){
    float4 f = q[k];
    x[4 * k] = f.x; x[4 * k + 1] = f.y; x[4 * k + 2] = f.z; x[4 * k + 3] = f.w;
  }
}
__device__ __forceinline__ uint4 pack8(const float* f){
  uint4 u;
  u.x = (u32)f2bf(f[0]) | ((u32)f2bf(f[1]) << 16);
  u.y = (u32)f2bf(f[2]) | ((u32)f2bf(f[3]) << 16);
  u.z = (u32)f2bf(f[4]) | ((u32)f2bf(f[5]) << 16);
  u.w = (u32)f2bf(f[6]) | ((u32)f2bf(f[7]) << 16);
  return u;
}
__device__ __forceinline__ float gelu_exact(float x){
  return 0.5f * x * (1.0f + erff(x * 0.70710678118654752f));
}
__device__ __forceinline__ float sigmoidf_(float x){ return 1.0f / (1.0f + expf(-x)); }

// ------- pre: zero accumulators + fold SA weights + transpose pos weights (R12: 64 blocks)
#define PRE_NT 16384
__global__ __launch_bounds__(256) void pre_kernel(
    const float* __restrict__ c1a, const float* __restrict__ c1b,
    const float* __restrict__ c2a, const float* __restrict__ c2b,
    const float* __restrict__ p1, const float* __restrict__ p2,
    const float* __restrict__ aw,
    float* __restrict__ zbase, float* __restrict__ W1, float* __restrict__ W2,
    u16* __restrict__ wt1, u16* __restrict__ wt2,
    u16* __restrict__ wA1, u16* __restrict__ wA2,
    u16* __restrict__ wAv, int fb){
  int gid = blockIdx.x * 256 + threadIdx.x;
  for (int i = gid; i < 4352; i += PRE_NT) zbase[i] = 0.f;     // sums(128) + S(4096 @ +256)
  for (int idx = gid; idx < 288; idx += PRE_NT){               // W1[r*32+j]
    int r = idx >> 5, j = idx & 31;
    float s0 = 0.f, s1 = 0.f, s2 = 0.f, s3 = 0.f;
    #pragma unroll
    for (int i = 0; i < 32; i += 4){
      s0 += c1b[i]     * c1a[((i)     * 32 + j) * 9 + r];
      s1 += c1b[i + 1] * c1a[((i + 1) * 32 + j) * 9 + r];
      s2 += c1b[i + 2] * c1a[((i + 2) * 32 + j) * 9 + r];
      s3 += c1b[i + 3] * c1a[((i + 3) * 32 + j) * 9 + r];
    }
    W1[idx] = (s0 + s1) + (s2 + s3);
  }
  for (int idx = gid; idx < 1568; idx += PRE_NT){              // W2[r*32+j]
    int r = idx >> 5, j = idx & 31;
    float s0 = 0.f, s1 = 0.f, s2 = 0.f, s3 = 0.f;
    #pragma unroll
    for (int i = 0; i < 32; i += 4){
      s0 += c2b[i]     * c2a[((i)     * 32 + j) * 49 + r];
      s1 += c2b[i + 1] * c2a[((i + 1) * 32 + j) * 49 + r];
      s2 += c2b[i + 2] * c2a[((i + 2) * 32 + j) * 49 + r];
      s3 += c2b[i + 3] * c2a[((i + 3) * 32 + j) * 49 + r];
    }
    W2[idx] = (s0 + s1) + (s2 + s3);
  }
  for (int idx = gid; idx < 9216; idx += PRE_NT){              // OIHW -> layouts
    int o = idx / 288;
    int rem = idx - o * 288;
    int i = rem / 9;
    int r = rem - i * 9;
    u16 w1v = f2bf(p1[idx]);
    u16 w2v = f2bf(p2[idx]);
    if (fb){
      wt1[(r * 32 + i) * 32 + o] = w1v;    // [r][i][o]  (fallback path only)
      wt2[(r * 32 + i) * 32 + o] = w2v;
    }
    wA1[(r * 32 + o) * 32 + i] = w1v;      // [r][o][i]  (MFMA A-fragments)
    wA2[(r * 32 + o) * 32 + i] = w2v;
    wAv[(r * 32 + o) * 32 + i] = f2bf(aw[idx]);
  }
}

// ---------------------------------------------------------------- channel sums
__global__ __launch_bounds__(256) void channel_sum_kernel(const float* __restrict__ xhsi,
                                                          float* __restrict__ sums){
  int b = blockIdx.x >> 6;
  int blk = blockIdx.x & 63;
  const float* p = xhsi + (size_t)b * NN * NC;
  int t = threadIdx.x;
  int base = blk * 32768;
  float acc = 0.f;
  for (int k = 0; k < 128; k++) acc += p[base + t + k * 256];
  __shared__ float red[256];
  red[t] = acc;
  __syncthreads();
  if (t < 32){
    float s = 0.f;
    #pragma unroll
    for (int k = 0; k < 8; k++) s += red[t + k * 32];     // channel of red[j] is j&31
    atomicAdd(&sums[b * 32 + t], s);
  }
}

// -------- R11: S = X^T X per batch, stage 1: per-block partials, NO atomics.
__global__ __launch_bounds__(256) void x2_kernel(const float* __restrict__ xfu,
                                                 float* __restrict__ pbufT){
  __shared__ float xs[256 * NC];                 // 32KB: [row][ch]
  __shared__ float red[4][64][17];               // pad 17: spread write banks
  int t = threadIdx.x;
  int bid = blockIdx.x;
  int b = bid >> 7, j = bid & 127;               // 128 blocks per batch
  int wv = t >> 6, l = t & 63;
  int o = l & 31, ebase = (l >> 5) * 16;
  float acc[16];
  #pragma unroll
  for (int q = 0; q < 16; q++) acc[q] = 0.f;
  for (int c = 0; c < 2; c++){
    const float* src = xfu + (size_t)(bid * 2 + c) * 256 * NC;
    #pragma unroll
    for (int q = 0; q < 32; q++) xs[t + q * 256] = src[t + q * 256];
    __syncthreads();
    const float* rp = xs + wv * 64 * NC;
    #pragma unroll 4
    for (int r = 0; r < 64; r++){
      const float* row = rp + r * NC;
      float xo = row[o];
      const float4* ep = (const float4*)(row + ebase);
      float4 e0 = ep[0], e1 = ep[1], e2 = ep[2], e3 = ep[3];
      acc[0]  += xo * e0.x; acc[1]  += xo * e0.y; acc[2]  += xo * e0.z; acc[3]  += xo * e0.w;
      acc[4]  += xo * e1.x; acc[5]  += xo * e1.y; acc[6]  += xo * e1.z; acc[7]  += xo * e1.w;
      acc[8]  += xo * e2.x; acc[9]  += xo * e2.y; acc[10] += xo * e2.z; acc[11] += xo * e2.w;
      acc[12] += xo * e3.x; acc[13] += xo * e3.y; acc[14] += xo * e3.z; acc[15] += xo * e3.w;
    }
    __syncthreads();                             // xs dead before next stage
  }
  #pragma unroll
  for (int q = 0; q < 16; q++) red[wv][l][q] = acc[q];
  __syncthreads();
  #pragma unroll
  for (int k = 0; k < 4; k++){
    int idx = t * 4 + k;
    int ll = idx >> 4, jj = idx & 15;
    float s = red[0][ll][jj] + red[1][ll][jj] + red[2][ll][jj] + red[3][ll][jj];
    int oo = ll & 31, eb = (ll >> 5) * 16;
    int e = oo * 32 + eb + jj;
    pbufT[((size_t)b * 1024 + e) * 128 + j] = s;   // plain store, no atomic
  }
}

// -------- R11: stage 2 — sum 128 contiguous partials per entry -> S[4096].
__global__ __launch_bounds__(64) void x2r_kernel(const float* __restrict__ pbufT,
                                                 float* __restrict__ S){
  int out = blockIdx.x * 64 + threadIdx.x;       // [0,4096)
  const float4* pp = (const float4*)(pbufT + (size_t)out * 128);
  float a0 = 0.f, a1 = 0.f, a2 = 0.f, a3 = 0.f;  // 4 independent chains
  #pragma unroll
  for (int k = 0; k < 32; k += 4){
    float4 v0 = pp[k], v1 = pp[k + 1], v2 = pp[k + 2], v3 = pp[k + 3];
    a0 += v0.x + v0.y + v0.z + v0.w;
    a1 += v1.x + v1.y + v1.z + v1.w;
    a2 += v2.x + v2.y + v2.z + v2.w;
    a3 += v3.x + v3.y + v3.z + v3.w;
  }
  S[out] = (a0 + a1) + (a2 + a3);
}

// --- mid: channel mask (sigmoid MLP) + attention softmax from S + M fold
// R8: all stride-32 LDS arrays padded to 33 (bank-conflict fix).
__global__ __launch_bounds__(256) void mid_kernel(
    const float* __restrict__ sums, const float* __restrict__ fc1,
    const float* __restrict__ fc2, float* __restrict__ cmaskf, float* __restrict__ out_cm,
    const float* __restrict__ S, const float* __restrict__ Wq, const float* __restrict__ Wk,
    const float* __restrict__ projW, float* __restrict__ Mf, u16* __restrict__ Mbf){
  __shared__ float avg[NB][NC], hid[NB][NC];
  __shared__ float attn_s[16][65];
  __shared__ float Wqs[32][33], Wks[32][33];
  __shared__ float Ss[4][32][33];
  __shared__ float Ts[4][32][33], Us[4][32][33];
  __shared__ float nq2[4][32], nk2[4][32];
  int t = threadIdx.x;
  for (int idx = t; idx < 1024; idx += 256){
    Wqs[idx >> 5][idx & 31] = Wq[idx];
    Wks[idx >> 5][idx & 31] = Wk[idx];
  }
  for (int idx = t; idx < 4096; idx += 256)
    Ss[idx >> 10][(idx >> 5) & 31][idx & 31] = S[idx];
  if (t < 128){
    int b = t >> 5, o = t & 31;
    avg[b][o] = sums[t] * (1.0f / 65536.0f);
  }
  __syncthreads();
  // T = S·Wq^T, U = S·Wk^T  (T[b][i][c] = sum_j S[b][i][j]·Wq[c][j])
  for (int idx = t; idx < 8192; idx += 256){
    int which = idx >> 12;
    int b = (idx >> 10) & 3, i = (idx >> 5) & 31, c = idx & 31;
    const float* wrow = which ? &Wks[c][0] : &Wqs[c][0];
    const float* srow = &Ss[b][i][0];
    float s = 0.f;
    #pragma unroll
    for (int j = 0; j < 32; j++) s += srow[j] * wrow[j];
    if (which) Us[b][i][c] = s; else Ts[b][i][c] = s;
  }
  if (t < 128){
    int b = t >> 5, o = t & 31;
    float s = 0.f;
    for (int j = 0; j < 32; j++) s += fc1[o * 32 + j] * avg[b][j];
    hid[b][o] = fmaxf(s, 0.f);
  }
  __syncthreads();
  // norms: ||q_c||^2 = Wq_c·T[:,c], ||k_o||^2 = Wk_o·U[:,o]
  if (t < 128){
    int b = t >> 5, c = t & 31;
    float sq = 0.f, sk = 0.f;
    #pragma unroll
    for (int i = 0; i < 32; i++){
      sq += Wqs[c][i] * Ts[b][i][c];
      sk += Wks[c][i] * Us[b][i][c];
    }
    nq2[b][c] = sq; nk2[b][c] = sk;
  }
  __syncthreads();
  // softmax over normalized gram; G[o][c] = Wk_o · T[:,c]
  if (t < 128){
    int bh = t >> 3, d = t & 7;   // bh = b*4+h
    int b = bh >> 2, h = bh & 3;
    int o = h * 8 + d;
    float nk = fmaxf(sqrtf(nk2[b][o]), 1e-12f);
    float l[8];
    float mx = -1e30f;
    #pragma unroll
    for (int e = 0; e < 8; e++){
      int c = h * 8 + e;
      float G = 0.f;
      #pragma unroll
      for (int i = 0; i < 32; i++) G += Wks[o][i] * Ts[b][i][c];
      float nq = fmaxf(sqrtf(nq2[b][c]), 1e-12f);
      l[e] = G / (nk * nq);
      mx = fmaxf(mx, l[e]);
    }
    float se = 0.f;
    #pragma unroll
    for (int e = 0; e < 8; e++){ l[e] = expf(l[e] - mx); se += l[e]; }
    float inv = 1.f / se;
    #pragma unroll
    for (int e = 0; e < 8; e++) attn_s[bh][d * 8 + e] = l[e] * inv;
  }
  if (t < 128){
    int b = t >> 5, o = t & 31;
    float s2 = 0.f;
    for (int i = 0; i < 32; i++) s2 += fc2[o * 32 + i] * hid[b][i];
    float m = sigmoidf_(s2);
    cmaskf[t] = m;
    out_cm[t] = m;
  }
  __syncthreads();
  for (int idx = t; idx < 4096; idx += 256){        // M[b][o][i]
    int b = idx >> 10, o = (idx >> 5) & 31, i = idx & 31;
    int hd = i >> 3, e = i & 7;
    float s = 0.f;
    #pragma unroll
    for (int d = 0; d < 8; d++)
      s += projW[o * 32 + hd * 8 + d] * attn_s[b * 4 + hd][d * 8 + e];
    Mf[idx] = s;
    Mbf[idx] = f2bf(s);
  }
}

// tile: [c8][xl][yl] uint4 (8 bf16 channels per uint4). 16x16 output px, halo 3.
// R12: inner dim padded 25->26 (read bank (8i+4j)%32, was 4(i+j)%32 8-way).
__global__ __launch_bounds__(256) void spatial_mask_kernel(
    const float* __restrict__ xmsi, const float* __restrict__ W1, const float* __restrict__ W2,
    const float* __restrict__ sac3, float* __restrict__ out_sm){
  __shared__ uint4 tile[4][22][26];
  __shared__ float W1s[9 * 32], W2s[49 * 32];
  int t = threadIdx.x;
  int b = blockIdx.z;
  int x0 = blockIdx.x * 16, y0 = blockIdx.y * 16;
  for (int idx = t; idx < 9 * 32;  idx += 256) W1s[idx] = W1[idx];
  for (int idx = t; idx < 49 * 32; idx += 256) W2s[idx] = W2[idx];
  for (int p = t; p < 484; p += 256){
    int xl = p / 22, yl = p - xl * 22;
    int X = x0 - 3 + xl, Y = y0 - 3 + yl;
    uint4 u0, u1, u2, u3;
    if (X >= 0 && X < NS && Y >= 0 && Y < NS){
      float xr[32];
      ld32f(xmsi + ((size_t)b * NN + (size_t)Y * NS + X) * NC, xr);
      u0 = pack8(xr); u1 = pack8(xr + 8); u2 = pack8(xr + 16); u3 = pack8(xr + 24);
    } else {
      u0 = u1 = u2 = u3 = make_uint4(0, 0, 0, 0);
    }
    tile[0][xl][yl] = u0; tile[1][xl][yl] = u1; tile[2][xl][yl] = u2; tile[3][xl][yl] = u3;
  }
  __syncthreads();
  int j = t & 15, i = t >> 4;     // j: y (h), i: x (w)
  float m1 = 0.f, m2 = 0.f;
  for (int aw = 0; aw < 7; aw++){
    for (int ah = 0; ah < 7; ah++){
      const float* wr = &W2s[(aw * 7 + ah) * 32];
      float s = 0.f;
      #pragma unroll
      for (int c = 0; c < 4; c++){
        uint4 u = tile[c][i + aw][j + ah];
        float g[8]; dec8(u, g);
        #pragma unroll
        for (int k = 0; k < 8; k++) s += g[k] * wr[c * 8 + k];
      }
      m2 += s;
    }
  }
  for (int aw = 0; aw < 3; aw++){
    for (int ah = 0; ah < 3; ah++){
      const float* wr = &W1s[(aw * 3 + ah) * 32];
      float s = 0.f;
      #pragma unroll
      for (int c = 0; c < 4; c++){
        uint4 u = tile[c][i + aw + 2][j + ah + 2];
        float g[8]; dec8(u, g);
        #pragma unroll
        for (int k = 0; k < 8; k++) s += g[k] * wr[c * 8 + k];
      }
      m1 += s;
    }
  }
  float m = sac3[0] * m1 + sac3[1] * m2;
  float sg = sigmoidf_(m);
  int x = x0 + i, y = y0 + j;
  out_sm[(size_t)b * NN + (size_t)x * NS + y] = sg;   // (b,1,w,h): w-major
}

// ----------------------- R6 SPLIT: vgate — f32 V-proj + gate, 2 px/thread, no halo
__global__ __launch_bounds__(256) void vgate_kernel(
    const float* __restrict__ xfu, const float* __restrict__ Wv,
    const float* __restrict__ out_sm, const float* __restrict__ cmaskf,
    u16* __restrict__ gv){
  __shared__ alignas(16) float WvL[1024];       // [i][o]
  __shared__ float cml[NC];
  int t = threadIdx.x;
  int b = blockIdx.x >> 7;                      // 512 blocks: 128 per batch, 2 rows each
  int px0 = blockIdx.x * 512 + t;               // (X = t, Y = 2*(blk&127))
  int px1 = px0 + 256;                          // (X = t, Y+1)
  int X = t;
  int Y0 = (px0 >> 8) & 255;

  for (int idx = t; idx < 1024; idx += 256){
    int oo = idx >> 5, ii = idx & 31;
    WvL[ii * 32 + oo] = Wv[idx];                // Wv[o][i] -> [i][o]
  }
  if (t < 32) cml[t] = cmaskf[b * 32 + t];
  __syncthreads();

  float xr0[32], xr1[32];
  ld32f(xfu + (size_t)px0 * NC, xr0);
  ld32f(xfu + (size_t)px1 * NC, xr1);
  float sm0 = out_sm[(size_t)b * NN + (size_t)X * NS + Y0];
  float sm1 = out_sm[(size_t)b * NN + (size_t)X * NS + Y0 + 1];

  float vo0[32], vo1[32];
  #pragma unroll
  for (int q = 0; q < 32; q++){ vo0[q] = 0.f; vo1[q] = 0.f; }
  for (int i = 0; i < 32; i++){
    const float4* wr = (const float4*)&WvL[i * 32];
    float a0 = xr0[i], a1 = xr1[i];
    #pragma unroll
    for (int q = 0; q < 8; q++){
      float4 w4 = wr[q];
      vo0[4 * q]     += a0 * w4.x;  vo1[4 * q]     += a1 * w4.x;
      vo0[4 * q + 1] += a0 * w4.y;  vo1[4 * q + 1] += a1 * w4.y;
      vo0[4 * q + 2] += a0 * w4.z;  vo1[4 * q + 2] += a1 * w4.z;
      vo0[4 * q + 3] += a0 * w4.w;  vo1[4 * q + 3] += a1 * w4.w;
    }
  }
  float g0[32], g1[32];
  #pragma unroll
  for (int c = 0; c < 32; c++){
    float cm = cml[c];
    g0[c] = vo0[c] * sm0 * cm;
    g1[c] = vo1[c] * sm1 * cm;
  }
  uint4* d0 = (uint4*)(gv + (size_t)px0 * NC);
  uint4* d1 = (uint4*)(gv + (size_t)px1 * NC);
  d0[0] = pack8(g0);  d0[1] = pack8(g0 + 8);  d0[2] = pack8(g0 + 16);  d0[3] = pack8(g0 + 24);
  d1[0] = pack8(g1);  d1[1] = pack8(g1 + 8);  d1[2] = pack8(g1 + 16);  d1[3] = pack8(g1 + 24);
}

// ------------------- R6 SPLIT: vconv — pos1-pattern MFMA conv3x3 + xhsi residual
__global__ __launch_bounds__(256) void vconv_mfma_kernel(
    const u16* __restrict__ gv, const u16* __restrict__ wAv,
    const float* __restrict__ xhsi, u16* __restrict__ vspec_g){
  int t = threadIdx.x;
  int wv = t >> 6, l = t & 63;
  int lp = l & 15, lk = l >> 4;                 // fragment pixel / k-chunk
  int b = blockIdx.x >> 8, Y = blockIdx.x & 255;

  bf16x8 wf[9][2];
  #pragma unroll
  for (int r = 0; r < 9; r++){
    wf[r][0] = *(const bf16x8*)(wAv + ((r * 32 + lp) * 32 + lk * 8));
    wf[r][1] = *(const bf16x8*)(wAv + ((r * 32 + 16 + lp) * 32 + lk * 8));
  }

  const u16* src = gv + (size_t)b * NN * NC;
  const float* res = xhsi + (size_t)b * NN * NC;
  u16* dst = vspec_g + (size_t)b * NN * NC;

  for (int g = 0; g < 4; g++){
    int X0 = wv * 64 + g * 16;
    f32x4 acc0 = {0.f, 0.f, 0.f, 0.f};
    f32x4 acc1 = {0.f, 0.f, 0.f, 0.f};
    #pragma unroll
    for (int dh = -1; dh <= 1; dh++){
      int Yi = Y + dh;
      if ((unsigned)Yi < NS){                   // uniform skip = zero-pad rows
        const u16* row = src + (size_t)Yi * (NS * NC) + lk * 8;
        #pragma unroll
        for (int dw = -1; dw <= 1; dw++){
          int Xi = X0 + lp + dw;
          uint4 u = make_uint4(0, 0, 0, 0);
          if (dw == 0 || (unsigned)Xi < NS) u = *(const uint4*)(row + Xi * NC);
          bf16x8 bfr = __builtin_bit_cast(bf16x8, u);
          const int r = (dw + 1) * 3 + (dh + 1);
          acc0 = __builtin_amdgcn_mfma_f32_16x16x32_bf16(wf[r][0], bfr, acc0, 0, 0, 0);
          acc1 = __builtin_amdgcn_mfma_f32_16x16x32_bf16(wf[r][1], bfr, acc1, 0, 0, 0);
        }
      }
    }
    // D: col=lp=pixel, rows = lk*4+j (+16 for tile 1) = out channel; + residual
    size_t n = (size_t)Y * NS + (X0 + lp);
    float4 rA = *(const float4*)(res + n * NC + lk * 4);
    float4 rB = *(const float4*)(res + n * NC + lk * 4 + 16);
    float v0 = acc0.x + rA.x;
    float v1 = acc0.y + rA.y;
    float v2 = acc0.z + rA.z;
    float v3 = acc0.w + rA.w;
    float v4 = acc1.x + rB.x;
    float v5 = acc1.y + rB.y;
    float v6 = acc1.z + rB.z;
    float v7 = acc1.w + rB.w;
    u16* dp = dst + n * NC + lk * 4;
    *(uint2*)dp = make_uint2((u32)f2bf(v0) | ((u32)f2bf(v1) << 16),
                             (u32)f2bf(v2) | ((u32)f2bf(v3) << 16));
    *(uint2*)(dp + 16) = make_uint2((u32)f2bf(v4) | ((u32)f2bf(v5) << 16),
                                    (u32)f2bf(v6) | ((u32)f2bf(v7) << 16));
  }
}

// ---------------- FALLBACK: fused V-proj + gate + conv + residual (R4, proven)
__global__ __launch_bounds__(256) void vspec_kernel(
    const float* __restrict__ xfu, const float* __restrict__ Wv,
    const float* __restrict__ attnW, const float* __restrict__ out_sm,
    const float* __restrict__ cmaskf, const float* __restrict__ xhsi,
    u16* __restrict__ vspec_g){
  __shared__ u16 gv[32 * 10 * 40];              // [c][xl][yl(34,pad40)] gated v, bf16
  __shared__ u16 Wl[9 * 32 * 32];               // [r][i][o] bf16, r = aw*3+ah
  __shared__ alignas(16) float WvL[1024];       // [i][o]
  __shared__ float cml[32];
  int t = threadIdx.x;
  int b = blockIdx.z;
  int x0 = blockIdx.x * 8, y0 = blockIdx.y * 32;

  for (int idx = t; idx < 1024; idx += 256){
    int oo = idx >> 5, ii = idx & 31;
    WvL[ii * 32 + oo] = Wv[idx];                // Wv[o][i] -> [i][o]
  }
  if (t < 32) cml[t] = cmaskf[b * 32 + t];
  __syncthreads();

  for (int idx = t; idx < 9216; idx += 256){
    int oo = idx / 288;
    int rem = idx - oo * 288;
    int ii = rem / 9;
    int r = rem - ii * 9;
    Wl[(r * 32 + ii) * 32 + oo] = f2bf(attnW[idx]);
  }
  for (int p = t; p < 340; p += 256){           // 10 x 34 halo tile
    int xl = p / 34, yl = p - xl * 34;
    int X = x0 - 1 + xl, Y = y0 - 1 + yl;       // X: w, Y: h
    u16* dst = &gv[xl * 40 + yl];               // + c*400 per channel
    if (X >= 0 && X < NS && Y >= 0 && Y < NS){
      float xr[32];
      ld32f(xfu + ((size_t)b * NN + (size_t)Y * NS + X) * NC, xr);
      float sm = out_sm[(size_t)b * NN + (size_t)X * NS + Y];
      float vo[32];
      #pragma unroll
      for (int q = 0; q < 32; q++) vo[q] = 0.f;
      for (int i = 0; i < 32; i++){
        const float4* wr = (const float4*)&WvL[i * 32];
        float xv = xr[i];
        #pragma unroll
        for (int q = 0; q < 8; q++){
          float4 w4 = wr[q];
          vo[4 * q]     += xv * w4.x;
          vo[4 * q + 1] += xv * w4.y;
          vo[4 * q + 2] += xv * w4.z;
          vo[4 * q + 3] += xv * w4.w;
        }
      }
      #pragma unroll
      for (int c = 0; c < 32; c++) dst[c * 400] = f2bf(vo[c] * sm * cml[c]);
    } else {
      #pragma unroll
      for (int c = 0; c < 32; c++) dst[c * 400] = 0;
    }
  }
  __syncthreads();

  int o = t & 31, xs = t >> 5;
  float acc[32];
  #pragma unroll
  for (int yy = 0; yy < 32; yy++) acc[yy] = 0.f;
  #pragma unroll
  for (int aw = 0; aw < 3; aw++){
    for (int i2 = 0; i2 < 32; i2++){
      const uint4* rp = (const uint4*)(gv + (i2 * 10 + xs + aw) * 40);
      uint4 r0 = rp[0], r1 = rp[1], r2 = rp[2], r3 = rp[3], r4 = rp[4];
      float g[40];
      dec8(r0, g); dec8(r1, g + 8); dec8(r2, g + 16); dec8(r3, g + 24); dec8(r4, g + 32);
      const int wb = (aw * 3 * 32 + i2) * 32 + o;
      float w0 = bf2f(Wl[wb]);
      float w1 = bf2f(Wl[wb + 1024]);
      float w2 = bf2f(Wl[wb + 2048]);
      #pragma unroll
      for (int yy = 0; yy < 32; yy++)
        acc[yy] = fmaf(g[yy], w0, fmaf(g[yy + 1], w1, fmaf(g[yy + 2], w2, acc[yy])));
    }
  }
  int x = x0 + xs;
  #pragma unroll
  for (int yy = 0; yy < 32; yy++){
    size_t n = (size_t)b * NN + (size_t)(y0 + yy) * NS + x;
    vspec_g[n * NC + o] = f2bf(acc[yy] + xhsi[n * NC + o]);
  }
}

// ------------------------- SPLIT PATH R5: MFMA pos1 (vspec -> t), no LDS
// Wave handles 4 groups of 16 consecutive X at fixed Y. A=W[r][o][i], B=vspec px.
__global__ __launch_bounds__(256) void pos1_mfma_kernel(
    const u16* __restrict__ vspec_g, const u16* __restrict__ wA,
    const float* __restrict__ pos1b, u16* __restrict__ t_g){
  int t = threadIdx.x;
  int wv = t >> 6, l = t & 63;
  int lp = l & 15, lk = l >> 4;                 // fragment pixel / k-chunk
  int b = blockIdx.x >> 8, Y = blockIdx.x & 255;

  bf16x8 wf[9][2];
  #pragma unroll
  for (int r = 0; r < 9; r++){
    wf[r][0] = *(const bf16x8*)(wA + ((r * 32 + lp) * 32 + lk * 8));
    wf[r][1] = *(const bf16x8*)(wA + ((r * 32 + 16 + lp) * 32 + lk * 8));
  }
  float bs[8];
  #pragma unroll
  for (int j = 0; j < 4; j++){
    bs[j]     = pos1b[lk * 4 + j];
    bs[4 + j] = pos1b[16 + lk * 4 + j];
  }

  const u16* src = vspec_g + (size_t)b * NN * NC;
  u16* dst = t_g + (size_t)b * NN * NC;

  for (int g = 0; g < 4; g++){
    int X0 = wv * 64 + g * 16;
    f32x4 acc0 = {0.f, 0.f, 0.f, 0.f};
    f32x4 acc1 = {0.f, 0.f, 0.f, 0.f};
    #pragma unroll
    for (int dh = -1; dh <= 1; dh++){
      int Yi = Y + dh;
      if ((unsigned)Yi < NS){                   // uniform skip = zero-pad rows
        const u16* row = src + (size_t)Yi * (NS * NC) + lk * 8;
        #pragma unroll
        for (int dw = -1; dw <= 1; dw++){
          int Xi = X0 + lp + dw;
          uint4 u = make_uint4(0, 0, 0, 0);
          if (dw == 0 || (unsigned)Xi < NS) u = *(const uint4*)(row + Xi * NC);
          bf16x8 bfr = __builtin_bit_cast(bf16x8, u);
          const int r = (dw + 1) * 3 + (dh + 1);
          acc0 = __builtin_amdgcn_mfma_f32_16x16x32_bf16(wf[r][0], bfr, acc0, 0, 0, 0);
          acc1 = __builtin_amdgcn_mfma_f32_16x16x32_bf16(wf[r][1], bfr, acc1, 0, 0, 0);
        }
      }
    }
    // D: col=lp=pixel, rows = lk*4+j (+16 for tile 1) = out channel
    float v0 = gelu_exact(acc0.x + bs[0]);
    float v1 = gelu_exact(acc0.y + bs[1]);
    float v2 = gelu_exact(acc0.z + bs[2]);
    float v3 = gelu_exact(acc0.w + bs[3]);
    float v4 = gelu_exact(acc1.x + bs[4]);
    float v5 = gelu_exact(acc1.y + bs[5]);
    float v6 = gelu_exact(acc1.z + bs[6]);
    float v7 = gelu_exact(acc1.w + bs[7]);
    u16* dp = dst + ((size_t)Y * NS + (X0 + lp)) * NC + lk * 4;
    *(uint2*)dp = make_uint2((u32)f2bf(v0) | ((u32)f2bf(v1) << 16),
                             (u32)f2bf(v2) | ((u32)f2bf(v3) << 16));
    *(uint2*)(dp + 16) = make_uint2((u32)f2bf(v4) | ((u32)f2bf(v5) << 16),
                                    (u32)f2bf(v6) | ((u32)f2bf(v7) << 16));
  }
}

// -------------------- SPLIT PATH R5: MFMA pos2 (t -> out, + out1 epilogue), no LDS
// Wave handles 4 groups of 16 consecutive Y at fixed X (store (b,c,w,h) coalesced in h).
__global__ __launch_bounds__(256) void pos2_mfma_kernel(
    const u16* __restrict__ t_g, const u16* __restrict__ vspec_g,
    const u16* __restrict__ wA, const float* __restrict__ pos2b,
    const u16* __restrict__ Mbf, const float* __restrict__ projb,
    float* __restrict__ outp){
  int t = threadIdx.x;
  int wv = t >> 6, l = t & 63;
  int lp = l & 15, lk = l >> 4;
  int b = blockIdx.x >> 8, X = blockIdx.x & 255;

  bf16x8 wf[9][2];
  #pragma unroll
  for (int r = 0; r < 9; r++){
    wf[r][0] = *(const bf16x8*)(wA + ((r * 32 + lp) * 32 + lk * 8));
    wf[r][1] = *(const bf16x8*)(wA + ((r * 32 + 16 + lp) * 32 + lk * 8));
  }
  bf16x8 mf0 = *(const bf16x8*)(Mbf + ((b * 32 + lp) * 32 + lk * 8));
  bf16x8 mf1 = *(const bf16x8*)(Mbf + ((b * 32 + 16 + lp) * 32 + lk * 8));
  float b2s[8], pbs[8];
  #pragma unroll
  for (int j = 0; j < 4; j++){
    b2s[j]     = pos2b[lk * 4 + j];
    b2s[4 + j] = pos2b[16 + lk * 4 + j];
    pbs[j]     = projb[lk * 4 + j];
    pbs[4 + j] = projb[16 + lk * 4 + j];
  }

  const u16* tsrc = t_g + (size_t)b * NN * NC;
  const u16* vsrc = vspec_g + (size_t)b * NN * NC;
  float* ob0 = outp + (size_t)b * 32 * NN + (size_t)X * NS;

  for (int g = 0; g < 4; g++){
    int Y0 = wv * 64 + g * 16;
    int Yp = Y0 + lp;
    // epilogue GEMM first (independent chain): P = M @ vspec[px]
    f32x4 e0 = {0.f, 0.f, 0.f, 0.f};
    f32x4 e1 = {0.f, 0.f, 0.f, 0.f};
    {
      uint4 u = *(const uint4*)(vsrc + ((size_t)Yp * NS + X) * NC + lk * 8);
      bf16x8 bfr = __builtin_bit_cast(bf16x8, u);
      e0 = __builtin_amdgcn_mfma_f32_16x16x32_bf16(mf0, bfr, e0, 0, 0, 0);
      e1 = __builtin_amdgcn_mfma_f32_16x16x32_bf16(mf1, bfr, e1, 0, 0, 0);
    }
    f32x4 acc0 = {0.f, 0.f, 0.f, 0.f};
    f32x4 acc1 = {0.f, 0.f, 0.f, 0.f};
    #pragma unroll
    for (int dw = -1; dw <= 1; dw++){
      int Xi = X + dw;
      if ((unsigned)Xi < NS){                   // uniform skip = zero-pad cols
        const u16* col = tsrc + (size_t)Xi * NC + lk * 8;
        #pragma unroll
        for (int dh = -1; dh <= 1; dh++){
          int Yi = Yp + dh;
          uint4 u = make_uint4(0, 0, 0, 0);
          if (dh == 0 || (unsigned)Yi < NS) u = *(const uint4*)(col + (size_t)Yi * (NS * NC));
          bf16x8 bfr = __builtin_bit_cast(bf16x8, u);
          const int r = (dw + 1) * 3 + (dh + 1);
          acc0 = __builtin_amdgcn_mfma_f32_16x16x32_bf16(wf[r][0], bfr, acc0, 0, 0, 0);
          acc1 = __builtin_amdgcn_mfma_f32_16x16x32_bf16(wf[r][1], bfr, acc1, 0, 0, 0);
        }
      }
    }
    float r0 = acc0.x + b2s[0] + gelu_exact(e0.x + pbs[0]);
    float r1 = acc0.y + b2s[1] + gelu_exact(e0.y + pbs[1]);
    float r2 = acc0.z + b2s[2] + gelu_exact(e0.z + pbs[2]);
    float r3 = acc0.w + b2s[3] + gelu_exact(e0.w + pbs[3]);
    float r4 = acc1.x + b2s[4] + gelu_exact(e1.x + pbs[4]);
    float r5 = acc1.y + b2s[5] + gelu_exact(e1.y + pbs[5]);
    float r6 = acc1.z + b2s[6] + gelu_exact(e1.z + pbs[6]);
    float r7 = acc1.w + b2s[7] + gelu_exact(e1.w + pbs[7]);
    float* ob = ob0 + Yp + (size_t)(lk * 4) * NN;   // channel lk*4, + c*NN per channel
    ob[0]                 = r0;
    ob[(size_t)NN]        = r1;
    ob[(size_t)2 * NN]    = r2;
    ob[(size_t)3 * NN]    = r3;
    float* ob2 = ob + (size_t)16 * NN;
    ob2[0]                = r4;
    ob2[(size_t)NN]       = r5;
    ob2[(size_t)2 * NN]   = r6;
    ob2[(size_t)3 * NN]   = r7;
  }
}

// ------------------------- FALLBACK PATH (ws too small): R3's fused pos_out, proven
__global__ __launch_bounds__(320) void pos_out_kernel(
    const u16* __restrict__ vspec_g, const u16* __restrict__ wt1,
    const u16* __restrict__ wt2, const float* __restrict__ pos1b,
    const float* __restrict__ pos2b, const float* __restrict__ Mf,
    const float* __restrict__ projb, float* __restrict__ outp){
  __shared__ u16 vs[32 * 12 * 40];    // [i][vxl(12)][vyl(36,pad40)]
  __shared__ u16 tt[32 * 10 * 40];    // [o][txl(10)][tyl(34,pad40)]
  __shared__ u16 wsl[3072];           // one aw-slice: [ah][i][o]
  int t = threadIdx.x;
  int b = blockIdx.z;
  int x0 = blockIdx.x * 8, y0 = blockIdx.y * 32;
  int o = t & 31, xsl = t >> 5;       // xsl in [0,10)

  for (int p = t; p < 12 * 36; p += 320){
    int vxl = p / 36, vyl = p - vxl * 36;
    int X = x0 - 2 + vxl, Y = y0 - 2 + vyl;
    u16* dst = &vs[vxl * 40 + vyl];
    if (X >= 0 && X < NS && Y >= 0 && Y < NS){
      const uint4* src = (const uint4*)(vspec_g + ((size_t)b * NN + (size_t)Y * NS + X) * NC);
      uint4 u0 = src[0], u1 = src[1], u2 = src[2], u3 = src[3];
      alignas(16) u16 raw[32];
      *(uint4*)(raw) = u0; *(uint4*)(raw + 8) = u1;
      *(uint4*)(raw + 16) = u2; *(uint4*)(raw + 24) = u3;
      #pragma unroll
      for (int i = 0; i < 32; i++) dst[i * 480] = raw[i];
    } else {
      #pragma unroll
      for (int i = 0; i < 32; i++) dst[i * 480] = 0;
    }
  }
  __syncthreads();

  float ta[34];
  #pragma unroll
  for (int k = 0; k < 34; k++) ta[k] = 0.f;
  for (int aw = 0; aw < 3; aw++){
    for (int idx = t; idx < 3072; idx += 320) wsl[idx] = wt1[aw * 3072 + idx];
    __syncthreads();
    for (int i2 = 0; i2 < 32; i2++){
      const uint4* rp = (const uint4*)(vs + (i2 * 12 + xsl + aw) * 40);
      uint4 r0 = rp[0], r1 = rp[1], r2 = rp[2], r3 = rp[3], r4 = rp[4];
      float g[40];
      dec8(r0, g); dec8(r1, g + 8); dec8(r2, g + 16); dec8(r3, g + 24); dec8(r4, g + 32);
      float w0 = bf2f(wsl[i2 * 32 + o]);
      float w1 = bf2f(wsl[i2 * 32 + o + 1024]);
      float w2 = bf2f(wsl[i2 * 32 + o + 2048]);
      #pragma unroll
      for (int yl = 0; yl < 34; yl++)
        ta[yl] = fmaf(g[yl], w0, fmaf(g[yl + 1], w1, fmaf(g[yl + 2], w2, ta[yl])));
    }
    __syncthreads();
  }
  {
    float b1 = pos1b[o];
    int X = x0 - 1 + xsl;
    bool colOK = (X >= 0 && X < NS);
    u16* trow = &tt[(o * 10 + xsl) * 40];
    #pragma unroll
    for (int yl = 0; yl < 34; yl++){
      int Y = y0 - 1 + yl;
      float val = (colOK && Y >= 0 && Y < NS) ? gelu_exact(ta[yl] + b1) : 0.f;
      trow[yl] = f2bf(val);
    }
  }
  __syncthreads();

  float acc2[32];
  #pragma unroll
  for (int yy = 0; yy < 32; yy++) acc2[yy] = 0.f;
  for (int aw = 0; aw < 3; aw++){
    for (int idx = t; idx < 3072; idx += 320) wsl[idx] = wt2[aw * 3072 + idx];
    __syncthreads();
    if (xsl < 8){
      for (int i2 = 0; i2 < 32; i2++){
        const uint4* rp = (const uint4*)(tt + (i2 * 10 + xsl + aw) * 40);
        uint4 r0 = rp[0], r1 = rp[1], r2 = rp[2], r3 = rp[3], r4 = rp[4];
        float g[40];
        dec8(r0, g); dec8(r1, g + 8); dec8(r2, g + 16); dec8(r3, g + 24); dec8(r4, g + 32);
        float w0 = bf2f(wsl[i2 * 32 + o]);
        float w1 = bf2f(wsl[i2 * 32 + o + 1024]);
        float w2 = bf2f(wsl[i2 * 32 + o + 2048]);
        #pragma unroll
        for (int yy = 0; yy < 32; yy++)
          acc2[yy] = fmaf(g[yy], w0, fmaf(g[yy + 1], w1, fmaf(g[yy + 2], w2, acc2[yy])));
      }
    }
    __syncthreads();
  }
  if (xsl < 8){
    int x = x0 + xsl;
    float m[32];
    {
      const float4* mp = (const float4*)(Mf + b * 1024 + o * 32);
      #pragma unroll
      for (int k = 0; k < 8; k++){
        float4 f = mp[k];
        m[4 * k] = f.x; m[4 * k + 1] = f.y; m[4 * k + 2] = f.z; m[4 * k + 3] = f.w;
      }
    }
    float pb = projb[o];
    float b2v = pos2b[o];
    float outv[32];
    #pragma unroll
    for (int yy = 0; yy < 32; yy++){
      size_t n = (size_t)b * NN + (size_t)(y0 + yy) * NS + x;
      const uint4* xp = (const uint4*)(vspec_g + n * NC);
      uint4 u0 = xp[0], u1 = xp[1], u2 = xp[2], u3 = xp[3];
      float xr[32];
      dec8(u0, xr); dec8(u1, xr + 8); dec8(u2, xr + 16); dec8(u3, xr + 24);
      float s = pb;
      #pragma unroll
      for (int i2 = 0; i2 < 32; i2++) s += m[i2] * xr[i2];
      outv[yy] = acc2[yy] + b2v + gelu_exact(s);
    }
    float4* dp = (float4*)(outp + (((size_t)(b * 32 + o) * NS) + x) * NS + y0);
    #pragma unroll
    for (int k = 0; k < 8; k++)
      dp[k] = make_float4(outv[4 * k], outv[4 * k + 1], outv[4 * k + 2], outv[4 * k + 3]);
  }
}

// ---------------------------------------------------------------------- launch
extern "C" void kernel_launch(void* const* d_in, const int* in_sizes, int n_in,
                              void* d_out, int out_size, void* d_ws, size_t ws_size,
                              hipStream_t stream){
  (void)in_sizes; (void)n_in; (void)out_size;
  const float* xfu   = (const float*)d_in[0];
  const float* xmsi  = (const float*)d_in[1];
  const float* xhsi  = (const float*)d_in[2];
  const float* Wq    = (const float*)d_in[3];
  const float* Wk    = (const float*)d_in[4];
  const float* Wv    = (const float*)d_in[5];
  const float* projW = (const float*)d_in[6];
  const float* projb = (const float*)d_in[7];
  const float* pos1W = (const float*)d_in[8];
  const float* pos1b = (const float*)d_in[9];
  const float* pos2W = (const float*)d_in[10];
  const float* pos2b = (const float*)d_in[11];
  const float* cafc1 = (const float*)d_in[12];
  const float* cafc2 = (const float*)d_in[13];
  const float* sac1a = (const float*)d_in[14];
  const float* sac1b = (const float*)d_in[15];
  const float* sac2a = (const float*)d_in[16];
  const float* sac2b = (const float*)d_in[17];
  const float* sac3  = (const float*)d_in[18];
  const float* attnW = (const float*)d_in[19];

  float* out = (float*)d_out;
  float* out_main = out;                  // (b,c,w,h) 8388608 f32
  float* out_cm   = out + 8388608;        // 128
  float* out_sm   = out + 8388736;        // 262144

  // workspace map: sums[0,512) S[1024,17408) cmask[17920] W1[18432] W2[20480]
  // Mf[28672,45056) wt1[45056] wt2[63488] wA1[81920] wA2[100352] Mbf[118784,126976)
  // vspec [131072,+16M) (first 2MB doubles as pbufT, dead before vconv),
  // t/gv [+16M,+32M)  (gv aliases t_g: disjoint lifetimes)
  char* ws = (char*)d_ws;
  float* sums   = (float*)(ws + 0);         // 128 f (zeroed with S: 4352 f total)
  float* Sm     = (float*)(ws + 1024);      // 4096 f = [4][32][32]
  float* cmaskf = (float*)(ws + 17920);     // 128 f
  float* W1     = (float*)(ws + 18432);     // 288 f
  float* W2     = (float*)(ws + 20480);     // 1568 f
  float* Mf     = (float*)(ws + 28672);     // 4096 f
  u16*   wt1    = (u16*)(ws + 45056);       // 9216 bf16 [r][i][o] (fallback) / wAv (split)
  u16*   wt2    = (u16*)(ws + 63488);       // 9216 bf16
  u16*   wA1    = (u16*)(ws + 81920);       // 9216 bf16 [r][o][i] (MFMA)
  u16*   wA2    = (u16*)(ws + 100352);      // 9216 bf16
  u16*   Mbf    = (u16*)(ws + 118784);      // 4096 bf16 [b][o][i]
  u16*   vspec  = (u16*)(ws + 131072);      // 16 MB bf16 (b,n,c)
  float* pbufT  = (float*)(ws + 131072);    // 2 MB partials [4096][128] (dead pre-vconv)
  u16*   t_g    = (u16*)(ws + 131072 + 16777216);   // 16 MB bf16 (split path only)
  const bool split = ws_size >= (size_t)(131072 + 2 * 16777216);
  u16*   wAv    = split ? wt1 : wA1;        // split: wt1 slot free; fallback: dummy
  u16*   gvbuf  = t_g;                      // gv dies before pos1 writes t_g

  pre_kernel<<<64, 256, 0, stream>>>(sac1a, sac1b, sac2a, sac2b, pos1W, pos2W, attnW,
                                     sums, W1, W2, wt1, wt2, wA1, wA2, wAv,
                                     split ? 0 : 1);
  channel_sum_kernel<<<256, 256, 0, stream>>>(xhsi, sums);
  spatial_mask_kernel<<<dim3(16, 16, NB), 256, 0, stream>>>(xmsi, W1, W2, sac3, out_sm);
  x2_kernel<<<512, 256, 0, stream>>>(xfu, pbufT);
  x2r_kernel<<<64, 64, 0, stream>>>(pbufT, Sm);
  mid_kernel<<<1, 256, 0, stream>>>(sums, cafc1, cafc2, cmaskf, out_cm,
                                    Sm, Wq, Wk, projW, Mf, Mbf);
  if (split){
    vgate_kernel<<<512, 256, 0, stream>>>(xfu, Wv, out_sm, cmaskf, gvbuf);
    vconv_mfma_kernel<<<1024, 256, 0, stream>>>(gvbuf, wAv, xhsi, vspec);
    pos1_mfma_kernel<<<1024, 256, 0, stream>>>(vspec, wA1, pos1b, t_g);
    pos2_mfma_kernel<<<1024, 256, 0, stream>>>(t_g, vspec, wA2, pos2b, Mbf, projb, out_main);
  } else {
    vspec_kernel<<<dim3(32, 8, NB), 256, 0, stream>>>(
        xfu, Wv, attnW, out_sm, cmaskf, xhsi, vspec);
    pos_out_kernel<<<dim3(32, 8, NB), 320, 0, stream>>>(
        vspec, wt1, wt2, pos1b, pos2b, Mf, projb, out_main);
  }
}

// Round 11
// 336.358 us; speedup vs baseline: 1.8392x; 1.0757x over previous
//
#include <hip/hip_runtime.h>
#include <hip/hip_bf16.h>

// Self_mask_Spectral_MSA on MI355X — Round 13 resubmit (R13 bench was an infra failure:
// "MI355X container failed twice", same signature as R1 which passed on resubmit).
// B=4, H=W=256, C=32, heads=4, d=8. f32 I/O, fp32 accumulation, bf16 intermediates.
//
// R13 changes vs R12 (passed, 362us):
//  - R12 post-mortem: spatial_mask pad 25->26 did NOT move SQ_LDS_BANK_CONFLICT
//    (3,866,624 bit-identical). Correct model: b128 conflict unit is the 16B bank
//    QUAD (idx mod 8); (s*i+j) mod 8 gives 8 lanes/quad for ANY stride (j covers
//    each quad twice). 64 lanes x 16B = 8 LDS cycles minimum — intrinsic, not
//    paddable. The real cost: VALUBusy 44% x 65us ~ 29us, half of it dec8 unpack.
//  - Fix: tile stored as f16 (better mantissa than bf16), weights as packed half2;
//    hot loop uses __builtin_amdgcn_fdot2 (v_dot2_f32_f16: 2 MACs, f32 accum,
//    no unpack): 16 dot2/tap vs 32 unpack + 32 FMA. 4 independent acc chains.
//    LDS ~40KB. Numerically >= previous bf16 path.
//  - Everything else unchanged from R12.

#define NB 4
#define NC 32
#define NS 256
#define NN 65536

typedef unsigned short u16;
typedef unsigned int u32;
typedef __bf16 bf16x8 __attribute__((ext_vector_type(8)));
typedef float f32x4 __attribute__((ext_vector_type(4)));
typedef _Float16 f16x2 __attribute__((ext_vector_type(2)));

__device__ __forceinline__ float bf2f(u16 s){ return __uint_as_float(((u32)s) << 16); }
__device__ __forceinline__ u16 f2bf(float x){
  u32 u = __float_as_uint(x);
  u32 r = (u + 0x7fffu + ((u >> 16) & 1u)) >> 16;   // RNE
  return (u16)r;
}
__device__ __forceinline__ void dec8(uint4 u, float* f){
  f[0] = __uint_as_float((u.x & 0xffffu) << 16);
  f[1] = __uint_as_float(u.x & 0xffff0000u);
  f[2] = __uint_as_float((u.y & 0xffffu) << 16);
  f[3] = __uint_as_float(u.y & 0xffff0000u);
  f[4] = __uint_as_float((u.z & 0xffffu) << 16);
  f[5] = __uint_as_float(u.z & 0xffff0000u);
  f[6] = __uint_as_float((u.w & 0xffffu) << 16);
  f[7] = __uint_as_float(u.w & 0xffff0000u);
}
__device__ __forceinline__ void ld32f(const float* __restrict__ p, float* x){
  const float4* q = (const float4*)p;
  #pragma unroll
  for (int k = 0; k < 8; k++){
    float4 f = q[k];
    x[4 * k] = f.x; x[4 * k + 1] = f.y; x[4 * k + 2] = f.z; x[4 * k + 3] = f.w;
  }
}
__device__ __forceinline__ uint4 pack8(const float* f){
  uint4 u;
  u.x = (u32)f2bf(f[0]) | ((u32)f2bf(f[1]) << 16);
  u.y = (u32)f2bf(f[2]) | ((u32)f2bf(f[3]) << 16);
  u.z = (u32)f2bf(f[4]) | ((u32)f2bf(f[5]) << 16);
  u.w = (u32)f2bf(f[6]) | ((u32)f2bf(f[7]) << 16);
  return u;
}
__device__ __forceinline__ u32 pkh(float a, float b){
  return __builtin_bit_cast(u32, __builtin_amdgcn_cvt_pkrtz(a, b));
}
__device__ __forceinline__ uint4 pack8h(const float* f){
  uint4 u;
  u.x = pkh(f[0], f[1]);
  u.y = pkh(f[2], f[3]);
  u.z = pkh(f[4], f[5]);
  u.w = pkh(f[6], f[7]);
  return u;
}
__device__ __forceinline__ f16x2 h2(u32 v){ return __builtin_bit_cast(f16x2, v); }
__device__ __forceinline__ float gelu_exact(float x){
  return 0.5f * x * (1.0f + erff(x * 0.70710678118654752f));
}
__device__ __forceinline__ float sigmoidf_(float x){ return 1.0f / (1.0f + expf(-x)); }

// ------- pre: zero accumulators + fold SA weights + transpose pos weights (R12: 64 blocks)
#define PRE_NT 16384
__global__ __launch_bounds__(256) void pre_kernel(
    const float* __restrict__ c1a, const float* __restrict__ c1b,
    const float* __restrict__ c2a, const float* __restrict__ c2b,
    const float* __restrict__ p1, const float* __restrict__ p2,
    const float* __restrict__ aw,
    float* __restrict__ zbase, float* __restrict__ W1, float* __restrict__ W2,
    u16* __restrict__ wt1, u16* __restrict__ wt2,
    u16* __restrict__ wA1, u16* __restrict__ wA2,
    u16* __restrict__ wAv, int fb){
  int gid = blockIdx.x * 256 + threadIdx.x;
  for (int i = gid; i < 4352; i += PRE_NT) zbase[i] = 0.f;     // sums(128) + S(4096 @ +256)
  for (int idx = gid; idx < 288; idx += PRE_NT){               // W1[r*32+j]
    int r = idx >> 5, j = idx & 31;
    float s0 = 0.f, s1 = 0.f, s2 = 0.f, s3 = 0.f;
    #pragma unroll
    for (int i = 0; i < 32; i += 4){
      s0 += c1b[i]     * c1a[((i)     * 32 + j) * 9 + r];
      s1 += c1b[i + 1] * c1a[((i + 1) * 32 + j) * 9 + r];
      s2 += c1b[i + 2] * c1a[((i + 2) * 32 + j) * 9 + r];
      s3 += c1b[i + 3] * c1a[((i + 3) * 32 + j) * 9 + r];
    }
    W1[idx] = (s0 + s1) + (s2 + s3);
  }
  for (int idx = gid; idx < 1568; idx += PRE_NT){              // W2[r*32+j]
    int r = idx >> 5, j = idx & 31;
    float s0 = 0.f, s1 = 0.f, s2 = 0.f, s3 = 0.f;
    #pragma unroll
    for (int i = 0; i < 32; i += 4){
      s0 += c2b[i]     * c2a[((i)     * 32 + j) * 49 + r];
      s1 += c2b[i + 1] * c2a[((i + 1) * 32 + j) * 49 + r];
      s2 += c2b[i + 2] * c2a[((i + 2) * 32 + j) * 49 + r];
      s3 += c2b[i + 3] * c2a[((i + 3) * 32 + j) * 49 + r];
    }
    W2[idx] = (s0 + s1) + (s2 + s3);
  }
  for (int idx = gid; idx < 9216; idx += PRE_NT){              // OIHW -> layouts
    int o = idx / 288;
    int rem = idx - o * 288;
    int i = rem / 9;
    int r = rem - i * 9;
    u16 w1v = f2bf(p1[idx]);
    u16 w2v = f2bf(p2[idx]);
    if (fb){
      wt1[(r * 32 + i) * 32 + o] = w1v;    // [r][i][o]  (fallback path only)
      wt2[(r * 32 + i) * 32 + o] = w2v;
    }
    wA1[(r * 32 + o) * 32 + i] = w1v;      // [r][o][i]  (MFMA A-fragments)
    wA2[(r * 32 + o) * 32 + i] = w2v;
    wAv[(r * 32 + o) * 32 + i] = f2bf(aw[idx]);
  }
}

// ---------------------------------------------------------------- channel sums
__global__ __launch_bounds__(256) void channel_sum_kernel(const float* __restrict__ xhsi,
                                                          float* __restrict__ sums){
  int b = blockIdx.x >> 6;
  int blk = blockIdx.x & 63;
  const float* p = xhsi + (size_t)b * NN * NC;
  int t = threadIdx.x;
  int base = blk * 32768;
  float acc = 0.f;
  for (int k = 0; k < 128; k++) acc += p[base + t + k * 256];
  __shared__ float red[256];
  red[t] = acc;
  __syncthreads();
  if (t < 32){
    float s = 0.f;
    #pragma unroll
    for (int k = 0; k < 8; k++) s += red[t + k * 32];     // channel of red[j] is j&31
    atomicAdd(&sums[b * 32 + t], s);
  }
}

// -------- R11: S = X^T X per batch, stage 1: per-block partials, NO atomics.
__global__ __launch_bounds__(256) void x2_kernel(const float* __restrict__ xfu,
                                                 float* __restrict__ pbufT){
  __shared__ float xs[256 * NC];                 // 32KB: [row][ch]
  __shared__ float red[4][64][17];               // pad 17: spread write banks
  int t = threadIdx.x;
  int bid = blockIdx.x;
  int b = bid >> 7, j = bid & 127;               // 128 blocks per batch
  int wv = t >> 6, l = t & 63;
  int o = l & 31, ebase = (l >> 5) * 16;
  float acc[16];
  #pragma unroll
  for (int q = 0; q < 16; q++) acc[q] = 0.f;
  for (int c = 0; c < 2; c++){
    const float* src = xfu + (size_t)(bid * 2 + c) * 256 * NC;
    #pragma unroll
    for (int q = 0; q < 32; q++) xs[t + q * 256] = src[t + q * 256];
    __syncthreads();
    const float* rp = xs + wv * 64 * NC;
    #pragma unroll 4
    for (int r = 0; r < 64; r++){
      const float* row = rp + r * NC;
      float xo = row[o];
      const float4* ep = (const float4*)(row + ebase);
      float4 e0 = ep[0], e1 = ep[1], e2 = ep[2], e3 = ep[3];
      acc[0]  += xo * e0.x; acc[1]  += xo * e0.y; acc[2]  += xo * e0.z; acc[3]  += xo * e0.w;
      acc[4]  += xo * e1.x; acc[5]  += xo * e1.y; acc[6]  += xo * e1.z; acc[7]  += xo * e1.w;
      acc[8]  += xo * e2.x; acc[9]  += xo * e2.y; acc[10] += xo * e2.z; acc[11] += xo * e2.w;
      acc[12] += xo * e3.x; acc[13] += xo * e3.y; acc[14] += xo * e3.z; acc[15] += xo * e3.w;
    }
    __syncthreads();                             // xs dead before next stage
  }
  #pragma unroll
  for (int q = 0; q < 16; q++) red[wv][l][q] = acc[q];
  __syncthreads();
  #pragma unroll
  for (int k = 0; k < 4; k++){
    int idx = t * 4 + k;
    int ll = idx >> 4, jj = idx & 15;
    float s = red[0][ll][jj] + red[1][ll][jj] + red[2][ll][jj] + red[3][ll][jj];
    int oo = ll & 31, eb = (ll >> 5) * 16;
    int e = oo * 32 + eb + jj;
    pbufT[((size_t)b * 1024 + e) * 128 + j] = s;   // plain store, no atomic
  }
}

// -------- R11: stage 2 — sum 128 contiguous partials per entry -> S[4096].
__global__ __launch_bounds__(64) void x2r_kernel(const float* __restrict__ pbufT,
                                                 float* __restrict__ S){
  int out = blockIdx.x * 64 + threadIdx.x;       // [0,4096)
  const float4* pp = (const float4*)(pbufT + (size_t)out * 128);
  float a0 = 0.f, a1 = 0.f, a2 = 0.f, a3 = 0.f;  // 4 independent chains
  #pragma unroll
  for (int k = 0; k < 32; k += 4){
    float4 v0 = pp[k], v1 = pp[k + 1], v2 = pp[k + 2], v3 = pp[k + 3];
    a0 += v0.x + v0.y + v0.z + v0.w;
    a1 += v1.x + v1.y + v1.z + v1.w;
    a2 += v2.x + v2.y + v2.z + v2.w;
    a3 += v3.x + v3.y + v3.z + v3.w;
  }
  S[out] = (a0 + a1) + (a2 + a3);
}

// --- mid: channel mask (sigmoid MLP) + attention softmax from S + M fold
// R8: all stride-32 LDS arrays padded to 33 (bank-conflict fix).
__global__ __launch_bounds__(256) void mid_kernel(
    const float* __restrict__ sums, const float* __restrict__ fc1,
    const float* __restrict__ fc2, float* __restrict__ cmaskf, float* __restrict__ out_cm,
    const float* __restrict__ S, const float* __restrict__ Wq, const float* __restrict__ Wk,
    const float* __restrict__ projW, float* __restrict__ Mf, u16* __restrict__ Mbf){
  __shared__ float avg[NB][NC], hid[NB][NC];
  __shared__ float attn_s[16][65];
  __shared__ float Wqs[32][33], Wks[32][33];
  __shared__ float Ss[4][32][33];
  __shared__ float Ts[4][32][33], Us[4][32][33];
  __shared__ float nq2[4][32], nk2[4][32];
  int t = threadIdx.x;
  for (int idx = t; idx < 1024; idx += 256){
    Wqs[idx >> 5][idx & 31] = Wq[idx];
    Wks[idx >> 5][idx & 31] = Wk[idx];
  }
  for (int idx = t; idx < 4096; idx += 256)
    Ss[idx >> 10][(idx >> 5) & 31][idx & 31] = S[idx];
  if (t < 128){
    int b = t >> 5, o = t & 31;
    avg[b][o] = sums[t] * (1.0f / 65536.0f);
  }
  __syncthreads();
  // T = S·Wq^T, U = S·Wk^T  (T[b][i][c] = sum_j S[b][i][j]·Wq[c][j])
  for (int idx = t; idx < 8192; idx += 256){
    int which = idx >> 12;
    int b = (idx >> 10) & 3, i = (idx >> 5) & 31, c = idx & 31;
    const float* wrow = which ? &Wks[c][0] : &Wqs[c][0];
    const float* srow = &Ss[b][i][0];
    float s = 0.f;
    #pragma unroll
    for (int j = 0; j < 32; j++) s += srow[j] * wrow[j];
    if (which) Us[b][i][c] = s; else Ts[b][i][c] = s;
  }
  if (t < 128){
    int b = t >> 5, o = t & 31;
    float s = 0.f;
    for (int j = 0; j < 32; j++) s += fc1[o * 32 + j] * avg[b][j];
    hid[b][o] = fmaxf(s, 0.f);
  }
  __syncthreads();
  // norms: ||q_c||^2 = Wq_c·T[:,c], ||k_o||^2 = Wk_o·U[:,o]
  if (t < 128){
    int b = t >> 5, c = t & 31;
    float sq = 0.f, sk = 0.f;
    #pragma unroll
    for (int i = 0; i < 32; i++){
      sq += Wqs[c][i] * Ts[b][i][c];
      sk += Wks[c][i] * Us[b][i][c];
    }
    nq2[b][c] = sq; nk2[b][c] = sk;
  }
  __syncthreads();
  // softmax over normalized gram; G[o][c] = Wk_o · T[:,c]
  if (t < 128){
    int bh = t >> 3, d = t & 7;   // bh = b*4+h
    int b = bh >> 2, h = bh & 3;
    int o = h * 8 + d;
    float nk = fmaxf(sqrtf(nk2[b][o]), 1e-12f);
    float l[8];
    float mx = -1e30f;
    #pragma unroll
    for (int e = 0; e < 8; e++){
      int c = h * 8 + e;
      float G = 0.f;
      #pragma unroll
      for (int i = 0; i < 32; i++) G += Wks[o][i] * Ts[b][i][c];
      float nq = fmaxf(sqrtf(nq2[b][c]), 1e-12f);
      l[e] = G / (nk * nq);
      mx = fmaxf(mx, l[e]);
    }
    float se = 0.f;
    #pragma unroll
    for (int e = 0; e < 8; e++){ l[e] = expf(l[e] - mx); se += l[e]; }
    float inv = 1.f / se;
    #pragma unroll
    for (int e = 0; e < 8; e++) attn_s[bh][d * 8 + e] = l[e] * inv;
  }
  if (t < 128){
    int b = t >> 5, o = t & 31;
    float s2 = 0.f;
    for (int i = 0; i < 32; i++) s2 += fc2[o * 32 + i] * hid[b][i];
    float m = sigmoidf_(s2);
    cmaskf[t] = m;
    out_cm[t] = m;
  }
  __syncthreads();
  for (int idx = t; idx < 4096; idx += 256){        // M[b][o][i]
    int b = idx >> 10, o = (idx >> 5) & 31, i = idx & 31;
    int hd = i >> 3, e = i & 7;
    float s = 0.f;
    #pragma unroll
    for (int d = 0; d < 8; d++)
      s += projW[o * 32 + hd * 8 + d] * attn_s[b * 4 + hd][d * 8 + e];
    Mf[idx] = s;
    Mbf[idx] = f2bf(s);
  }
}

// tile: [c8][xl][yl] uint4 (8 f16 channels per uint4). 16x16 output px, halo 3.
// R13: f16 tile + packed half2 weights + v_dot2_f32_f16 (no unpack, f32 accum).
__global__ __launch_bounds__(256) void spatial_mask_kernel(
    const float* __restrict__ xmsi, const float* __restrict__ W1, const float* __restrict__ W2,
    const float* __restrict__ sac3, float* __restrict__ out_sm){
  __shared__ uint4 tile[4][22][26];
  __shared__ u32 W1h[9 * 16], W2h[49 * 16];
  int t = threadIdx.x;
  int b = blockIdx.z;
  int x0 = blockIdx.x * 16, y0 = blockIdx.y * 16;
  for (int idx = t; idx < 9 * 16;  idx += 256){
    int tap = idx >> 4, cp = idx & 15;
    W1h[idx] = pkh(W1[tap * 32 + 2 * cp], W1[tap * 32 + 2 * cp + 1]);
  }
  for (int idx = t; idx < 49 * 16; idx += 256){
    int tap = idx >> 4, cp = idx & 15;
    W2h[idx] = pkh(W2[tap * 32 + 2 * cp], W2[tap * 32 + 2 * cp + 1]);
  }
  for (int p = t; p < 484; p += 256){
    int xl = p / 22, yl = p - xl * 22;
    int X = x0 - 3 + xl, Y = y0 - 3 + yl;
    uint4 u0, u1, u2, u3;
    if (X >= 0 && X < NS && Y >= 0 && Y < NS){
      float xr[32];
      ld32f(xmsi + ((size_t)b * NN + (size_t)Y * NS + X) * NC, xr);
      u0 = pack8h(xr); u1 = pack8h(xr + 8); u2 = pack8h(xr + 16); u3 = pack8h(xr + 24);
    } else {
      u0 = u1 = u2 = u3 = make_uint4(0, 0, 0, 0);
    }
    tile[0][xl][yl] = u0; tile[1][xl][yl] = u1; tile[2][xl][yl] = u2; tile[3][xl][yl] = u3;
  }
  __syncthreads();
  int j = t & 15, i = t >> 4;     // j: y (h), i: x (w)
  // m2: 7x7 taps, 4 independent chains (one per 8-channel group)
  float a0 = 0.f, a1 = 0.f, a2 = 0.f, a3 = 0.f;
  for (int aw = 0; aw < 7; aw++){
    for (int ah = 0; ah < 7; ah++){
      const u32* wr = &W2h[(aw * 7 + ah) * 16];
      uint4 u0 = tile[0][i + aw][j + ah];
      uint4 u1 = tile[1][i + aw][j + ah];
      uint4 u2 = tile[2][i + aw][j + ah];
      uint4 u3 = tile[3][i + aw][j + ah];
      a0 = __builtin_amdgcn_fdot2(h2(u0.x), h2(wr[0]),  a0, false);
      a0 = __builtin_amdgcn_fdot2(h2(u0.y), h2(wr[1]),  a0, false);
      a0 = __builtin_amdgcn_fdot2(h2(u0.z), h2(wr[2]),  a0, false);
      a0 = __builtin_amdgcn_fdot2(h2(u0.w), h2(wr[3]),  a0, false);
      a1 = __builtin_amdgcn_fdot2(h2(u1.x), h2(wr[4]),  a1, false);
      a1 = __builtin_amdgcn_fdot2(h2(u1.y), h2(wr[5]),  a1, false);
      a1 = __builtin_amdgcn_fdot2(h2(u1.z), h2(wr[6]),  a1, false);
      a1 = __builtin_amdgcn_fdot2(h2(u1.w), h2(wr[7]),  a1, false);
      a2 = __builtin_amdgcn_fdot2(h2(u2.x), h2(wr[8]),  a2, false);
      a2 = __builtin_amdgcn_fdot2(h2(u2.y), h2(wr[9]),  a2, false);
      a2 = __builtin_amdgcn_fdot2(h2(u2.z), h2(wr[10]), a2, false);
      a2 = __builtin_amdgcn_fdot2(h2(u2.w), h2(wr[11]), a2, false);
      a3 = __builtin_amdgcn_fdot2(h2(u3.x), h2(wr[12]), a3, false);
      a3 = __builtin_amdgcn_fdot2(h2(u3.y), h2(wr[13]), a3, false);
      a3 = __builtin_amdgcn_fdot2(h2(u3.z), h2(wr[14]), a3, false);
      a3 = __builtin_amdgcn_fdot2(h2(u3.w), h2(wr[15]), a3, false);
    }
  }
  float m2 = (a0 + a1) + (a2 + a3);
  // m1: 3x3 taps (offset +2)
  float b0 = 0.f, b1v = 0.f, b2v = 0.f, b3 = 0.f;
  for (int aw = 0; aw < 3; aw++){
    for (int ah = 0; ah < 3; ah++){
      const u32* wr = &W1h[(aw * 3 + ah) * 16];
      uint4 u0 = tile[0][i + aw + 2][j + ah + 2];
      uint4 u1 = tile[1][i + aw + 2][j + ah + 2];
      uint4 u2 = tile[2][i + aw + 2][j + ah + 2];
      uint4 u3 = tile[3][i + aw + 2][j + ah + 2];
      b0  = __builtin_amdgcn_fdot2(h2(u0.x), h2(wr[0]),  b0,  false);
      b0  = __builtin_amdgcn_fdot2(h2(u0.y), h2(wr[1]),  b0,  false);
      b0  = __builtin_amdgcn_fdot2(h2(u0.z), h2(wr[2]),  b0,  false);
      b0  = __builtin_amdgcn_fdot2(h2(u0.w), h2(wr[3]),  b0,  false);
      b1v = __builtin_amdgcn_fdot2(h2(u1.x), h2(wr[4]),  b1v, false);
      b1v = __builtin_amdgcn_fdot2(h2(u1.y), h2(wr[5]),  b1v, false);
      b1v = __builtin_amdgcn_fdot2(h2(u1.z), h2(wr[6]),  b1v, false);
      b1v = __builtin_amdgcn_fdot2(h2(u1.w), h2(wr[7]),  b1v, false);
      b2v = __builtin_amdgcn_fdot2(h2(u2.x), h2(wr[8]),  b2v, false);
      b2v = __builtin_amdgcn_fdot2(h2(u2.y), h2(wr[9]),  b2v, false);
      b2v = __builtin_amdgcn_fdot2(h2(u2.z), h2(wr[10]), b2v, false);
      b2v = __builtin_amdgcn_fdot2(h2(u2.w), h2(wr[11]), b2v, false);
      b3  = __builtin_amdgcn_fdot2(h2(u3.x), h2(wr[12]), b3,  false);
      b3  = __builtin_amdgcn_fdot2(h2(u3.y), h2(wr[13]), b3,  false);
      b3  = __builtin_amdgcn_fdot2(h2(u3.z), h2(wr[14]), b3,  false);
      b3  = __builtin_amdgcn_fdot2(h2(u3.w), h2(wr[15]), b3,  false);
    }
  }
  float m1 = (b0 + b1v) + (b2v + b3);
  float m = sac3[0] * m1 + sac3[1] * m2;
  float sg = sigmoidf_(m);
  int x = x0 + i, y = y0 + j;
  out_sm[(size_t)b * NN + (size_t)x * NS + y] = sg;   // (b,1,w,h): w-major
}

// ----------------------- R6 SPLIT: vgate — f32 V-proj + gate, 2 px/thread, no halo
__global__ __launch_bounds__(256) void vgate_kernel(
    const float* __restrict__ xfu, const float* __restrict__ Wv,
    const float* __restrict__ out_sm, const float* __restrict__ cmaskf,
    u16* __restrict__ gv){
  __shared__ alignas(16) float WvL[1024];       // [i][o]
  __shared__ float cml[NC];
  int t = threadIdx.x;
  int b = blockIdx.x >> 7;                      // 512 blocks: 128 per batch, 2 rows each
  int px0 = blockIdx.x * 512 + t;               // (X = t, Y = 2*(blk&127))
  int px1 = px0 + 256;                          // (X = t, Y+1)
  int X = t;
  int Y0 = (px0 >> 8) & 255;

  for (int idx = t; idx < 1024; idx += 256){
    int oo = idx >> 5, ii = idx & 31;
    WvL[ii * 32 + oo] = Wv[idx];                // Wv[o][i] -> [i][o]
  }
  if (t < 32) cml[t] = cmaskf[b * 32 + t];
  __syncthreads();

  float xr0[32], xr1[32];
  ld32f(xfu + (size_t)px0 * NC, xr0);
  ld32f(xfu + (size_t)px1 * NC, xr1);
  float sm0 = out_sm[(size_t)b * NN + (size_t)X * NS + Y0];
  float sm1 = out_sm[(size_t)b * NN + (size_t)X * NS + Y0 + 1];

  float vo0[32], vo1[32];
  #pragma unroll
  for (int q = 0; q < 32; q++){ vo0[q] = 0.f; vo1[q] = 0.f; }
  for (int i = 0; i < 32; i++){
    const float4* wr = (const float4*)&WvL[i * 32];
    float a0 = xr0[i], a1 = xr1[i];
    #pragma unroll
    for (int q = 0; q < 8; q++){
      float4 w4 = wr[q];
      vo0[4 * q]     += a0 * w4.x;  vo1[4 * q]     += a1 * w4.x;
      vo0[4 * q + 1] += a0 * w4.y;  vo1[4 * q + 1] += a1 * w4.y;
      vo0[4 * q + 2] += a0 * w4.z;  vo1[4 * q + 2] += a1 * w4.z;
      vo0[4 * q + 3] += a0 * w4.w;  vo1[4 * q + 3] += a1 * w4.w;
    }
  }
  float g0[32], g1[32];
  #pragma unroll
  for (int c = 0; c < 32; c++){
    float cm = cml[c];
    g0[c] = vo0[c] * sm0 * cm;
    g1[c] = vo1[c] * sm1 * cm;
  }
  uint4* d0 = (uint4*)(gv + (size_t)px0 * NC);
  uint4* d1 = (uint4*)(gv + (size_t)px1 * NC);
  d0[0] = pack8(g0);  d0[1] = pack8(g0 + 8);  d0[2] = pack8(g0 + 16);  d0[3] = pack8(g0 + 24);
  d1[0] = pack8(g1);  d1[1] = pack8(g1 + 8);  d1[2] = pack8(g1 + 16);  d1[3] = pack8(g1 + 24);
}

// ------------------- R6 SPLIT: vconv — pos1-pattern MFMA conv3x3 + xhsi residual
__global__ __launch_bounds__(256) void vconv_mfma_kernel(
    const u16* __restrict__ gv, const u16* __restrict__ wAv,
    const float* __restrict__ xhsi, u16* __restrict__ vspec_g){
  int t = threadIdx.x;
  int wv = t >> 6, l = t & 63;
  int lp = l & 15, lk = l >> 4;                 // fragment pixel / k-chunk
  int b = blockIdx.x >> 8, Y = blockIdx.x & 255;

  bf16x8 wf[9][2];
  #pragma unroll
  for (int r = 0; r < 9; r++){
    wf[r][0] = *(const bf16x8*)(wAv + ((r * 32 + lp) * 32 + lk * 8));
    wf[r][1] = *(const bf16x8*)(wAv + ((r * 32 + 16 + lp) * 32 + lk * 8));
  }

  const u16* src = gv + (size_t)b * NN * NC;
  const float* res = xhsi + (size_t)b * NN * NC;
  u16* dst = vspec_g + (size_t)b * NN * NC;

  for (int g = 0; g < 4; g++){
    int X0 = wv * 64 + g * 16;
    f32x4 acc0 = {0.f, 0.f, 0.f, 0.f};
    f32x4 acc1 = {0.f, 0.f, 0.f, 0.f};
    #pragma unroll
    for (int dh = -1; dh <= 1; dh++){
      int Yi = Y + dh;
      if ((unsigned)Yi < NS){                   // uniform skip = zero-pad rows
        const u16* row = src + (size_t)Yi * (NS * NC) + lk * 8;
        #pragma unroll
        for (int dw = -1; dw <= 1; dw++){
          int Xi = X0 + lp + dw;
          uint4 u = make_uint4(0, 0, 0, 0);
          if (dw == 0 || (unsigned)Xi < NS) u = *(const uint4*)(row + Xi * NC);
          bf16x8 bfr = __builtin_bit_cast(bf16x8, u);
          const int r = (dw + 1) * 3 + (dh + 1);
          acc0 = __builtin_amdgcn_mfma_f32_16x16x32_bf16(wf[r][0], bfr, acc0, 0, 0, 0);
          acc1 = __builtin_amdgcn_mfma_f32_16x16x32_bf16(wf[r][1], bfr, acc1, 0, 0, 0);
        }
      }
    }
    // D: col=lp=pixel, rows = lk*4+j (+16 for tile 1) = out channel; + residual
    size_t n = (size_t)Y * NS + (X0 + lp);
    float4 rA = *(const float4*)(res + n * NC + lk * 4);
    float4 rB = *(const float4*)(res + n * NC + lk * 4 + 16);
    float v0 = acc0.x + rA.x;
    float v1 = acc0.y + rA.y;
    float v2 = acc0.z + rA.z;
    float v3 = acc0.w + rA.w;
    float v4 = acc1.x + rB.x;
    float v5 = acc1.y + rB.y;
    float v6 = acc1.z + rB.z;
    float v7 = acc1.w + rB.w;
    u16* dp = dst + n * NC + lk * 4;
    *(uint2*)dp = make_uint2((u32)f2bf(v0) | ((u32)f2bf(v1) << 16),
                             (u32)f2bf(v2) | ((u32)f2bf(v3) << 16));
    *(uint2*)(dp + 16) = make_uint2((u32)f2bf(v4) | ((u32)f2bf(v5) << 16),
                                    (u32)f2bf(v6) | ((u32)f2bf(v7) << 16));
  }
}

// ---------------- FALLBACK: fused V-proj + gate + conv + residual (R4, proven)
__global__ __launch_bounds__(256) void vspec_kernel(
    const float* __restrict__ xfu, const float* __restrict__ Wv,
    const float* __restrict__ attnW, const float* __restrict__ out_sm,
    const float* __restrict__ cmaskf, const float* __restrict__ xhsi,
    u16* __restrict__ vspec_g){
  __shared__ u16 gv[32 * 10 * 40];              // [c][xl][yl(34,pad40)] gated v, bf16
  __shared__ u16 Wl[9 * 32 * 32];               // [r][i][o] bf16, r = aw*3+ah
  __shared__ alignas(16) float WvL[1024];       // [i][o]
  __shared__ float cml[32];
  int t = threadIdx.x;
  int b = blockIdx.z;
  int x0 = blockIdx.x * 8, y0 = blockIdx.y * 32;

  for (int idx = t; idx < 1024; idx += 256){
    int oo = idx >> 5, ii = idx & 31;
    WvL[ii * 32 + oo] = Wv[idx];                // Wv[o][i] -> [i][o]
  }
  if (t < 32) cml[t] = cmaskf[b * 32 + t];
  __syncthreads();

  for (int idx = t; idx < 9216; idx += 256){
    int oo = idx / 288;
    int rem = idx - oo * 288;
    int ii = rem / 9;
    int r = rem - ii * 9;
    Wl[(r * 32 + ii) * 32 + oo] = f2bf(attnW[idx]);
  }
  for (int p = t; p < 340; p += 256){           // 10 x 34 halo tile
    int xl = p / 34, yl = p - xl * 34;
    int X = x0 - 1 + xl, Y = y0 - 1 + yl;       // X: w, Y: h
    u16* dst = &gv[xl * 40 + yl];               // + c*400 per channel
    if (X >= 0 && X < NS && Y >= 0 && Y < NS){
      float xr[32];
      ld32f(xfu + ((size_t)b * NN + (size_t)Y * NS + X) * NC, xr);
      float sm = out_sm[(size_t)b * NN + (size_t)X * NS + Y];
      float vo[32];
      #pragma unroll
      for (int q = 0; q < 32; q++) vo[q] = 0.f;
      for (int i = 0; i < 32; i++){
        const float4* wr = (const float4*)&WvL[i * 32];
        float xv = xr[i];
        #pragma unroll
        for (int q = 0; q < 8; q++){
          float4 w4 = wr[q];
          vo[4 * q]     += xv * w4.x;
          vo[4 * q + 1] += xv * w4.y;
          vo[4 * q + 2] += xv * w4.z;
          vo[4 * q + 3] += xv * w4.w;
        }
      }
      #pragma unroll
      for (int c = 0; c < 32; c++) dst[c * 400] = f2bf(vo[c] * sm * cml[c]);
    } else {
      #pragma unroll
      for (int c = 0; c < 32; c++) dst[c * 400] = 0;
    }
  }
  __syncthreads();

  int o = t & 31, xs = t >> 5;
  float acc[32];
  #pragma unroll
  for (int yy = 0; yy < 32; yy++) acc[yy] = 0.f;
  #pragma unroll
  for (int aw = 0; aw < 3; aw++){
    for (int i2 = 0; i2 < 32; i2++){
      const uint4* rp = (const uint4*)(gv + (i2 * 10 + xs + aw) * 40);
      uint4 r0 = rp[0], r1 = rp[1], r2 = rp[2], r3 = rp[3], r4 = rp[4];
      float g[40];
      dec8(r0, g); dec8(r1, g + 8); dec8(r2, g + 16); dec8(r3, g + 24); dec8(r4, g + 32);
      const int wb = (aw * 3 * 32 + i2) * 32 + o;
      float w0 = bf2f(Wl[wb]);
      float w1 = bf2f(Wl[wb + 1024]);
      float w2 = bf2f(Wl[wb + 2048]);
      #pragma unroll
      for (int yy = 0; yy < 32; yy++)
        acc[yy] = fmaf(g[yy], w0, fmaf(g[yy + 1], w1, fmaf(g[yy + 2], w2, acc[yy])));
    }
  }
  int x = x0 + xs;
  #pragma unroll
  for (int yy = 0; yy < 32; yy++){
    size_t n = (size_t)b * NN + (size_t)(y0 + yy) * NS + x;
    vspec_g[n * NC + o] = f2bf(acc[yy] + xhsi[n * NC + o]);
  }
}

// ------------------------- SPLIT PATH R5: MFMA pos1 (vspec -> t), no LDS
// Wave handles 4 groups of 16 consecutive X at fixed Y. A=W[r][o][i], B=vspec px.
__global__ __launch_bounds__(256) void pos1_mfma_kernel(
    const u16* __restrict__ vspec_g, const u16* __restrict__ wA,
    const float* __restrict__ pos1b, u16* __restrict__ t_g){
  int t = threadIdx.x;
  int wv = t >> 6, l = t & 63;
  int lp = l & 15, lk = l >> 4;                 // fragment pixel / k-chunk
  int b = blockIdx.x >> 8, Y = blockIdx.x & 255;

  bf16x8 wf[9][2];
  #pragma unroll
  for (int r = 0; r < 9; r++){
    wf[r][0] = *(const bf16x8*)(wA + ((r * 32 + lp) * 32 + lk * 8));
    wf[r][1] = *(const bf16x8*)(wA + ((r * 32 + 16 + lp) * 32 + lk * 8));
  }
  float bs[8];
  #pragma unroll
  for (int j = 0; j < 4; j++){
    bs[j]     = pos1b[lk * 4 + j];
    bs[4 + j] = pos1b[16 + lk * 4 + j];
  }

  const u16* src = vspec_g + (size_t)b * NN * NC;
  u16* dst = t_g + (size_t)b * NN * NC;

  for (int g = 0; g < 4; g++){
    int X0 = wv * 64 + g * 16;
    f32x4 acc0 = {0.f, 0.f, 0.f, 0.f};
    f32x4 acc1 = {0.f, 0.f, 0.f, 0.f};
    #pragma unroll
    for (int dh = -1; dh <= 1; dh++){
      int Yi = Y + dh;
      if ((unsigned)Yi < NS){                   // uniform skip = zero-pad rows
        const u16* row = src + (size_t)Yi * (NS * NC) + lk * 8;
        #pragma unroll
        for (int dw = -1; dw <= 1; dw++){
          int Xi = X0 + lp + dw;
          uint4 u = make_uint4(0, 0, 0, 0);
          if (dw == 0 || (unsigned)Xi < NS) u = *(const uint4*)(row + Xi * NC);
          bf16x8 bfr = __builtin_bit_cast(bf16x8, u);
          const int r = (dw + 1) * 3 + (dh + 1);
          acc0 = __builtin_amdgcn_mfma_f32_16x16x32_bf16(wf[r][0], bfr, acc0, 0, 0, 0);
          acc1 = __builtin_amdgcn_mfma_f32_16x16x32_bf16(wf[r][1], bfr, acc1, 0, 0, 0);
        }
      }
    }
    // D: col=lp=pixel, rows = lk*4+j (+16 for tile 1) = out channel
    float v0 = gelu_exact(acc0.x + bs[0]);
    float v1 = gelu_exact(acc0.y + bs[1]);
    float v2 = gelu_exact(acc0.z + bs[2]);
    float v3 = gelu_exact(acc0.w + bs[3]);
    float v4 = gelu_exact(acc1.x + bs[4]);
    float v5 = gelu_exact(acc1.y + bs[5]);
    float v6 = gelu_exact(acc1.z + bs[6]);
    float v7 = gelu_exact(acc1.w + bs[7]);
    u16* dp = dst + ((size_t)Y * NS + (X0 + lp)) * NC + lk * 4;
    *(uint2*)dp = make_uint2((u32)f2bf(v0) | ((u32)f2bf(v1) << 16),
                             (u32)f2bf(v2) | ((u32)f2bf(v3) << 16));
    *(uint2*)(dp + 16) = make_uint2((u32)f2bf(v4) | ((u32)f2bf(v5) << 16),
                                    (u32)f2bf(v6) | ((u32)f2bf(v7) << 16));
  }
}

// -------------------- SPLIT PATH R5: MFMA pos2 (t -> out, + out1 epilogue), no LDS
// Wave handles 4 groups of 16 consecutive Y at fixed X (store (b,c,w,h) coalesced in h).
__global__ __launch_bounds__(256) void pos2_mfma_kernel(
    const u16* __restrict__ t_g, const u16* __restrict__ vspec_g,
    const u16* __restrict__ wA, const float* __restrict__ pos2b,
    const u16* __restrict__ Mbf, const float* __restrict__ projb,
    float* __restrict__ outp){
  int t = threadIdx.x;
  int wv = t >> 6, l = t & 63;
  int lp = l & 15, lk = l >> 4;
  int b = blockIdx.x >> 8, X = blockIdx.x & 255;

  bf16x8 wf[9][2];
  #pragma unroll
  for (int r = 0; r < 9; r++){
    wf[r][0] = *(const bf16x8*)(wA + ((r * 32 + lp) * 32 + lk * 8));
    wf[r][1] = *(const bf16x8*)(wA + ((r * 32 + 16 + lp) * 32 + lk * 8));
  }
  bf16x8 mf0 = *(const bf16x8*)(Mbf + ((b * 32 + lp) * 32 + lk * 8));
  bf16x8 mf1 = *(const bf16x8*)(Mbf + ((b * 32 + 16 + lp) * 32 + lk * 8));
  float b2s[8], pbs[8];
  #pragma unroll
  for (int j = 0; j < 4; j++){
    b2s[j]     = pos2b[lk * 4 + j];
    b2s[4 + j] = pos2b[16 + lk * 4 + j];
    pbs[j]     = projb[lk * 4 + j];
    pbs[4 + j] = projb[16 + lk * 4 + j];
  }

  const u16* tsrc = t_g + (size_t)b * NN * NC;
  const u16* vsrc = vspec_g + (size_t)b * NN * NC;
  float* ob0 = outp + (size_t)b * 32 * NN + (size_t)X * NS;

  for (int g = 0; g < 4; g++){
    int Y0 = wv * 64 + g * 16;
    int Yp = Y0 + lp;
    // epilogue GEMM first (independent chain): P = M @ vspec[px]
    f32x4 e0 = {0.f, 0.f, 0.f, 0.f};
    f32x4 e1 = {0.f, 0.f, 0.f, 0.f};
    {
      uint4 u = *(const uint4*)(vsrc + ((size_t)Yp * NS + X) * NC + lk * 8);
      bf16x8 bfr = __builtin_bit_cast(bf16x8, u);
      e0 = __builtin_amdgcn_mfma_f32_16x16x32_bf16(mf0, bfr, e0, 0, 0, 0);
      e1 = __builtin_amdgcn_mfma_f32_16x16x32_bf16(mf1, bfr, e1, 0, 0, 0);
    }
    f32x4 acc0 = {0.f, 0.f, 0.f, 0.f};
    f32x4 acc1 = {0.f, 0.f, 0.f, 0.f};
    #pragma unroll
    for (int dw = -1; dw <= 1; dw++){
      int Xi = X + dw;
      if ((unsigned)Xi < NS){                   // uniform skip = zero-pad cols
        const u16* col = tsrc + (size_t)Xi * NC + lk * 8;
        #pragma unroll
        for (int dh = -1; dh <= 1; dh++){
          int Yi = Yp + dh;
          uint4 u = make_uint4(0, 0, 0, 0);
          if (dh == 0 || (unsigned)Yi < NS) u = *(const uint4*)(col + (size_t)Yi * (NS * NC));
          bf16x8 bfr = __builtin_bit_cast(bf16x8, u);
          const int r = (dw + 1) * 3 + (dh + 1);
          acc0 = __builtin_amdgcn_mfma_f32_16x16x32_bf16(wf[r][0], bfr, acc0, 0, 0, 0);
          acc1 = __builtin_amdgcn_mfma_f32_16x16x32_bf16(wf[r][1], bfr, acc1, 0, 0, 0);
        }
      }
    }
    float r0 = acc0.x + b2s[0] + gelu_exact(e0.x + pbs[0]);
    float r1 = acc0.y + b2s[1] + gelu_exact(e0.y + pbs[1]);
    float r2 = acc0.z + b2s[2] + gelu_exact(e0.z + pbs[2]);
    float r3 = acc0.w + b2s[3] + gelu_exact(e0.w + pbs[3]);
    float r4 = acc1.x + b2s[4] + gelu_exact(e1.x + pbs[4]);
    float r5 = acc1.y + b2s[5] + gelu_exact(e1.y + pbs[5]);
    float r6 = acc1.z + b2s[6] + gelu_exact(e1.z + pbs[6]);
    float r7 = acc1.w + b2s[7] + gelu_exact(e1.w + pbs[7]);
    float* ob = ob0 + Yp + (size_t)(lk * 4) * NN;   // channel lk*4, + c*NN per channel
    ob[0]                 = r0;
    ob[(size_t)NN]        = r1;
    ob[(size_t)2 * NN]    = r2;
    ob[(size_t)3 * NN]    = r3;
    float* ob2 = ob + (size_t)16 * NN;
    ob2[0]                = r4;
    ob2[(size_t)NN]       = r5;
    ob2[(size_t)2 * NN]   = r6;
    ob2[(size_t)3 * NN]   = r7;
  }
}

// ------------------------- FALLBACK PATH (ws too small): R3's fused pos_out, proven
__global__ __launch_bounds__(320) void pos_out_kernel(
    const u16* __restrict__ vspec_g, const u16* __restrict__ wt1,
    const u16* __restrict__ wt2, const float* __restrict__ pos1b,
    const float* __restrict__ pos2b, const float* __restrict__ Mf,
    const float* __restrict__ projb, float* __restrict__ outp){
  __shared__ u16 vs[32 * 12 * 40];    // [i][vxl(12)][vyl(36,pad40)]
  __shared__ u16 tt[32 * 10 * 40];    // [o][txl(10)][tyl(34,pad40)]
  __shared__ u16 wsl[3072];           // one aw-slice: [ah][i][o]
  int t = threadIdx.x;
  int b = blockIdx.z;
  int x0 = blockIdx.x * 8, y0 = blockIdx.y * 32;
  int o = t & 31, xsl = t >> 5;       // xsl in [0,10)

  for (int p = t; p < 12 * 36; p += 320){
    int vxl = p / 36, vyl = p - vxl * 36;
    int X = x0 - 2 + vxl, Y = y0 - 2 + vyl;
    u16* dst = &vs[vxl * 40 + vyl];
    if (X >= 0 && X < NS && Y >= 0 && Y < NS){
      const uint4* src = (const uint4*)(vspec_g + ((size_t)b * NN + (size_t)Y * NS + X) * NC);
      uint4 u0 = src[0], u1 = src[1], u2 = src[2], u3 = src[3];
      alignas(16) u16 raw[32];
      *(uint4*)(raw) = u0; *(uint4*)(raw + 8) = u1;
      *(uint4*)(raw + 16) = u2; *(uint4*)(raw + 24) = u3;
      #pragma unroll
      for (int i = 0; i < 32; i++) dst[i * 480] = raw[i];
    } else {
      #pragma unroll
      for (int i = 0; i < 32; i++) dst[i * 480] = 0;
    }
  }
  __syncthreads();

  float ta[34];
  #pragma unroll
  for (int k = 0; k < 34; k++) ta[k] = 0.f;
  for (int aw = 0; aw < 3; aw++){
    for (int idx = t; idx < 3072; idx += 320) wsl[idx] = wt1[aw * 3072 + idx];
    __syncthreads();
    for (int i2 = 0; i2 < 32; i2++){
      const uint4* rp = (const uint4*)(vs + (i2 * 12 + xsl + aw) * 40);
      uint4 r0 = rp[0], r1 = rp[1], r2 = rp[2], r3 = rp[3], r4 = rp[4];
      float g[40];
      dec8(r0, g); dec8(r1, g + 8); dec8(r2, g + 16); dec8(r3, g + 24); dec8(r4, g + 32);
      float w0 = bf2f(wsl[i2 * 32 + o]);
      float w1 = bf2f(wsl[i2 * 32 + o + 1024]);
      float w2 = bf2f(wsl[i2 * 32 + o + 2048]);
      #pragma unroll
      for (int yl = 0; yl < 34; yl++)
        ta[yl] = fmaf(g[yl], w0, fmaf(g[yl + 1], w1, fmaf(g[yl + 2], w2, ta[yl])));
    }
    __syncthreads();
  }
  {
    float b1 = pos1b[o];
    int X = x0 - 1 + xsl;
    bool colOK = (X >= 0 && X < NS);
    u16* trow = &tt[(o * 10 + xsl) * 40];
    #pragma unroll
    for (int yl = 0; yl < 34; yl++){
      int Y = y0 - 1 + yl;
      float val = (colOK && Y >= 0 && Y < NS) ? gelu_exact(ta[yl] + b1) : 0.f;
      trow[yl] = f2bf(val);
    }
  }
  __syncthreads();

  float acc2[32];
  #pragma unroll
  for (int yy = 0; yy < 32; yy++) acc2[yy] = 0.f;
  for (int aw = 0; aw < 3; aw++){
    for (int idx = t; idx < 3072; idx += 320) wsl[idx] = wt2[aw * 3072 + idx];
    __syncthreads();
    if (xsl < 8){
      for (int i2 = 0; i2 < 32; i2++){
        const uint4* rp = (const uint4*)(tt + (i2 * 10 + xsl + aw) * 40);
        uint4 r0 = rp[0], r1 = rp[1], r2 = rp[2], r3 = rp[3], r4 = rp[4];
        float g[40];
        dec8(r0, g); dec8(r1, g + 8); dec8(r2, g + 16); dec8(r3, g + 24); dec8(r4, g + 32);
        float w0 = bf2f(wsl[i2 * 32 + o]);
        float w1 = bf2f(wsl[i2 * 32 + o + 1024]);
        float w2 = bf2f(wsl[i2 * 32 + o + 2048]);
        #pragma unroll
        for (int yy = 0; yy < 32; yy++)
          acc2[yy] = fmaf(g[yy], w0, fmaf(g[yy + 1], w1, fmaf(g[yy + 2], w2, acc2[yy])));
      }
    }
    __syncthreads();
  }
  if (xsl < 8){
    int x = x0 + xsl;
    float m[32];
    {
      const float4* mp = (const float4*)(Mf + b * 1024 + o * 32);
      #pragma unroll
      for (int k = 0; k < 8; k++){
        float4 f = mp[k];
        m[4 * k] = f.x; m[4 * k + 1] = f.y; m[4 * k + 2] = f.z; m[4 * k + 3] = f.w;
      }
    }
    float pb = projb[o];
    float b2v = pos2b[o];
    float outv[32];
    #pragma unroll
    for (int yy = 0; yy < 32; yy++){
      size_t n = (size_t)b * NN + (size_t)(y0 + yy) * NS + x;
      const uint4* xp = (const uint4*)(vspec_g + n * NC);
      uint4 u0 = xp[0], u1 = xp[1], u2 = xp[2], u3 = xp[3];
      float xr[32];
      dec8(u0, xr); dec8(u1, xr + 8); dec8(u2, xr + 16); dec8(u3, xr + 24);
      float s = pb;
      #pragma unroll
      for (int i2 = 0; i2 < 32; i2++) s += m[i2] * xr[i2];
      outv[yy] = acc2[yy] + b2v + gelu_exact(s);
    }
    float4* dp = (float4*)(outp + (((size_t)(b * 32 + o) * NS) + x) * NS + y0);
    #pragma unroll
    for (int k = 0; k < 8; k++)
      dp[k] = make_float4(outv[4 * k], outv[4 * k + 1], outv[4 * k + 2], outv[4 * k + 3]);
  }
}

// ---------------------------------------------------------------------- launch
extern "C" void kernel_launch(void* const* d_in, const int* in_sizes, int n_in,
                              void* d_out, int out_size, void* d_ws, size_t ws_size,
                              hipStream_t stream){
  (void)in_sizes; (void)n_in; (void)out_size;
  const float* xfu   = (const float*)d_in[0];
  const float* xmsi  = (const float*)d_in[1];
  const float* xhsi  = (const float*)d_in[2];
  const float* Wq    = (const float*)d_in[3];
  const float* Wk    = (const float*)d_in[4];
  const float* Wv    = (const float*)d_in[5];
  const float* projW = (const float*)d_in[6];
  const float* projb = (const float*)d_in[7];
  const float* pos1W = (const float*)d_in[8];
  const float* pos1b = (const float*)d_in[9];
  const float* pos2W = (const float*)d_in[10];
  const float* pos2b = (const float*)d_in[11];
  const float* cafc1 = (const float*)d_in[12];
  const float* cafc2 = (const float*)d_in[13];
  const float* sac1a = (const float*)d_in[14];
  const float* sac1b = (const float*)d_in[15];
  const float* sac2a = (const float*)d_in[16];
  const float* sac2b = (const float*)d_in[17];
  const float* sac3  = (const float*)d_in[18];
  const float* attnW = (const float*)d_in[19];

  float* out = (float*)d_out;
  float* out_main = out;                  // (b,c,w,h) 8388608 f32
  float* out_cm   = out + 8388608;        // 128
  float* out_sm   = out + 8388736;        // 262144

  // workspace map: sums[0,512) S[1024,17408) cmask[17920] W1[18432] W2[20480]
  // Mf[28672,45056) wt1[45056] wt2[63488] wA1[81920] wA2[100352] Mbf[118784,126976)
  // vspec [131072,+16M) (first 2MB doubles as pbufT, dead before vconv),
  // t/gv [+16M,+32M)  (gv aliases t_g: disjoint lifetimes)
  char* ws = (char*)d_ws;
  float* sums   = (float*)(ws + 0);         // 128 f (zeroed with S: 4352 f total)
  float* Sm     = (float*)(ws + 1024);      // 4096 f = [4][32][32]
  float* cmaskf = (float*)(ws + 17920);     // 128 f
  float* W1     = (float*)(ws + 18432);     // 288 f
  float* W2     = (float*)(ws + 20480);     // 1568 f
  float* Mf     = (float*)(ws + 28672);     // 4096 f
  u16*   wt1    = (u16*)(ws + 45056);       // 9216 bf16 [r][i][o] (fallback) / wAv (split)
  u16*   wt2    = (u16*)(ws + 63488);       // 9216 bf16
  u16*   wA1    = (u16*)(ws + 81920);       // 9216 bf16 [r][o][i] (MFMA)
  u16*   wA2    = (u16*)(ws + 100352);      // 9216 bf16
  u16*   Mbf    = (u16*)(ws + 118784);      // 4096 bf16 [b][o][i]
  u16*   vspec  = (u16*)(ws + 131072);      // 16 MB bf16 (b,n,c)
  float* pbufT  = (float*)(ws + 131072);    // 2 MB partials [4096][128] (dead pre-vconv)
  u16*   t_g    = (u16*)(ws + 131072 + 16777216);   // 16 MB bf16 (split path only)
  const bool split = ws_size >= (size_t)(131072 + 2 * 16777216);
  u16*   wAv    = split ? wt1 : wA1;        // split: wt1 slot free; fallback: dummy
  u16*   gvbuf  = t_g;                      // gv dies before pos1 writes t_g

  pre_kernel<<<64, 256, 0, stream>>>(sac1a, sac1b, sac2a, sac2b, pos1W, pos2W, attnW,
                                     sums, W1, W2, wt1, wt2, wA1, wA2, wAv,
                                     split ? 0 : 1);
  channel_sum_kernel<<<256, 256, 0, stream>>>(xhsi, sums);
  spatial_mask_kernel<<<dim3(16, 16, NB), 256, 0, stream>>>(xmsi, W1, W2, sac3, out_sm);
  x2_kernel<<<512, 256, 0, stream>>>(xfu, pbufT);
  x2r_kernel<<<64, 64, 0, stream>>>(pbufT, Sm);
  mid_kernel<<<1, 256, 0, stream>>>(sums, cafc1, cafc2, cmaskf, out_cm,
                                    Sm, Wq, Wk, projW, Mf, Mbf);
  if (split){
    vgate_kernel<<<512, 256, 0, stream>>>(xfu, Wv, out_sm, cmaskf, gvbuf);
    vconv_mfma_kernel<<<1024, 256, 0, stream>>>(gvbuf, wAv, xhsi, vspec);
    pos1_mfma_kernel<<<1024, 256, 0, stream>>>(vspec, wA1, pos1b, t_g);
    pos2_mfma_kernel<<<1024, 256, 0, stream>>>(t_g, vspec, wA2, pos2b, Mbf, projb, out_main);
  } else {
    vspec_kernel<<<dim3(32, 8, NB), 256, 0, stream>>>(
        xfu, Wv, attnW, out_sm, cmaskf, xhsi, vspec);
    pos_out_kernel<<<dim3(32, 8, NB), 320, 0, stream>>>(
        vspec, wt1, wt2, pos1b, pos2b, Mf, projb, out_main);
  }
}